// Round 1
// baseline (5383.316 us; speedup 1.0000x reference)
//
#include <hip/hip_runtime.h>

#define N_A 50000
#define N_P 100000
#define E_W 1600000
#define E_C 3200000
#define HA (N_A*64)
#define HP (N_P*64)

__device__ __forceinline__ unsigned fenc(float f) {
    unsigned u = __float_as_uint(f);
    return (u & 0x80000000u) ? ~u : (u | 0x80000000u);
}
__device__ __forceinline__ float fdec(unsigned k) {
    return (k & 0x80000000u) ? __uint_as_float(k & 0x7fffffffu) : __uint_as_float(~k);
}

// out[M,64] = act(X[M,K] @ W^T + b); optional el/er = sum_F (out * al/ar) per head
__global__ void gemm_kernel(const float* __restrict__ X, const float* __restrict__ W,
                            const float* __restrict__ bias, float* __restrict__ out,
                            const float* __restrict__ al, float* __restrict__ el,
                            const float* __restrict__ ar, float* __restrict__ er,
                            int M, int K, int H, int doRelu)
{
    extern __shared__ float smem[];
    float* Ws = smem;                  // 64 x (K+1)  (pad breaks bank conflicts)
    float* Xs = smem + 64 * (K + 1);   // 4 x K
    int tid = threadIdx.x;
    int lane = tid & 63;
    int r = tid >> 6;
    int row = blockIdx.x * 4 + r;

    for (int idx = tid; idx < 64 * K; idx += 256) {
        int o = idx / K, k = idx - o * K;
        Ws[o * (K + 1) + k] = W[idx];
    }
    if (row < M) {
        for (int k = lane; k < K; k += 64) Xs[r * K + k] = X[(long)row * K + k];
    } else {
        for (int k = lane; k < K; k += 64) Xs[r * K + k] = 0.f;
    }
    __syncthreads();

    float acc = bias ? bias[lane] : 0.f;
    const float* xrow = Xs + r * K;
    const float* wrow = Ws + lane * (K + 1);
#pragma unroll 8
    for (int k = 0; k < K; ++k) acc = fmaf(xrow[k], wrow[k], acc);
    if (doRelu) acc = fmaxf(acc, 0.f);
    if (row < M) out[(long)row * 64 + lane] = acc;

    int Fd = 64 / H;
    if (el) {
        float p = acc * al[lane];
        for (int off = 1; off < Fd; off <<= 1) p += __shfl_xor(p, off, 64);
        if ((lane & (Fd - 1)) == 0 && row < M) el[row * H + (lane / Fd)] = p;
    }
    if (er) {
        float p = acc * ar[lane];
        for (int off = 1; off < Fd; off <<= 1) p += __shfl_xor(p, off, 64);
        if ((lane & (Fd - 1)) == 0 && row < M) er[row * H + (lane / Fd)] = p;
    }
}

__global__ void init_bias_kernel(float* __restrict__ out, const float* __restrict__ b1,
                                 const float* __restrict__ b2, int N)
{
    long i = (long)blockIdx.x * blockDim.x + threadIdx.x;
    if (i >= (long)N * 64) return;
    int c = (int)(i & 63);
    out[i] = b1[c] + (b2 ? b2[c] : 0.f);
}

__global__ void edge_max_kernel(const int* __restrict__ src, const int* __restrict__ dst,
                                const float* __restrict__ el, const float* __restrict__ er,
                                unsigned* __restrict__ menc, int E, int hshift)
{
    long i = (long)blockIdx.x * blockDim.x + threadIdx.x;
    int H1 = 1 << hshift;
    if (i >= ((long)E << hshift)) return;
    int e = (int)(i >> hshift), h = (int)(i & (H1 - 1));
    float v = el[src[e] * H1 + h] + er[dst[e] * H1 + h];
    v = v > 0.f ? v : 0.2f * v;
    atomicMax(&menc[dst[e] * H1 + h], fenc(v));
}

__global__ void edge_sum_kernel(const int* __restrict__ src, const int* __restrict__ dst,
                                const float* __restrict__ el, const float* __restrict__ er,
                                const unsigned* __restrict__ menc, float* __restrict__ ssum,
                                int E, int hshift)
{
    long i = (long)blockIdx.x * blockDim.x + threadIdx.x;
    int H1 = 1 << hshift;
    if (i >= ((long)E << hshift)) return;
    int e = (int)(i >> hshift), h = (int)(i & (H1 - 1));
    int d = dst[e];
    float v = el[src[e] * H1 + h] + er[d * H1 + h];
    v = v > 0.f ? v : 0.2f * v;
    atomicAdd(&ssum[d * H1 + h], expf(v - fdec(menc[d * H1 + h])));
}

// one wave per edge; lane = output feature
__global__ void edge_agg_kernel(const int* __restrict__ src, const int* __restrict__ dst,
                                const float* __restrict__ el, const float* __restrict__ er,
                                const unsigned* __restrict__ menc, const float* __restrict__ ssum,
                                const float* __restrict__ Fsrc, float* __restrict__ rst,
                                int E, int hshift)
{
    long gt = (long)blockIdx.x * blockDim.x + threadIdx.x;
    int eIdx = (int)(gt >> 6);
    int lane = threadIdx.x & 63;
    if (eIdx >= E) return;
    int sN = src[eIdx], dN = dst[eIdx];
    int H1 = 1 << hshift;
    int h = lane >> (6 - hshift);
    float v = el[sN * H1 + h] + er[dN * H1 + h];
    v = v > 0.f ? v : 0.2f * v;
    float a = expf(v - fdec(menc[dN * H1 + h])) / ssum[dN * H1 + h];
    atomicAdd(&rst[(long)dN * 64 + lane], Fsrc[(long)sN * 64 + lane] * a);
}

__global__ void l2norm_kernel(const float* __restrict__ in, float* __restrict__ out, int N)
{
    long gt = (long)blockIdx.x * blockDim.x + threadIdx.x;
    int row = (int)(gt >> 6);
    int lane = threadIdx.x & 63;
    if (row >= N) return;
    float v = in[(long)row * 64 + lane];
    float ss = v * v;
    for (int off = 1; off < 64; off <<= 1) ss += __shfl_xor(ss, off, 64);
    out[(long)row * 64 + lane] = v / fmaxf(sqrtf(ss), 1e-12f);
}

static void run_gat(const float* h_src, const float* h_dst, int Ns, int Nd,
                    const int* srcI, const int* dstI, int E,
                    const float* W, const float* al, const float* ar,
                    float* Psrc, float* Pdst, float* el, float* er,
                    unsigned* menc, float* ssum, float* rst, int H, hipStream_t stream)
{
    int hshift = (H == 4) ? 2 : 0;
    size_t shmem = (64 * 65 + 4 * 64) * sizeof(float);
    if (h_src == h_dst) {
        gemm_kernel<<<(Ns + 3) / 4, 256, shmem, stream>>>(h_src, W, nullptr, Psrc,
                                                          al, el, ar, er, Ns, 64, H, 0);
        Pdst = Psrc;
    } else {
        gemm_kernel<<<(Ns + 3) / 4, 256, shmem, stream>>>(h_src, W, nullptr, Psrc,
                                                          al, el, nullptr, nullptr, Ns, 64, H, 0);
        gemm_kernel<<<(Nd + 3) / 4, 256, shmem, stream>>>(h_dst, W, nullptr, Pdst,
                                                          nullptr, nullptr, ar, er, Nd, 64, H, 0);
    }
    hipMemsetAsync(menc, 0, (size_t)Nd * H * sizeof(unsigned), stream);
    hipMemsetAsync(ssum, 0, (size_t)Nd * H * sizeof(float), stream);
    long EH = (long)E * H;
    edge_max_kernel<<<(EH + 255) / 256, 256, 0, stream>>>(srcI, dstI, el, er, menc, E, hshift);
    edge_sum_kernel<<<(EH + 255) / 256, 256, 0, stream>>>(srcI, dstI, el, er, menc, ssum, E, hshift);
    long ET = (long)E * 64;
    edge_agg_kernel<<<(ET + 255) / 256, 256, 0, stream>>>(srcI, dstI, el, er, menc, ssum,
                                                          Psrc, rst, E, hshift);
}

extern "C" void kernel_launch(void* const* d_in, const int* in_sizes, int n_in,
                              void* d_out, int out_size, void* d_ws, size_t ws_size,
                              hipStream_t stream)
{
    const float* feat_a = (const float*)d_in[0];
    const float* feat_p = (const float*)d_in[1];
    const float* fmWa = (const float*)d_in[2];
    const float* fmba = (const float*)d_in[3];
    const float* fmWp = (const float*)d_in[4];
    const float* fmbp = (const float*)d_in[5];
    // etype blocks: writes@6, written_by@14, cites@22; layout: g1W,g1al,g1ar,g1b,g2W,g2al,g2ar,g2b
    const float* g1w_W = (const float*)d_in[6];  const float* g1w_al = (const float*)d_in[7];
    const float* g1w_ar = (const float*)d_in[8]; const float* g1w_b = (const float*)d_in[9];
    const float* g2w_W = (const float*)d_in[10]; const float* g2w_al = (const float*)d_in[11];
    const float* g2w_ar = (const float*)d_in[12]; const float* g2w_b = (const float*)d_in[13];
    const float* g1wb_W = (const float*)d_in[14]; const float* g1wb_al = (const float*)d_in[15];
    const float* g1wb_ar = (const float*)d_in[16]; const float* g1wb_b = (const float*)d_in[17];
    const float* g2wb_W = (const float*)d_in[18]; const float* g2wb_al = (const float*)d_in[19];
    const float* g2wb_ar = (const float*)d_in[20]; const float* g2wb_b = (const float*)d_in[21];
    const float* g1c_W = (const float*)d_in[22]; const float* g1c_al = (const float*)d_in[23];
    const float* g1c_ar = (const float*)d_in[24]; const float* g1c_b = (const float*)d_in[25];
    const float* g2c_W = (const float*)d_in[26]; const float* g2c_al = (const float*)d_in[27];
    const float* g2c_ar = (const float*)d_in[28]; const float* g2c_b = (const float*)d_in[29];
    const int* w_src = (const int*)d_in[30];
    const int* w_dst = (const int*)d_in[31];
    const int* wb_src = (const int*)d_in[32];
    const int* wb_dst = (const int*)d_in[33];
    const int* c_src = (const int*)d_in[34];
    const int* c_dst = (const int*)d_in[35];

    float* ws = (float*)d_ws;
    size_t off = 0;
    auto alloc = [&](size_t n) { float* p = ws + off; off += n; return p; };
    float* h_a  = alloc(HA);
    float* h_p  = alloc(HP);
    float* Pa   = alloc(HP);
    float* Pb   = alloc(HP);
    float* h1_p = alloc(HP);
    float* h1_a = alloc(HA);
    float* elb  = alloc((size_t)N_P * 4);
    float* erb  = alloc((size_t)N_P * 4);
    unsigned* menc = (unsigned*)alloc((size_t)N_P * 4);
    float* ssum = alloc((size_t)N_P * 4);
    float* h2_p = h_p;  // reuse: h_p dead after layer-1 projections
    float* h2_a = h_a;

    // Feature mapping: relu(X @ W^T + b)
    {
        size_t sh128 = (64 * 129 + 4 * 128) * sizeof(float);
        size_t sh256 = (64 * 257 + 4 * 256) * sizeof(float);
        gemm_kernel<<<(N_A + 3) / 4, 256, sh128, stream>>>(feat_a, fmWa, fmba, h_a,
            nullptr, nullptr, nullptr, nullptr, N_A, 128, 4, 1);
        gemm_kernel<<<(N_P + 3) / 4, 256, sh256, stream>>>(feat_p, fmWp, fmbp, h_p,
            nullptr, nullptr, nullptr, nullptr, N_P, 256, 4, 1);
    }

    // ---- Layer 1 (H=4) ----
    init_bias_kernel<<<((long)N_P * 64 + 255) / 256, 256, 0, stream>>>(h1_p, g1w_b, g1c_b, N_P);
    init_bias_kernel<<<((long)N_A * 64 + 255) / 256, 256, 0, stream>>>(h1_a, g1wb_b, nullptr, N_A);
    run_gat(h_a, h_p, N_A, N_P, w_src, w_dst, E_W, g1w_W, g1w_al, g1w_ar,
            Pa, Pb, elb, erb, menc, ssum, h1_p, 4, stream);
    run_gat(h_p, h_p, N_P, N_P, c_src, c_dst, E_C, g1c_W, g1c_al, g1c_ar,
            Pa, Pb, elb, erb, menc, ssum, h1_p, 4, stream);
    run_gat(h_p, h_a, N_P, N_A, wb_src, wb_dst, E_W, g1wb_W, g1wb_al, g1wb_ar,
            Pa, Pb, elb, erb, menc, ssum, h1_a, 4, stream);

    // ---- Layer 2 (H=1) ----
    init_bias_kernel<<<((long)N_P * 64 + 255) / 256, 256, 0, stream>>>(h2_p, g2w_b, g2c_b, N_P);
    init_bias_kernel<<<((long)N_A * 64 + 255) / 256, 256, 0, stream>>>(h2_a, g2wb_b, nullptr, N_A);
    run_gat(h1_a, h1_p, N_A, N_P, w_src, w_dst, E_W, g2w_W, g2w_al, g2w_ar,
            Pa, Pb, elb, erb, menc, ssum, h2_p, 1, stream);
    run_gat(h1_p, h1_p, N_P, N_P, c_src, c_dst, E_C, g2c_W, g2c_al, g2c_ar,
            Pa, Pb, elb, erb, menc, ssum, h2_p, 1, stream);
    run_gat(h1_p, h1_a, N_P, N_A, wb_src, wb_dst, E_W, g2wb_W, g2wb_al, g2wb_ar,
            Pa, Pb, elb, erb, menc, ssum, h2_a, 1, stream);

    // ---- L2 normalize: authors first, then papers ----
    float* out = (float*)d_out;
    l2norm_kernel<<<((long)N_A * 64 + 255) / 256, 256, 0, stream>>>(h2_a, out, N_A);
    l2norm_kernel<<<((long)N_P * 64 + 255) / 256, 256, 0, stream>>>(h2_p, out + HA, N_P);
}

// Round 2
// 2996.677 us; speedup vs baseline: 1.7964x; 1.7964x over previous
//
#include <hip/hip_runtime.h>

#define N_A 50000
#define N_P 100000
#define E_W 1600000
#define E_C 3200000
#define HA (N_A*64)
#define HP (N_P*64)

// ---------------- dense projection ----------------
// out[M,64] = act(X[M,K] @ W^T + b); optional el/er = sum_F (out * al/ar) per head
// out may be nullptr (projection used only for the attention dot products).
__global__ void gemm_kernel(const float* __restrict__ X, const float* __restrict__ W,
                            const float* __restrict__ bias, float* __restrict__ out,
                            const float* __restrict__ al, float* __restrict__ el,
                            const float* __restrict__ ar, float* __restrict__ er,
                            int M, int K, int H, int doRelu)
{
    extern __shared__ float smem[];
    float* Ws = smem;                  // 64 x (K+1)
    float* Xs = smem + 64 * (K + 1);   // 4 x K
    int tid = threadIdx.x;
    int lane = tid & 63;
    int r = tid >> 6;
    int row = blockIdx.x * 4 + r;

    for (int idx = tid; idx < 64 * K; idx += 256) {
        int o = idx / K, k = idx - o * K;
        Ws[o * (K + 1) + k] = W[idx];
    }
    if (row < M) {
        for (int k = lane; k < K; k += 64) Xs[r * K + k] = X[(long)row * K + k];
    } else {
        for (int k = lane; k < K; k += 64) Xs[r * K + k] = 0.f;
    }
    __syncthreads();

    float acc = bias ? bias[lane] : 0.f;
    const float* xrow = Xs + r * K;
    const float* wrow = Ws + lane * (K + 1);
#pragma unroll 8
    for (int k = 0; k < K; ++k) acc = fmaf(xrow[k], wrow[k], acc);
    if (doRelu) acc = fmaxf(acc, 0.f);
    if (out && row < M) out[(long)row * 64 + lane] = acc;

    int Fd = 64 / H;
    if (el) {
        float p = acc * al[lane];
        for (int off = 1; off < Fd; off <<= 1) p += __shfl_xor(p, off, 64);
        if ((lane & (Fd - 1)) == 0 && row < M) el[row * H + (lane / Fd)] = p;
    }
    if (er) {
        float p = acc * ar[lane];
        for (int off = 1; off < Fd; off <<= 1) p += __shfl_xor(p, off, 64);
        if ((lane & (Fd - 1)) == 0 && row < M) er[row * H + (lane / Fd)] = p;
    }
}

__global__ void init_bias_kernel(float* __restrict__ out, const float* __restrict__ b1,
                                 const float* __restrict__ b2, int N)
{
    long i = (long)blockIdx.x * blockDim.x + threadIdx.x;
    if (i >= (long)N * 64) return;
    int c = (int)(i & 63);
    out[i] = b1[c] + (b2 ? b2[c] : 0.f);
}

// ---------------- CSR build ----------------
__global__ void hist_kernel(const int* __restrict__ dst, int* __restrict__ cnt, int E)
{
    int i = blockIdx.x * blockDim.x + threadIdx.x;
    if (i < E) atomicAdd(&cnt[dst[i]], 1);
}

__global__ void scan_block_kernel(const int* __restrict__ cnt, int* __restrict__ offs,
                                  int* __restrict__ psum, int N)
{
    __shared__ int sm[256];
    int i = blockIdx.x * 256 + threadIdx.x;
    int v = (i < N) ? cnt[i] : 0;
    sm[threadIdx.x] = v;
    __syncthreads();
    for (int o = 1; o < 256; o <<= 1) {
        int t = (threadIdx.x >= o) ? sm[threadIdx.x - o] : 0;
        __syncthreads();
        sm[threadIdx.x] += t;
        __syncthreads();
    }
    if (i < N) offs[i] = sm[threadIdx.x] - v;   // exclusive
    if (threadIdx.x == 255) psum[blockIdx.x] = sm[255];
}

__global__ void scan_top_kernel(int* __restrict__ psum, int B)
{
    __shared__ int sm[512];
    int v = (threadIdx.x < B) ? psum[threadIdx.x] : 0;
    sm[threadIdx.x] = v;
    __syncthreads();
    for (int o = 1; o < 512; o <<= 1) {
        int t = (threadIdx.x >= (unsigned)o) ? sm[threadIdx.x - o] : 0;
        __syncthreads();
        sm[threadIdx.x] += t;
        __syncthreads();
    }
    if (threadIdx.x < B) psum[threadIdx.x] = sm[threadIdx.x] - v;  // exclusive
}

__global__ void add_back_kernel(int* __restrict__ offs, const int* __restrict__ psum,
                                int N, int E)
{
    int i = blockIdx.x * blockDim.x + threadIdx.x;
    if (i < N) offs[i] += psum[i >> 8];
    if (i == 0) offs[N] = E;
}

__global__ void fill_kernel(const int* __restrict__ src, const int* __restrict__ dst,
                            int* __restrict__ cursor, int* __restrict__ csr, int E)
{
    int i = blockIdx.x * blockDim.x + threadIdx.x;
    if (i >= E) return;
    int pos = atomicAdd(&cursor[dst[i]], 1);
    csr[pos] = src[i];
}

// ---------------- fused GAT aggregation (gather, one wave per dst node) ----------------
__global__ void gat_csr_kernel(const int* __restrict__ offs, const int* __restrict__ csr,
                               const float* __restrict__ el, const float* __restrict__ er,
                               const float* __restrict__ Fsrc, float* __restrict__ rst,
                               int Nd, int hshift)
{
    int d = (blockIdx.x << 2) | (threadIdx.x >> 6);
    int lane = threadIdx.x & 63;
    if (d >= Nd) return;
    int H = 1 << hshift;
    int off = offs[d];
    int n = offs[d + 1] - off;

    // pass A: online softmax (max + sum of exp) per head, lanes strided over edges
    int h = lane & (H - 1);
    float erd = er[d * H + h];
    float m = -INFINITY, ssum = 0.f;
    int estep = 64 >> hshift;
    for (int i = lane >> hshift; i < n; i += estep) {
        int sn = csr[off + i];
        float v = el[sn * H + h] + erd;
        v = v > 0.f ? v : 0.2f * v;
        if (v > m) { ssum = ssum * __expf(m - v) + 1.f; m = v; }
        else       { ssum += __expf(v - m); }
    }
    for (int o = H; o < 64; o <<= 1) {
        float om = __shfl_xor(m, o, 64);
        float os = __shfl_xor(ssum, o, 64);
        float nm = fmaxf(m, om);
        float e1 = (m == nm) ? 1.f : __expf(m - nm);
        float e2 = (om == nm) ? 1.f : __expf(om - nm);
        ssum = ssum * e1 + os * e2;
        m = nm;
    }

    // redistribute per-feature: lane = output feature, its head = lane >> (6-hshift)
    int hf = lane >> (6 - hshift);
    float m_f = __shfl(m, hf, 64);
    float s_f = __shfl(ssum, hf, 64);
    float er_f = __shfl(erd, hf, 64);
    float rinv = 1.f / s_f;

    // pass B: weighted gather-accumulate
    float acc = 0.f;
    for (int base = 0; base < n; base += 64) {
        int sreg = (base + lane < n) ? csr[off + base + lane] : 0;
        int cnt = min(64, n - base);
        for (int j = 0; j < cnt; ++j) {
            int sn = __shfl(sreg, j, 64);
            float v = el[sn * H + hf] + er_f;
            v = v > 0.f ? v : 0.2f * v;
            float a = __expf(v - m_f) * rinv;
            acc = fmaf(Fsrc[(long)sn * 64 + lane], a, acc);
        }
    }
    rst[(long)d * 64 + lane] += acc;
}

__global__ void l2norm_kernel(const float* __restrict__ in, float* __restrict__ out, int N)
{
    long gt = (long)blockIdx.x * blockDim.x + threadIdx.x;
    int row = (int)(gt >> 6);
    int lane = threadIdx.x & 63;
    if (row >= N) return;
    float v = in[(long)row * 64 + lane];
    float ss = v * v;
    for (int off = 1; off < 64; off <<= 1) ss += __shfl_xor(ss, off, 64);
    out[(long)row * 64 + lane] = v / fmaxf(sqrtf(ss), 1e-12f);
}

// ---------------- host-side helpers ----------------
static void build_csr(const int* src, const int* dst, int E, int N,
                      int* offs, int* cnt, int* psum, int* csr, hipStream_t stream)
{
    hipMemsetAsync(cnt, 0, (size_t)N * sizeof(int), stream);
    hist_kernel<<<(E + 255) / 256, 256, 0, stream>>>(dst, cnt, E);
    int B = (N + 255) / 256;
    scan_block_kernel<<<B, 256, 0, stream>>>(cnt, offs, psum, N);
    scan_top_kernel<<<1, 512, 0, stream>>>(psum, B);
    add_back_kernel<<<(N + 255) / 256, 256, 0, stream>>>(offs, psum, N, E);
    hipMemcpyAsync(cnt, offs, (size_t)N * sizeof(int), hipMemcpyDeviceToDevice, stream);
    fill_kernel<<<(E + 255) / 256, 256, 0, stream>>>(src, dst, cnt, csr, E);
}

static void run_gat(const float* h_src, const float* h_dst, int Ns, int Nd,
                    const int* offs, const int* csr,
                    const float* W, const float* al, const float* ar,
                    float* Psrc, float* el, float* er, float* rst, int H, hipStream_t stream)
{
    size_t shmem = (64 * 65 + 4 * 64) * sizeof(float);
    if (h_src == h_dst) {
        gemm_kernel<<<(Ns + 3) / 4, 256, shmem, stream>>>(h_src, W, nullptr, Psrc,
                                                          al, el, ar, er, Ns, 64, H, 0);
    } else {
        gemm_kernel<<<(Ns + 3) / 4, 256, shmem, stream>>>(h_src, W, nullptr, Psrc,
                                                          al, el, nullptr, nullptr, Ns, 64, H, 0);
        gemm_kernel<<<(Nd + 3) / 4, 256, shmem, stream>>>(h_dst, W, nullptr, nullptr,
                                                          nullptr, nullptr, ar, er, Nd, 64, H, 0);
    }
    int hshift = (H == 4) ? 2 : 0;
    gat_csr_kernel<<<(Nd + 3) / 4, 256, 0, stream>>>(offs, csr, el, er, Psrc, rst, Nd, hshift);
}

extern "C" void kernel_launch(void* const* d_in, const int* in_sizes, int n_in,
                              void* d_out, int out_size, void* d_ws, size_t ws_size,
                              hipStream_t stream)
{
    const float* feat_a = (const float*)d_in[0];
    const float* feat_p = (const float*)d_in[1];
    const float* fmWa = (const float*)d_in[2];
    const float* fmba = (const float*)d_in[3];
    const float* fmWp = (const float*)d_in[4];
    const float* fmbp = (const float*)d_in[5];
    const float* g1w_W = (const float*)d_in[6];  const float* g1w_al = (const float*)d_in[7];
    const float* g1w_ar = (const float*)d_in[8]; const float* g1w_b = (const float*)d_in[9];
    const float* g2w_W = (const float*)d_in[10]; const float* g2w_al = (const float*)d_in[11];
    const float* g2w_ar = (const float*)d_in[12]; const float* g2w_b = (const float*)d_in[13];
    const float* g1wb_W = (const float*)d_in[14]; const float* g1wb_al = (const float*)d_in[15];
    const float* g1wb_ar = (const float*)d_in[16]; const float* g1wb_b = (const float*)d_in[17];
    const float* g2wb_W = (const float*)d_in[18]; const float* g2wb_al = (const float*)d_in[19];
    const float* g2wb_ar = (const float*)d_in[20]; const float* g2wb_b = (const float*)d_in[21];
    const float* g1c_W = (const float*)d_in[22]; const float* g1c_al = (const float*)d_in[23];
    const float* g1c_ar = (const float*)d_in[24]; const float* g1c_b = (const float*)d_in[25];
    const float* g2c_W = (const float*)d_in[26]; const float* g2c_al = (const float*)d_in[27];
    const float* g2c_ar = (const float*)d_in[28]; const float* g2c_b = (const float*)d_in[29];
    const int* w_src = (const int*)d_in[30];
    const int* w_dst = (const int*)d_in[31];
    const int* wb_src = (const int*)d_in[32];
    const int* wb_dst = (const int*)d_in[33];
    const int* c_src = (const int*)d_in[34];
    const int* c_dst = (const int*)d_in[35];

    float* ws = (float*)d_ws;
    size_t off = 0;
    auto alloc = [&](size_t n) { float* p = ws + off; off += n; return p; };
    float* h_a  = alloc(HA);
    float* h_p  = alloc(HP);
    float* Pa   = alloc(HP);
    float* h1_p = alloc(HP);
    float* h1_a = alloc(HA);
    float* elb  = alloc((size_t)N_P * 4);
    float* erb  = alloc((size_t)N_P * 4);
    int* w_offs  = (int*)alloc(N_P + 1);
    int* c_offs  = (int*)alloc(N_P + 1);
    int* wb_offs = (int*)alloc(N_A + 1);
    int* cnt     = (int*)alloc(N_P);
    int* psum    = (int*)alloc(512);
    int* w_csr   = (int*)alloc(E_W);
    int* wb_csr  = (int*)alloc(E_W);
    int* c_csr   = (int*)alloc(E_C);
    float* h2_p = h_p;   // reuse: dead after layer-1 projections
    float* h2_a = h_a;

    // CSRs (shared across both layers)
    build_csr(w_src, w_dst, E_W, N_P, w_offs, cnt, psum, w_csr, stream);
    build_csr(c_src, c_dst, E_C, N_P, c_offs, cnt, psum, c_csr, stream);
    build_csr(wb_src, wb_dst, E_W, N_A, wb_offs, cnt, psum, wb_csr, stream);

    // Feature mapping: relu(X @ W^T + b)
    {
        size_t sh128 = (64 * 129 + 4 * 128) * sizeof(float);
        size_t sh256 = (64 * 257 + 4 * 256) * sizeof(float);
        gemm_kernel<<<(N_A + 3) / 4, 256, sh128, stream>>>(feat_a, fmWa, fmba, h_a,
            nullptr, nullptr, nullptr, nullptr, N_A, 128, 4, 1);
        gemm_kernel<<<(N_P + 3) / 4, 256, sh256, stream>>>(feat_p, fmWp, fmbp, h_p,
            nullptr, nullptr, nullptr, nullptr, N_P, 256, 4, 1);
    }

    // ---- Layer 1 (H=4) ----
    init_bias_kernel<<<((long)N_P * 64 + 255) / 256, 256, 0, stream>>>(h1_p, g1w_b, g1c_b, N_P);
    init_bias_kernel<<<((long)N_A * 64 + 255) / 256, 256, 0, stream>>>(h1_a, g1wb_b, nullptr, N_A);
    run_gat(h_a, h_p, N_A, N_P, w_offs, w_csr, g1w_W, g1w_al, g1w_ar,
            Pa, elb, erb, h1_p, 4, stream);
    run_gat(h_p, h_p, N_P, N_P, c_offs, c_csr, g1c_W, g1c_al, g1c_ar,
            Pa, elb, erb, h1_p, 4, stream);
    run_gat(h_p, h_a, N_P, N_A, wb_offs, wb_csr, g1wb_W, g1wb_al, g1wb_ar,
            Pa, elb, erb, h1_a, 4, stream);

    // ---- Layer 2 (H=1) ----
    init_bias_kernel<<<((long)N_P * 64 + 255) / 256, 256, 0, stream>>>(h2_p, g2w_b, g2c_b, N_P);
    init_bias_kernel<<<((long)N_A * 64 + 255) / 256, 256, 0, stream>>>(h2_a, g2wb_b, nullptr, N_A);
    run_gat(h1_a, h1_p, N_A, N_P, w_offs, w_csr, g2w_W, g2w_al, g2w_ar,
            Pa, elb, erb, h2_p, 1, stream);
    run_gat(h1_p, h1_p, N_P, N_P, c_offs, c_csr, g2c_W, g2c_al, g2c_ar,
            Pa, elb, erb, h2_p, 1, stream);
    run_gat(h1_p, h1_a, N_P, N_A, wb_offs, wb_csr, g2wb_W, g2wb_al, g2wb_ar,
            Pa, elb, erb, h2_a, 1, stream);

    // ---- L2 normalize: authors first, then papers ----
    float* out = (float*)d_out;
    l2norm_kernel<<<((long)N_A * 64 + 255) / 256, 256, 0, stream>>>(h2_a, out, N_A);
    l2norm_kernel<<<((long)N_P * 64 + 255) / 256, 256, 0, stream>>>(h2_p, out + HA, N_P);
}

// Round 3
// 2371.243 us; speedup vs baseline: 2.2703x; 1.2638x over previous
//
#include <hip/hip_runtime.h>

#define N_A 50000
#define N_P 100000
#define E_W 1600000
#define E_C 3200000
#define HA (N_A*64)
#define HP (N_P*64)

// ---------------- tiled fp32 GEMM: out[M,64] = act(X[M,K] @ W^T + b) ----------------
// BM=128, BN=64(full), BK=32; 256 threads; 8x4 micro-tile; K must be multiple of 32.
__global__ __launch_bounds__(256) void gemm_tiled(const float* __restrict__ X,
        const float* __restrict__ W, const float* __restrict__ bias,
        float* __restrict__ out, int M, int K, int doRelu)
{
    __shared__ float Xs[32 * 132];   // [k][row], stride 132 (conflict-free, 16B-aligned)
    __shared__ float Wsh[32 * 68];   // [k][n],   stride 68
    int tid = threadIdx.x;
    int bm0 = blockIdx.x * 128;
    int tx = tid & 15, ty = tid >> 4;

    float acc[8][4];
#pragma unroll
    for (int i = 0; i < 8; ++i)
#pragma unroll
        for (int j = 0; j < 4; ++j) acc[i][j] = 0.f;

    for (int k0 = 0; k0 < K; k0 += 32) {
        // stage X tile transposed: Xs[k][row]
#pragma unroll
        for (int it = 0; it < 4; ++it) {
            int row = (tid & 31) + 32 * it;
            int chunk = tid >> 5;                       // 0..7
            int rg = bm0 + row; rg = rg < M ? rg : M - 1;
            const float4 v = *reinterpret_cast<const float4*>(&X[(long)rg * K + k0 + chunk * 4]);
            int kb = chunk * 4;
            Xs[(kb + 0) * 132 + row] = v.x;
            Xs[(kb + 1) * 132 + row] = v.y;
            Xs[(kb + 2) * 132 + row] = v.z;
            Xs[(kb + 3) * 132 + row] = v.w;
        }
        // stage W tile transposed: Wsh[k][n]
#pragma unroll
        for (int it = 0; it < 2; ++it) {
            int n = tid & 63;
            int chunk = (tid >> 6) + 4 * it;            // 0..7
            const float4 v = *reinterpret_cast<const float4*>(&W[(long)n * K + k0 + chunk * 4]);
            int kb = chunk * 4;
            Wsh[(kb + 0) * 68 + n] = v.x;
            Wsh[(kb + 1) * 68 + n] = v.y;
            Wsh[(kb + 2) * 68 + n] = v.z;
            Wsh[(kb + 3) * 68 + n] = v.w;
        }
        __syncthreads();
#pragma unroll
        for (int k = 0; k < 32; ++k) {
            float4 a0 = *reinterpret_cast<const float4*>(&Xs[k * 132 + ty * 8]);
            float4 a1 = *reinterpret_cast<const float4*>(&Xs[k * 132 + ty * 8 + 4]);
            float4 b  = *reinterpret_cast<const float4*>(&Wsh[k * 68 + tx * 4]);
            float av[8] = {a0.x, a0.y, a0.z, a0.w, a1.x, a1.y, a1.z, a1.w};
            float bv[4] = {b.x, b.y, b.z, b.w};
#pragma unroll
            for (int i = 0; i < 8; ++i)
#pragma unroll
                for (int j = 0; j < 4; ++j)
                    acc[i][j] = fmaf(av[i], bv[j], acc[i][j]);
        }
        __syncthreads();
    }

    float bj[4] = {0.f, 0.f, 0.f, 0.f};
    if (bias) {
        bj[0] = bias[tx * 4 + 0]; bj[1] = bias[tx * 4 + 1];
        bj[2] = bias[tx * 4 + 2]; bj[3] = bias[tx * 4 + 3];
    }
#pragma unroll
    for (int i = 0; i < 8; ++i) {
        int r = bm0 + ty * 8 + i;
        if (r < M) {
            float4 o;
            o.x = acc[i][0] + bj[0]; o.y = acc[i][1] + bj[1];
            o.z = acc[i][2] + bj[2]; o.w = acc[i][3] + bj[3];
            if (doRelu) {
                o.x = fmaxf(o.x, 0.f); o.y = fmaxf(o.y, 0.f);
                o.z = fmaxf(o.z, 0.f); o.w = fmaxf(o.w, 0.f);
            }
            *reinterpret_cast<float4*>(&out[(long)r * 64 + tx * 4]) = o;
        }
    }
}

// ---------------- attention vector folding ----------------
// wal[k][h] = sum_f W[h*F+f][k]*al[h][f];  war likewise. One block of 64 threads.
__global__ void prep_attn_kernel(const float* __restrict__ W, const float* __restrict__ al,
                                 const float* __restrict__ ar, float* __restrict__ wal,
                                 float* __restrict__ war, int H)
{
    int k = threadIdx.x;   // 0..63
    int F = 64 / H;
    for (int hh = 0; hh < H; ++hh) {
        float sl = 0.f, sr = 0.f;
        for (int f = 0; f < F; ++f) {
            float w = W[(hh * F + f) * 64 + k];
            sl = fmaf(w, al[hh * F + f], sl);
            sr = fmaf(w, ar[hh * F + f], sr);
        }
        wal[k * H + hh] = sl;
        war[k * H + hh] = sr;
    }
}

// el[i][h] = h_row . wal[:,h] ; er likewise. One wave per node.
__global__ void attnvec_kernel(const float* __restrict__ h,
                               const float* __restrict__ wal, const float* __restrict__ war,
                               float* __restrict__ el, float* __restrict__ er, int N, int H)
{
    int node = (blockIdx.x << 2) | (threadIdx.x >> 6);
    int lane = threadIdx.x & 63;
    if (node >= N) return;
    float v = h[(long)node * 64 + lane];
    for (int hh = 0; hh < H; ++hh) {
        if (el) {
            float p = v * wal[lane * H + hh];
            for (int o = 1; o < 64; o <<= 1) p += __shfl_xor(p, o, 64);
            if (lane == hh) el[node * H + hh] = p;
        }
        if (er) {
            float p = v * war[lane * H + hh];
            for (int o = 1; o < 64; o <<= 1) p += __shfl_xor(p, o, 64);
            if (lane == hh) er[node * H + hh] = p;
        }
    }
}

__global__ void init_bias_kernel(float* __restrict__ out, const float* __restrict__ b1,
                                 const float* __restrict__ b2, int N)
{
    long i = (long)blockIdx.x * blockDim.x + threadIdx.x;
    if (i >= (long)N * 64) return;
    int c = (int)(i & 63);
    out[i] = b1[c] + (b2 ? b2[c] : 0.f);
}

// ---------------- CSR build ----------------
__global__ void hist_kernel(const int* __restrict__ dst, int* __restrict__ cnt, int E)
{
    int i = blockIdx.x * blockDim.x + threadIdx.x;
    if (i < E) atomicAdd(&cnt[dst[i]], 1);
}

__global__ void scan_block_kernel(const int* __restrict__ cnt, int* __restrict__ offs,
                                  int* __restrict__ psum, int N)
{
    __shared__ int sm[256];
    int i = blockIdx.x * 256 + threadIdx.x;
    int v = (i < N) ? cnt[i] : 0;
    sm[threadIdx.x] = v;
    __syncthreads();
    for (int o = 1; o < 256; o <<= 1) {
        int t = (threadIdx.x >= o) ? sm[threadIdx.x - o] : 0;
        __syncthreads();
        sm[threadIdx.x] += t;
        __syncthreads();
    }
    if (i < N) offs[i] = sm[threadIdx.x] - v;   // exclusive
    if (threadIdx.x == 255) psum[blockIdx.x] = sm[255];
}

__global__ void scan_top_kernel(int* __restrict__ psum, int B)
{
    __shared__ int sm[512];
    int v = (threadIdx.x < B) ? psum[threadIdx.x] : 0;
    sm[threadIdx.x] = v;
    __syncthreads();
    for (int o = 1; o < 512; o <<= 1) {
        int t = (threadIdx.x >= (unsigned)o) ? sm[threadIdx.x - o] : 0;
        __syncthreads();
        sm[threadIdx.x] += t;
        __syncthreads();
    }
    if (threadIdx.x < B) psum[threadIdx.x] = sm[threadIdx.x] - v;  // exclusive
}

__global__ void add_back_kernel(int* __restrict__ offs, const int* __restrict__ psum,
                                int N, int E)
{
    int i = blockIdx.x * blockDim.x + threadIdx.x;
    if (i < N) offs[i] += psum[i >> 8];
    if (i == 0) offs[N] = E;
}

__global__ void fill_kernel(const int* __restrict__ src, const int* __restrict__ dst,
                            int* __restrict__ cursor, int* __restrict__ csr, int E)
{
    int i = blockIdx.x * blockDim.x + threadIdx.x;
    if (i >= E) return;
    int pos = atomicAdd(&cursor[dst[i]], 1);
    csr[pos] = src[i];
}

// ---------------- fused GAT aggregation (gather, one wave per dst node) ----------------
__global__ void gat_csr_kernel(const int* __restrict__ offs, const int* __restrict__ csr,
                               const float* __restrict__ el, const float* __restrict__ er,
                               const float* __restrict__ Fsrc, float* __restrict__ rst,
                               int Nd, int hshift)
{
    int d = (blockIdx.x << 2) | (threadIdx.x >> 6);
    int lane = threadIdx.x & 63;
    if (d >= Nd) return;
    int H = 1 << hshift;
    int off = offs[d];
    int n = offs[d + 1] - off;

    // pass A: online softmax (max + sum of exp) per head, lanes strided over edges
    int h = lane & (H - 1);
    float erd = er[d * H + h];
    float m = -INFINITY, ssum = 0.f;
    int estep = 64 >> hshift;
    for (int i = lane >> hshift; i < n; i += estep) {
        int sn = csr[off + i];
        float v = el[sn * H + h] + erd;
        v = v > 0.f ? v : 0.2f * v;
        if (v > m) { ssum = ssum * __expf(m - v) + 1.f; m = v; }
        else       { ssum += __expf(v - m); }
    }
    for (int o = H; o < 64; o <<= 1) {
        float om = __shfl_xor(m, o, 64);
        float os = __shfl_xor(ssum, o, 64);
        float nm = fmaxf(m, om);
        float e1 = (m == nm) ? 1.f : __expf(m - nm);
        float e2 = (om == nm) ? 1.f : __expf(om - nm);
        ssum = ssum * e1 + os * e2;
        m = nm;
    }

    // redistribute per-feature: lane = output feature, its head = lane >> (6-hshift)
    int hf = lane >> (6 - hshift);
    float m_f = __shfl(m, hf, 64);
    float s_f = __shfl(ssum, hf, 64);
    float er_f = __shfl(erd, hf, 64);
    float rinv = 1.f / s_f;

    // pass B: weighted gather-accumulate
    float acc = 0.f;
    for (int base = 0; base < n; base += 64) {
        int sreg = (base + lane < n) ? csr[off + base + lane] : 0;
        int cnt = min(64, n - base);
        for (int j = 0; j < cnt; ++j) {
            int sn = __shfl(sreg, j, 64);
            float v = el[sn * H + hf] + er_f;
            v = v > 0.f ? v : 0.2f * v;
            float a = __expf(v - m_f) * rinv;
            acc = fmaf(Fsrc[(long)sn * 64 + lane], a, acc);
        }
    }
    rst[(long)d * 64 + lane] += acc;
}

__global__ void l2norm_kernel(const float* __restrict__ in, float* __restrict__ out, int N)
{
    long gt = (long)blockIdx.x * blockDim.x + threadIdx.x;
    int row = (int)(gt >> 6);
    int lane = threadIdx.x & 63;
    if (row >= N) return;
    float v = in[(long)row * 64 + lane];
    float ss = v * v;
    for (int off = 1; off < 64; off <<= 1) ss += __shfl_xor(ss, off, 64);
    out[(long)row * 64 + lane] = v / fmaxf(sqrtf(ss), 1e-12f);
}

// ---------------- host-side helpers ----------------
static void build_csr(const int* src, const int* dst, int E, int N,
                      int* offs, int* cnt, int* psum, int* csr, hipStream_t stream)
{
    hipMemsetAsync(cnt, 0, (size_t)N * sizeof(int), stream);
    hist_kernel<<<(E + 255) / 256, 256, 0, stream>>>(dst, cnt, E);
    int B = (N + 255) / 256;
    scan_block_kernel<<<B, 256, 0, stream>>>(cnt, offs, psum, N);
    scan_top_kernel<<<1, 512, 0, stream>>>(psum, B);
    add_back_kernel<<<(N + 255) / 256, 256, 0, stream>>>(offs, psum, N, E);
    hipMemcpyAsync(cnt, offs, (size_t)N * sizeof(int), hipMemcpyDeviceToDevice, stream);
    fill_kernel<<<(E + 255) / 256, 256, 0, stream>>>(src, dst, cnt, csr, E);
}

static void run_gat(const float* h_src, const float* h_dst, int Ns, int Nd,
                    const int* offs, const int* csr,
                    const float* W, const float* al, const float* ar,
                    float* Psrc, float* wal, float* war,
                    float* el, float* er, float* rst, int H, hipStream_t stream)
{
    prep_attn_kernel<<<1, 64, 0, stream>>>(W, al, ar, wal, war, H);
    gemm_tiled<<<(Ns + 127) / 128, 256, 0, stream>>>(h_src, W, nullptr, Psrc, Ns, 64, 0);
    if (h_src == h_dst) {
        attnvec_kernel<<<(Ns + 3) / 4, 256, 0, stream>>>(h_src, wal, war, el, er, Ns, H);
    } else {
        attnvec_kernel<<<(Ns + 3) / 4, 256, 0, stream>>>(h_src, wal, nullptr, el, nullptr, Ns, H);
        attnvec_kernel<<<(Nd + 3) / 4, 256, 0, stream>>>(h_dst, nullptr, war, nullptr, er, Nd, H);
    }
    int hshift = (H == 4) ? 2 : 0;
    gat_csr_kernel<<<(Nd + 3) / 4, 256, 0, stream>>>(offs, csr, el, er, Psrc, rst, Nd, hshift);
}

extern "C" void kernel_launch(void* const* d_in, const int* in_sizes, int n_in,
                              void* d_out, int out_size, void* d_ws, size_t ws_size,
                              hipStream_t stream)
{
    const float* feat_a = (const float*)d_in[0];
    const float* feat_p = (const float*)d_in[1];
    const float* fmWa = (const float*)d_in[2];
    const float* fmba = (const float*)d_in[3];
    const float* fmWp = (const float*)d_in[4];
    const float* fmbp = (const float*)d_in[5];
    const float* g1w_W = (const float*)d_in[6];  const float* g1w_al = (const float*)d_in[7];
    const float* g1w_ar = (const float*)d_in[8]; const float* g1w_b = (const float*)d_in[9];
    const float* g2w_W = (const float*)d_in[10]; const float* g2w_al = (const float*)d_in[11];
    const float* g2w_ar = (const float*)d_in[12]; const float* g2w_b = (const float*)d_in[13];
    const float* g1wb_W = (const float*)d_in[14]; const float* g1wb_al = (const float*)d_in[15];
    const float* g1wb_ar = (const float*)d_in[16]; const float* g1wb_b = (const float*)d_in[17];
    const float* g2wb_W = (const float*)d_in[18]; const float* g2wb_al = (const float*)d_in[19];
    const float* g2wb_ar = (const float*)d_in[20]; const float* g2wb_b = (const float*)d_in[21];
    const float* g1c_W = (const float*)d_in[22]; const float* g1c_al = (const float*)d_in[23];
    const float* g1c_ar = (const float*)d_in[24]; const float* g1c_b = (const float*)d_in[25];
    const float* g2c_W = (const float*)d_in[26]; const float* g2c_al = (const float*)d_in[27];
    const float* g2c_ar = (const float*)d_in[28]; const float* g2c_b = (const float*)d_in[29];
    const int* w_src = (const int*)d_in[30];
    const int* w_dst = (const int*)d_in[31];
    const int* wb_src = (const int*)d_in[32];
    const int* wb_dst = (const int*)d_in[33];
    const int* c_src = (const int*)d_in[34];
    const int* c_dst = (const int*)d_in[35];

    float* ws = (float*)d_ws;
    size_t off = 0;
    auto alloc = [&](size_t n) { float* p = ws + off; off += n; return p; };
    float* h_a  = alloc(HA);
    float* h_p  = alloc(HP);
    float* Pa   = alloc(HP);
    float* h1_p = alloc(HP);
    float* h1_a = alloc(HA);
    float* elb  = alloc((size_t)N_P * 4);
    float* erb  = alloc((size_t)N_P * 4);
    float* wal  = alloc(256);
    float* war  = alloc(256);
    int* w_offs  = (int*)alloc(N_P + 1);
    int* c_offs  = (int*)alloc(N_P + 1);
    int* wb_offs = (int*)alloc(N_A + 1);
    int* cnt     = (int*)alloc(N_P);
    int* psum    = (int*)alloc(512);
    int* w_csr   = (int*)alloc(E_W);
    int* wb_csr  = (int*)alloc(E_W);
    int* c_csr   = (int*)alloc(E_C);
    float* h2_p = h_p;   // reuse: dead after layer-1 projections
    float* h2_a = h_a;

    // CSRs (shared across both layers)
    build_csr(w_src, w_dst, E_W, N_P, w_offs, cnt, psum, w_csr, stream);
    build_csr(c_src, c_dst, E_C, N_P, c_offs, cnt, psum, c_csr, stream);
    build_csr(wb_src, wb_dst, E_W, N_A, wb_offs, cnt, psum, wb_csr, stream);

    // Feature mapping: relu(X @ W^T + b)
    gemm_tiled<<<(N_A + 127) / 128, 256, 0, stream>>>(feat_a, fmWa, fmba, h_a, N_A, 128, 1);
    gemm_tiled<<<(N_P + 127) / 128, 256, 0, stream>>>(feat_p, fmWp, fmbp, h_p, N_P, 256, 1);

    // ---- Layer 1 (H=4) ----
    init_bias_kernel<<<((long)N_P * 64 + 255) / 256, 256, 0, stream>>>(h1_p, g1w_b, g1c_b, N_P);
    init_bias_kernel<<<((long)N_A * 64 + 255) / 256, 256, 0, stream>>>(h1_a, g1wb_b, nullptr, N_A);
    run_gat(h_a, h_p, N_A, N_P, w_offs, w_csr, g1w_W, g1w_al, g1w_ar,
            Pa, wal, war, elb, erb, h1_p, 4, stream);
    run_gat(h_p, h_p, N_P, N_P, c_offs, c_csr, g1c_W, g1c_al, g1c_ar,
            Pa, wal, war, elb, erb, h1_p, 4, stream);
    run_gat(h_p, h_a, N_P, N_A, wb_offs, wb_csr, g1wb_W, g1wb_al, g1wb_ar,
            Pa, wal, war, elb, erb, h1_a, 4, stream);

    // ---- Layer 2 (H=1) ----
    init_bias_kernel<<<((long)N_P * 64 + 255) / 256, 256, 0, stream>>>(h2_p, g2w_b, g2c_b, N_P);
    init_bias_kernel<<<((long)N_A * 64 + 255) / 256, 256, 0, stream>>>(h2_a, g2wb_b, nullptr, N_A);
    run_gat(h1_a, h1_p, N_A, N_P, w_offs, w_csr, g2w_W, g2w_al, g2w_ar,
            Pa, wal, war, elb, erb, h2_p, 1, stream);
    run_gat(h1_p, h1_p, N_P, N_P, c_offs, c_csr, g2c_W, g2c_al, g2c_ar,
            Pa, wal, war, elb, erb, h2_p, 1, stream);
    run_gat(h1_p, h1_a, N_P, N_A, wb_offs, wb_csr, g2wb_W, g2wb_al, g2wb_ar,
            Pa, wal, war, elb, erb, h2_a, 1, stream);

    // ---- L2 normalize: authors first, then papers ----
    float* out = (float*)d_out;
    l2norm_kernel<<<((long)N_A * 64 + 255) / 256, 256, 0, stream>>>(h2_a, out, N_A);
    l2norm_kernel<<<((long)N_P * 64 + 255) / 256, 256, 0, stream>>>(h2_p, out + HA, N_P);
}

// Round 4
// 1911.009 us; speedup vs baseline: 2.8170x; 1.2408x over previous
//
#include <hip/hip_runtime.h>

#define N_A 50000
#define N_P 100000
#define E_W 1600000
#define E_C 3200000
#define HA (N_A*64)
#define HP (N_P*64)

// ---------------- tiled fp32 GEMM: out[M,64] = act(X[M,K] @ W^T + b) ----------------
__global__ __launch_bounds__(256) void gemm_tiled(const float* __restrict__ X,
        const float* __restrict__ W, const float* __restrict__ bias,
        float* __restrict__ out, int M, int K, int doRelu)
{
    __shared__ float Xs[32 * 132];
    __shared__ float Wsh[32 * 68];
    int tid = threadIdx.x;
    int bm0 = blockIdx.x * 128;
    int tx = tid & 15, ty = tid >> 4;

    float acc[8][4];
#pragma unroll
    for (int i = 0; i < 8; ++i)
#pragma unroll
        for (int j = 0; j < 4; ++j) acc[i][j] = 0.f;

    for (int k0 = 0; k0 < K; k0 += 32) {
#pragma unroll
        for (int it = 0; it < 4; ++it) {
            int row = (tid & 31) + 32 * it;
            int chunk = tid >> 5;
            int rg = bm0 + row; rg = rg < M ? rg : M - 1;
            const float4 v = *reinterpret_cast<const float4*>(&X[(long)rg * K + k0 + chunk * 4]);
            int kb = chunk * 4;
            Xs[(kb + 0) * 132 + row] = v.x;
            Xs[(kb + 1) * 132 + row] = v.y;
            Xs[(kb + 2) * 132 + row] = v.z;
            Xs[(kb + 3) * 132 + row] = v.w;
        }
#pragma unroll
        for (int it = 0; it < 2; ++it) {
            int n = tid & 63;
            int chunk = (tid >> 6) + 4 * it;
            const float4 v = *reinterpret_cast<const float4*>(&W[(long)n * K + k0 + chunk * 4]);
            int kb = chunk * 4;
            Wsh[(kb + 0) * 68 + n] = v.x;
            Wsh[(kb + 1) * 68 + n] = v.y;
            Wsh[(kb + 2) * 68 + n] = v.z;
            Wsh[(kb + 3) * 68 + n] = v.w;
        }
        __syncthreads();
#pragma unroll
        for (int k = 0; k < 32; ++k) {
            float4 a0 = *reinterpret_cast<const float4*>(&Xs[k * 132 + ty * 8]);
            float4 a1 = *reinterpret_cast<const float4*>(&Xs[k * 132 + ty * 8 + 4]);
            float4 b  = *reinterpret_cast<const float4*>(&Wsh[k * 68 + tx * 4]);
            float av[8] = {a0.x, a0.y, a0.z, a0.w, a1.x, a1.y, a1.z, a1.w};
            float bv[4] = {b.x, b.y, b.z, b.w};
#pragma unroll
            for (int i = 0; i < 8; ++i)
#pragma unroll
                for (int j = 0; j < 4; ++j)
                    acc[i][j] = fmaf(av[i], bv[j], acc[i][j]);
        }
        __syncthreads();
    }

    float bj[4] = {0.f, 0.f, 0.f, 0.f};
    if (bias) {
        bj[0] = bias[tx * 4 + 0]; bj[1] = bias[tx * 4 + 1];
        bj[2] = bias[tx * 4 + 2]; bj[3] = bias[tx * 4 + 3];
    }
#pragma unroll
    for (int i = 0; i < 8; ++i) {
        int r = bm0 + ty * 8 + i;
        if (r < M) {
            float4 o;
            o.x = acc[i][0] + bj[0]; o.y = acc[i][1] + bj[1];
            o.z = acc[i][2] + bj[2]; o.w = acc[i][3] + bj[3];
            if (doRelu) {
                o.x = fmaxf(o.x, 0.f); o.y = fmaxf(o.y, 0.f);
                o.z = fmaxf(o.z, 0.f); o.w = fmaxf(o.w, 0.f);
            }
            *reinterpret_cast<float4*>(&out[(long)r * 64 + tx * 4]) = o;
        }
    }
}

// ---------------- attention vector folding ----------------
__global__ void prep_attn_kernel(const float* __restrict__ W, const float* __restrict__ al,
                                 const float* __restrict__ ar, float* __restrict__ wal,
                                 float* __restrict__ war, int H)
{
    int k = threadIdx.x;
    int F = 64 / H;
    for (int hh = 0; hh < H; ++hh) {
        float sl = 0.f, sr = 0.f;
        for (int f = 0; f < F; ++f) {
            float w = W[(hh * F + f) * 64 + k];
            sl = fmaf(w, al[hh * F + f], sl);
            sr = fmaf(w, ar[hh * F + f], sr);
        }
        wal[k * H + hh] = sl;
        war[k * H + hh] = sr;
    }
}

__global__ void attnvec_kernel(const float* __restrict__ h,
                               const float* __restrict__ wal, const float* __restrict__ war,
                               float* __restrict__ el, float* __restrict__ er, int N, int H)
{
    int node = (blockIdx.x << 2) | (threadIdx.x >> 6);
    int lane = threadIdx.x & 63;
    if (node >= N) return;
    float v = h[(long)node * 64 + lane];
    for (int hh = 0; hh < H; ++hh) {
        if (el) {
            float p = v * wal[lane * H + hh];
            for (int o = 1; o < 64; o <<= 1) p += __shfl_xor(p, o, 64);
            if (lane == hh) el[node * H + hh] = p;
        }
        if (er) {
            float p = v * war[lane * H + hh];
            for (int o = 1; o < 64; o <<= 1) p += __shfl_xor(p, o, 64);
            if (lane == hh) er[node * H + hh] = p;
        }
    }
}

__global__ void init_bias_kernel(float* __restrict__ out, const float* __restrict__ b1,
                                 const float* __restrict__ b2, int N)
{
    long i = (long)blockIdx.x * blockDim.x + threadIdx.x;
    if (i >= (long)N * 64) return;
    int c = (int)(i & 63);
    out[i] = b1[c] + (b2 ? b2[c] : 0.f);
}

// ---------------- CSR build v2: locality-aware bucket sort ----------------
// bucket = dst >> 9 (512 nodes per bucket), NB <= 196.

__global__ void bucket_hist(const int* __restrict__ dst, int* __restrict__ bcnt,
                            int E, int NB, int shift)
{
    __shared__ int h[256];
    int tid = threadIdx.x;
    for (int i = tid; i < NB; i += 256) h[i] = 0;
    __syncthreads();
    for (long i = (long)blockIdx.x * 256 + tid; i < E; i += (long)gridDim.x * 256)
        atomicAdd(&h[dst[i] >> shift], 1);
    __syncthreads();
    for (int i = tid; i < NB; i += 256) atomicAdd(&bcnt[i], h[i]);
}

__global__ void bucket_scan(const int* __restrict__ bcnt, int* __restrict__ bstart,
                            int* __restrict__ gcur, int* __restrict__ offs,
                            int NB, int E, int N)
{
    __shared__ int sc[256];
    int tid = threadIdx.x;
    int v = (tid < NB) ? bcnt[tid] : 0;
    sc[tid] = v;
    __syncthreads();
    for (int off = 1; off < 256; off <<= 1) {
        int t = (tid >= off) ? sc[tid - off] : 0;
        __syncthreads();
        sc[tid] += t;
        __syncthreads();
    }
    int excl = sc[tid] - v;
    if (tid < NB) { bstart[tid] = excl; gcur[tid] = excl; }
    if (tid == 0) { bstart[NB] = E; offs[N] = E; }
}

#define EPT 8
__global__ __launch_bounds__(256) void part_kernel(const int* __restrict__ src,
        const int* __restrict__ dst, int* __restrict__ gcur,
        uint2* __restrict__ pairs, int E, int NB, int shift)
{
    __shared__ int hcnt[256];
    __shared__ int hbase[256];
    int tid = threadIdx.x;
    long base = (long)blockIdx.x * (256 * EPT);
    for (int i = tid; i < NB; i += 256) hcnt[i] = 0;
    __syncthreads();
    int b[EPT], r[EPT], s[EPT], d[EPT];
#pragma unroll
    for (int k = 0; k < EPT; ++k) {
        long idx = base + k * 256 + tid;
        if (idx < E) {
            s[k] = src[idx]; d[k] = dst[idx];
            b[k] = d[k] >> shift;
            r[k] = atomicAdd(&hcnt[b[k]], 1);
        } else b[k] = -1;
    }
    __syncthreads();
    for (int i = tid; i < NB; i += 256) hbase[i] = atomicAdd(&gcur[i], hcnt[i]);
    __syncthreads();
#pragma unroll
    for (int k = 0; k < EPT; ++k) {
        if (b[k] >= 0)
            pairs[hbase[b[k]] + r[k]] = make_uint2((unsigned)s[k], (unsigned)d[k]);
    }
}

// one WG per bucket: derive offs + scatter csr within an L2-resident region
__global__ __launch_bounds__(512) void csr_finalize(const uint2* __restrict__ pairs,
        const int* __restrict__ bstart, int* __restrict__ offs, int* __restrict__ csr,
        int N, int shift)
{
    __shared__ int cnt[512];
    __shared__ int sc[512];
    int tid = threadIdx.x;
    int b = blockIdx.x;
    int d0 = b << shift;
    int pS = bstart[b], pE = bstart[b + 1];
    cnt[tid] = 0;
    __syncthreads();
    for (int i = pS + tid; i < pE; i += 512)
        atomicAdd(&cnt[pairs[i].y - d0], 1);
    __syncthreads();
    int v = cnt[tid];
    sc[tid] = v;
    __syncthreads();
    for (int off = 1; off < 512; off <<= 1) {
        int t = (tid >= off) ? sc[tid - off] : 0;
        __syncthreads();
        sc[tid] += t;
        __syncthreads();
    }
    int excl = sc[tid] - v;
    if (d0 + tid < N) offs[d0 + tid] = pS + excl;
    cnt[tid] = excl;                       // reuse as local cursor
    __syncthreads();
    for (int i = pS + tid; i < pE; i += 512) {
        uint2 u = pairs[i];
        int p = atomicAdd(&cnt[u.y - d0], 1);
        csr[pS + p] = (int)u.x;
    }
}

// ---------------- fused GAT aggregation (gather, one wave per dst node) ----------------
__global__ void gat_csr_kernel(const int* __restrict__ offs, const int* __restrict__ csr,
                               const float* __restrict__ el, const float* __restrict__ er,
                               const float* __restrict__ Fsrc, float* __restrict__ rst,
                               int Nd, int hshift)
{
    int d = (blockIdx.x << 2) | (threadIdx.x >> 6);
    int lane = threadIdx.x & 63;
    if (d >= Nd) return;
    int H = 1 << hshift;
    int off = offs[d];
    int n = offs[d + 1] - off;

    int h = lane & (H - 1);
    float erd = er[d * H + h];
    float m = -INFINITY, ssum = 0.f;
    int estep = 64 >> hshift;
    for (int i = lane >> hshift; i < n; i += estep) {
        int sn = csr[off + i];
        float v = el[sn * H + h] + erd;
        v = v > 0.f ? v : 0.2f * v;
        if (v > m) { ssum = ssum * __expf(m - v) + 1.f; m = v; }
        else       { ssum += __expf(v - m); }
    }
    for (int o = H; o < 64; o <<= 1) {
        float om = __shfl_xor(m, o, 64);
        float os = __shfl_xor(ssum, o, 64);
        float nm = fmaxf(m, om);
        float e1 = (m == nm) ? 1.f : __expf(m - nm);
        float e2 = (om == nm) ? 1.f : __expf(om - nm);
        ssum = ssum * e1 + os * e2;
        m = nm;
    }

    int hf = lane >> (6 - hshift);
    float m_f = __shfl(m, hf, 64);
    float s_f = __shfl(ssum, hf, 64);
    float er_f = __shfl(erd, hf, 64);
    float rinv = 1.f / s_f;

    float acc = 0.f;
    for (int base = 0; base < n; base += 64) {
        int sreg = (base + lane < n) ? csr[off + base + lane] : 0;
        int cnt = min(64, n - base);
        for (int j = 0; j < cnt; ++j) {
            int sn = __shfl(sreg, j, 64);
            float v = el[sn * H + hf] + er_f;
            v = v > 0.f ? v : 0.2f * v;
            float a = __expf(v - m_f) * rinv;
            acc = fmaf(Fsrc[(long)sn * 64 + lane], a, acc);
        }
    }
    rst[(long)d * 64 + lane] += acc;
}

__global__ void l2norm_kernel(const float* __restrict__ in, float* __restrict__ out, int N)
{
    long gt = (long)blockIdx.x * blockDim.x + threadIdx.x;
    int row = (int)(gt >> 6);
    int lane = threadIdx.x & 63;
    if (row >= N) return;
    float v = in[(long)row * 64 + lane];
    float ss = v * v;
    for (int off = 1; off < 64; off <<= 1) ss += __shfl_xor(ss, off, 64);
    out[(long)row * 64 + lane] = v / fmaxf(sqrtf(ss), 1e-12f);
}

// ---------------- host-side helpers ----------------
static void build_csr2(const int* src, const int* dst, int E, int N,
                       int* offs, int* csr, int* bcnt, int* bstart, int* gcur,
                       uint2* pairs, hipStream_t stream)
{
    const int SHIFT = 9;
    int NB = (N + 511) >> 9;
    hipMemsetAsync(bcnt, 0, NB * sizeof(int), stream);
    bucket_hist<<<512, 256, 0, stream>>>(dst, bcnt, E, NB, SHIFT);
    bucket_scan<<<1, 256, 0, stream>>>(bcnt, bstart, gcur, offs, NB, E, N);
    part_kernel<<<(E + 2047) / 2048, 256, 0, stream>>>(src, dst, gcur, pairs, E, NB, SHIFT);
    csr_finalize<<<NB, 512, 0, stream>>>(pairs, bstart, offs, csr, N, SHIFT);
}

static void run_gat(const float* h_src, const float* h_dst, int Ns, int Nd,
                    const int* offs, const int* csr,
                    const float* W, const float* al, const float* ar,
                    float* Psrc, float* wal, float* war,
                    float* el, float* er, float* rst, int H, hipStream_t stream)
{
    prep_attn_kernel<<<1, 64, 0, stream>>>(W, al, ar, wal, war, H);
    gemm_tiled<<<(Ns + 127) / 128, 256, 0, stream>>>(h_src, W, nullptr, Psrc, Ns, 64, 0);
    if (h_src == h_dst) {
        attnvec_kernel<<<(Ns + 3) / 4, 256, 0, stream>>>(h_src, wal, war, el, er, Ns, H);
    } else {
        attnvec_kernel<<<(Ns + 3) / 4, 256, 0, stream>>>(h_src, wal, nullptr, el, nullptr, Ns, H);
        attnvec_kernel<<<(Nd + 3) / 4, 256, 0, stream>>>(h_dst, nullptr, war, nullptr, er, Nd, H);
    }
    int hshift = (H == 4) ? 2 : 0;
    gat_csr_kernel<<<(Nd + 3) / 4, 256, 0, stream>>>(offs, csr, el, er, Psrc, rst, Nd, hshift);
}

extern "C" void kernel_launch(void* const* d_in, const int* in_sizes, int n_in,
                              void* d_out, int out_size, void* d_ws, size_t ws_size,
                              hipStream_t stream)
{
    const float* feat_a = (const float*)d_in[0];
    const float* feat_p = (const float*)d_in[1];
    const float* fmWa = (const float*)d_in[2];
    const float* fmba = (const float*)d_in[3];
    const float* fmWp = (const float*)d_in[4];
    const float* fmbp = (const float*)d_in[5];
    const float* g1w_W = (const float*)d_in[6];  const float* g1w_al = (const float*)d_in[7];
    const float* g1w_ar = (const float*)d_in[8]; const float* g1w_b = (const float*)d_in[9];
    const float* g2w_W = (const float*)d_in[10]; const float* g2w_al = (const float*)d_in[11];
    const float* g2w_ar = (const float*)d_in[12]; const float* g2w_b = (const float*)d_in[13];
    const float* g1wb_W = (const float*)d_in[14]; const float* g1wb_al = (const float*)d_in[15];
    const float* g1wb_ar = (const float*)d_in[16]; const float* g1wb_b = (const float*)d_in[17];
    const float* g2wb_W = (const float*)d_in[18]; const float* g2wb_al = (const float*)d_in[19];
    const float* g2wb_ar = (const float*)d_in[20]; const float* g2wb_b = (const float*)d_in[21];
    const float* g1c_W = (const float*)d_in[22]; const float* g1c_al = (const float*)d_in[23];
    const float* g1c_ar = (const float*)d_in[24]; const float* g1c_b = (const float*)d_in[25];
    const float* g2c_W = (const float*)d_in[26]; const float* g2c_al = (const float*)d_in[27];
    const float* g2c_ar = (const float*)d_in[28]; const float* g2c_b = (const float*)d_in[29];
    const int* w_src = (const int*)d_in[30];
    const int* w_dst = (const int*)d_in[31];
    const int* wb_src = (const int*)d_in[32];
    const int* wb_dst = (const int*)d_in[33];
    const int* c_src = (const int*)d_in[34];
    const int* c_dst = (const int*)d_in[35];

    float* ws = (float*)d_ws;
    size_t off = 0;
    auto alloc = [&](size_t n) { float* p = ws + off; off += n; return p; };
    float* h_a  = alloc(HA);
    float* h_p  = alloc(HP);
    float* Pa   = alloc(HP);
    float* h1_p = alloc(HP);
    float* h1_a = alloc(HA);
    float* elb  = alloc((size_t)N_P * 4);
    float* erb  = alloc((size_t)N_P * 4);
    float* wal  = alloc(256);
    float* war  = alloc(256);
    int* w_offs  = (int*)alloc(N_P + 1);
    int* c_offs  = (int*)alloc(N_P + 1);
    int* wb_offs = (int*)alloc(N_A + 1);
    int* bcnt    = (int*)alloc(256);
    int* bstart  = (int*)alloc(260);
    int* gcur    = (int*)alloc(256);
    int* w_csr   = (int*)alloc(E_W);
    int* wb_csr  = (int*)alloc(E_W);
    int* c_csr   = (int*)alloc(E_C);
    off = (off + 1) & ~(size_t)1;          // 8B align for uint2
    uint2* pairs = (uint2*)alloc((size_t)E_C * 2);
    float* h2_p = h_p;   // reuse: dead after layer-1 projections
    float* h2_a = h_a;

    // CSRs (shared across both layers)
    build_csr2(w_src, w_dst, E_W, N_P, w_offs, w_csr, bcnt, bstart, gcur, pairs, stream);
    build_csr2(c_src, c_dst, E_C, N_P, c_offs, c_csr, bcnt, bstart, gcur, pairs, stream);
    build_csr2(wb_src, wb_dst, E_W, N_A, wb_offs, wb_csr, bcnt, bstart, gcur, pairs, stream);

    // Feature mapping: relu(X @ W^T + b)
    gemm_tiled<<<(N_A + 127) / 128, 256, 0, stream>>>(feat_a, fmWa, fmba, h_a, N_A, 128, 1);
    gemm_tiled<<<(N_P + 127) / 128, 256, 0, stream>>>(feat_p, fmWp, fmbp, h_p, N_P, 256, 1);

    // ---- Layer 1 (H=4) ----
    init_bias_kernel<<<((long)N_P * 64 + 255) / 256, 256, 0, stream>>>(h1_p, g1w_b, g1c_b, N_P);
    init_bias_kernel<<<((long)N_A * 64 + 255) / 256, 256, 0, stream>>>(h1_a, g1wb_b, nullptr, N_A);
    run_gat(h_a, h_p, N_A, N_P, w_offs, w_csr, g1w_W, g1w_al, g1w_ar,
            Pa, wal, war, elb, erb, h1_p, 4, stream);
    run_gat(h_p, h_p, N_P, N_P, c_offs, c_csr, g1c_W, g1c_al, g1c_ar,
            Pa, wal, war, elb, erb, h1_p, 4, stream);
    run_gat(h_p, h_a, N_P, N_A, wb_offs, wb_csr, g1wb_W, g1wb_al, g1wb_ar,
            Pa, wal, war, elb, erb, h1_a, 4, stream);

    // ---- Layer 2 (H=1) ----
    init_bias_kernel<<<((long)N_P * 64 + 255) / 256, 256, 0, stream>>>(h2_p, g2w_b, g2c_b, N_P);
    init_bias_kernel<<<((long)N_A * 64 + 255) / 256, 256, 0, stream>>>(h2_a, g2wb_b, nullptr, N_A);
    run_gat(h1_a, h1_p, N_A, N_P, w_offs, w_csr, g2w_W, g2w_al, g2w_ar,
            Pa, wal, war, elb, erb, h2_p, 1, stream);
    run_gat(h1_p, h1_p, N_P, N_P, c_offs, c_csr, g2c_W, g2c_al, g2c_ar,
            Pa, wal, war, elb, erb, h2_p, 1, stream);
    run_gat(h1_p, h1_a, N_P, N_A, wb_offs, wb_csr, g2wb_W, g2wb_al, g2wb_ar,
            Pa, wal, war, elb, erb, h2_a, 1, stream);

    // ---- L2 normalize: authors first, then papers ----
    float* out = (float*)d_out;
    l2norm_kernel<<<((long)N_A * 64 + 255) / 256, 256, 0, stream>>>(h2_a, out, N_A);
    l2norm_kernel<<<((long)N_P * 64 + 255) / 256, 256, 0, stream>>>(h2_p, out + HA, N_P);
}

// Round 5
// 1860.317 us; speedup vs baseline: 2.8938x; 1.0272x over previous
//
#include <hip/hip_runtime.h>
#include <hip/hip_bf16.h>

#define N_A 50000
#define N_P 100000
#define E_W 1600000
#define E_C 3200000
#define HA (N_A*64)
#define HP (N_P*64)

// ---------------- tiled fp32 GEMM: out[M,64] = act(X[M,K] @ W^T + b) ----------------
// outBf16: store output as bf16 (packed ushort4), else fp32 float4.
__global__ __launch_bounds__(256) void gemm_tiled(const float* __restrict__ X,
        const float* __restrict__ W, const float* __restrict__ bias,
        void* __restrict__ out, int M, int K, int doRelu, int outBf16)
{
    __shared__ float Xs[32 * 132];
    __shared__ float Wsh[32 * 68];
    int tid = threadIdx.x;
    int bm0 = blockIdx.x * 128;
    int tx = tid & 15, ty = tid >> 4;

    float acc[8][4];
#pragma unroll
    for (int i = 0; i < 8; ++i)
#pragma unroll
        for (int j = 0; j < 4; ++j) acc[i][j] = 0.f;

    for (int k0 = 0; k0 < K; k0 += 32) {
#pragma unroll
        for (int it = 0; it < 4; ++it) {
            int row = (tid & 31) + 32 * it;
            int chunk = tid >> 5;
            int rg = bm0 + row; rg = rg < M ? rg : M - 1;
            const float4 v = *reinterpret_cast<const float4*>(&X[(long)rg * K + k0 + chunk * 4]);
            int kb = chunk * 4;
            Xs[(kb + 0) * 132 + row] = v.x;
            Xs[(kb + 1) * 132 + row] = v.y;
            Xs[(kb + 2) * 132 + row] = v.z;
            Xs[(kb + 3) * 132 + row] = v.w;
        }
#pragma unroll
        for (int it = 0; it < 2; ++it) {
            int n = tid & 63;
            int chunk = (tid >> 6) + 4 * it;
            const float4 v = *reinterpret_cast<const float4*>(&W[(long)n * K + k0 + chunk * 4]);
            int kb = chunk * 4;
            Wsh[(kb + 0) * 68 + n] = v.x;
            Wsh[(kb + 1) * 68 + n] = v.y;
            Wsh[(kb + 2) * 68 + n] = v.z;
            Wsh[(kb + 3) * 68 + n] = v.w;
        }
        __syncthreads();
#pragma unroll
        for (int k = 0; k < 32; ++k) {
            float4 a0 = *reinterpret_cast<const float4*>(&Xs[k * 132 + ty * 8]);
            float4 a1 = *reinterpret_cast<const float4*>(&Xs[k * 132 + ty * 8 + 4]);
            float4 b  = *reinterpret_cast<const float4*>(&Wsh[k * 68 + tx * 4]);
            float av[8] = {a0.x, a0.y, a0.z, a0.w, a1.x, a1.y, a1.z, a1.w};
            float bv[4] = {b.x, b.y, b.z, b.w};
#pragma unroll
            for (int i = 0; i < 8; ++i)
#pragma unroll
                for (int j = 0; j < 4; ++j)
                    acc[i][j] = fmaf(av[i], bv[j], acc[i][j]);
        }
        __syncthreads();
    }

    float bj[4] = {0.f, 0.f, 0.f, 0.f};
    if (bias) {
        bj[0] = bias[tx * 4 + 0]; bj[1] = bias[tx * 4 + 1];
        bj[2] = bias[tx * 4 + 2]; bj[3] = bias[tx * 4 + 3];
    }
#pragma unroll
    for (int i = 0; i < 8; ++i) {
        int r = bm0 + ty * 8 + i;
        if (r < M) {
            float o[4];
            o[0] = acc[i][0] + bj[0]; o[1] = acc[i][1] + bj[1];
            o[2] = acc[i][2] + bj[2]; o[3] = acc[i][3] + bj[3];
            if (doRelu) {
#pragma unroll
                for (int j = 0; j < 4; ++j) o[j] = fmaxf(o[j], 0.f);
            }
            if (outBf16) {
                ushort4 u;
                __hip_bfloat16 b0 = __float2bfloat16(o[0]);
                __hip_bfloat16 b1 = __float2bfloat16(o[1]);
                __hip_bfloat16 b2 = __float2bfloat16(o[2]);
                __hip_bfloat16 b3 = __float2bfloat16(o[3]);
                u.x = *reinterpret_cast<unsigned short*>(&b0);
                u.y = *reinterpret_cast<unsigned short*>(&b1);
                u.z = *reinterpret_cast<unsigned short*>(&b2);
                u.w = *reinterpret_cast<unsigned short*>(&b3);
                *reinterpret_cast<ushort4*>((unsigned short*)out + (long)r * 64 + tx * 4) = u;
            } else {
                float4 o4; o4.x = o[0]; o4.y = o[1]; o4.z = o[2]; o4.w = o[3];
                *reinterpret_cast<float4*>((float*)out + (long)r * 64 + tx * 4) = o4;
            }
        }
    }
}

// ---------------- attention vector folding ----------------
__global__ void prep_attn_kernel(const float* __restrict__ W, const float* __restrict__ al,
                                 const float* __restrict__ ar, float* __restrict__ wal,
                                 float* __restrict__ war, int H)
{
    int k = threadIdx.x;
    int F = 64 / H;
    for (int hh = 0; hh < H; ++hh) {
        float sl = 0.f, sr = 0.f;
        for (int f = 0; f < F; ++f) {
            float w = W[(hh * F + f) * 64 + k];
            sl = fmaf(w, al[hh * F + f], sl);
            sr = fmaf(w, ar[hh * F + f], sr);
        }
        wal[k * H + hh] = sl;
        war[k * H + hh] = sr;
    }
}

__global__ void attnvec_kernel(const float* __restrict__ h,
                               const float* __restrict__ wal, const float* __restrict__ war,
                               float* __restrict__ el, float* __restrict__ er, int N, int H)
{
    int node = (blockIdx.x << 2) | (threadIdx.x >> 6);
    int lane = threadIdx.x & 63;
    if (node >= N) return;
    float v = h[(long)node * 64 + lane];
    for (int hh = 0; hh < H; ++hh) {
        if (el) {
            float p = v * wal[lane * H + hh];
            for (int o = 1; o < 64; o <<= 1) p += __shfl_xor(p, o, 64);
            if (lane == hh) el[node * H + hh] = p;
        }
        if (er) {
            float p = v * war[lane * H + hh];
            for (int o = 1; o < 64; o <<= 1) p += __shfl_xor(p, o, 64);
            if (lane == hh) er[node * H + hh] = p;
        }
    }
}

__global__ void init_bias_kernel(float* __restrict__ out, const float* __restrict__ b1,
                                 const float* __restrict__ b2, int N)
{
    long i = (long)blockIdx.x * blockDim.x + threadIdx.x;
    if (i >= (long)N * 64) return;
    int c = (int)(i & 63);
    out[i] = b1[c] + (b2 ? b2[c] : 0.f);
}

// ---------------- CSR build: locality-aware bucket sort ----------------
__global__ void bucket_hist(const int* __restrict__ dst, int* __restrict__ bcnt,
                            int E, int NB, int shift)
{
    __shared__ int h[256];
    int tid = threadIdx.x;
    for (int i = tid; i < NB; i += 256) h[i] = 0;
    __syncthreads();
    for (long i = (long)blockIdx.x * 256 + tid; i < E; i += (long)gridDim.x * 256)
        atomicAdd(&h[dst[i] >> shift], 1);
    __syncthreads();
    for (int i = tid; i < NB; i += 256) atomicAdd(&bcnt[i], h[i]);
}

__global__ void bucket_scan(const int* __restrict__ bcnt, int* __restrict__ bstart,
                            int* __restrict__ gcur, int* __restrict__ offs,
                            int NB, int E, int N)
{
    __shared__ int sc[256];
    int tid = threadIdx.x;
    int v = (tid < NB) ? bcnt[tid] : 0;
    sc[tid] = v;
    __syncthreads();
    for (int off = 1; off < 256; off <<= 1) {
        int t = (tid >= off) ? sc[tid - off] : 0;
        __syncthreads();
        sc[tid] += t;
        __syncthreads();
    }
    int excl = sc[tid] - v;
    if (tid < NB) { bstart[tid] = excl; gcur[tid] = excl; }
    if (tid == 0) { bstart[NB] = E; offs[N] = E; }
}

#define EPT 8
__global__ __launch_bounds__(256) void part_kernel(const int* __restrict__ src,
        const int* __restrict__ dst, int* __restrict__ gcur,
        uint2* __restrict__ pairs, int E, int NB, int shift)
{
    __shared__ int hcnt[256];
    __shared__ int hbase[256];
    int tid = threadIdx.x;
    long base = (long)blockIdx.x * (256 * EPT);
    for (int i = tid; i < NB; i += 256) hcnt[i] = 0;
    __syncthreads();
    int b[EPT], r[EPT], s[EPT], d[EPT];
#pragma unroll
    for (int k = 0; k < EPT; ++k) {
        long idx = base + k * 256 + tid;
        if (idx < E) {
            s[k] = src[idx]; d[k] = dst[idx];
            b[k] = d[k] >> shift;
            r[k] = atomicAdd(&hcnt[b[k]], 1);
        } else b[k] = -1;
    }
    __syncthreads();
    for (int i = tid; i < NB; i += 256) hbase[i] = atomicAdd(&gcur[i], hcnt[i]);
    __syncthreads();
#pragma unroll
    for (int k = 0; k < EPT; ++k) {
        if (b[k] >= 0)
            pairs[hbase[b[k]] + r[k]] = make_uint2((unsigned)s[k], (unsigned)d[k]);
    }
}

__global__ __launch_bounds__(512) void csr_finalize(const uint2* __restrict__ pairs,
        const int* __restrict__ bstart, int* __restrict__ offs, int* __restrict__ csr,
        int N, int shift)
{
    __shared__ int cnt[512];
    __shared__ int sc[512];
    int tid = threadIdx.x;
    int b = blockIdx.x;
    int d0 = b << shift;
    int pS = bstart[b], pE = bstart[b + 1];
    cnt[tid] = 0;
    __syncthreads();
    for (int i = pS + tid; i < pE; i += 512)
        atomicAdd(&cnt[pairs[i].y - d0], 1);
    __syncthreads();
    int v = cnt[tid];
    sc[tid] = v;
    __syncthreads();
    for (int off = 1; off < 512; off <<= 1) {
        int t = (tid >= off) ? sc[tid - off] : 0;
        __syncthreads();
        sc[tid] += t;
        __syncthreads();
    }
    int excl = sc[tid] - v;
    if (d0 + tid < N) offs[d0 + tid] = pS + excl;
    cnt[tid] = excl;
    __syncthreads();
    for (int i = pS + tid; i < pE; i += 512) {
        uint2 u = pairs[i];
        int p = atomicAdd(&cnt[u.y - d0], 1);
        csr[pS + p] = (int)u.x;
    }
}

// ---------------- fused GAT aggregation (gather; bf16 features; precomputed alpha) ----------------
__global__ void gat_csr_kernel(const int* __restrict__ offs, const int* __restrict__ csr,
                               const float* __restrict__ el, const float* __restrict__ er,
                               const unsigned short* __restrict__ Fsrc, float* __restrict__ rst,
                               int Nd, int hshift)
{
    int d = (blockIdx.x << 2) | (threadIdx.x >> 6);
    int lane = threadIdx.x & 63;
    if (d >= Nd) return;
    int H = 1 << hshift;
    int off = offs[d];
    int n = offs[d + 1] - off;
    if (n == 0) return;

    // pass A: online softmax per head; lane handles edge (lane>>hshift), head (lane&(H-1))
    int h = lane & (H - 1);
    float erd = er[d * H + h];
    float m = -INFINITY, ssum = 0.f;
    int estep = 64 >> hshift;
    for (int i = lane >> hshift; i < n; i += estep) {
        int sn = csr[off + i];
        float v = el[sn * H + h] + erd;
        v = v > 0.f ? v : 0.2f * v;
        if (v > m) { ssum = ssum * __expf(m - v) + 1.f; m = v; }
        else       { ssum += __expf(v - m); }
    }
    for (int o = H; o < 64; o <<= 1) {
        float om = __shfl_xor(m, o, 64);
        float os = __shfl_xor(ssum, o, 64);
        float nm = fmaxf(m, om);
        float e1 = (m == nm) ? 1.f : __expf(m - nm);
        float e2 = (om == nm) ? 1.f : __expf(om - nm);
        ssum = ssum * e1 + os * e2;
        m = nm;
    }
    // now every lane holds m, ssum for head (lane & (H-1))
    float rinv = 1.f / ssum;
    int hf = lane >> (6 - hshift);       // head owning this lane's output feature

    // pass B: per round of EPL=64>>hshift edges, lane precomputes alpha for its
    // (edge, head) slot exactly as pass A; j-loop shuffles alpha+src and fmas.
    float acc = 0.f;
    for (int base = 0; base < n; base += estep) {
        int i = base + (lane >> hshift);
        int sn = 0; float a = 0.f;
        if (i < n) {
            sn = csr[off + i];
            float v = el[sn * H + h] + erd;
            v = v > 0.f ? v : 0.2f * v;
            a = __expf(v - m) * rinv;
        }
        int cnt = min(estep, n - base);
        for (int j = 0; j < cnt; ++j) {
            int s2 = __shfl(sn, j << hshift, 64);
            float a2 = __shfl(a, (j << hshift) | hf, 64);
            unsigned short ub = Fsrc[(long)s2 * 64 + lane];
            float fv = __bfloat162float(*reinterpret_cast<__hip_bfloat16*>(&ub));
            acc = fmaf(fv, a2, acc);
        }
    }
    rst[(long)d * 64 + lane] += acc;
}

__global__ void l2norm_kernel(const float* __restrict__ in, float* __restrict__ out, int N)
{
    long gt = (long)blockIdx.x * blockDim.x + threadIdx.x;
    int row = (int)(gt >> 6);
    int lane = threadIdx.x & 63;
    if (row >= N) return;
    float v = in[(long)row * 64 + lane];
    float ss = v * v;
    for (int off = 1; off < 64; off <<= 1) ss += __shfl_xor(ss, off, 64);
    out[(long)row * 64 + lane] = v / fmaxf(sqrtf(ss), 1e-12f);
}

// ---------------- host-side helpers ----------------
static void build_csr2(const int* src, const int* dst, int E, int N,
                       int* offs, int* csr, int* bcnt, int* bstart, int* gcur,
                       uint2* pairs, hipStream_t stream)
{
    const int SHIFT = 9;
    int NB = (N + 511) >> 9;
    hipMemsetAsync(bcnt, 0, NB * sizeof(int), stream);
    bucket_hist<<<512, 256, 0, stream>>>(dst, bcnt, E, NB, SHIFT);
    bucket_scan<<<1, 256, 0, stream>>>(bcnt, bstart, gcur, offs, NB, E, N);
    part_kernel<<<(E + 2047) / 2048, 256, 0, stream>>>(src, dst, gcur, pairs, E, NB, SHIFT);
    csr_finalize<<<NB, 512, 0, stream>>>(pairs, bstart, offs, csr, N, SHIFT);
}

static void run_gat(const float* h_src, const float* h_dst, int Ns, int Nd,
                    const int* offs, const int* csr,
                    const float* W, const float* al, const float* ar,
                    unsigned short* Psrc, float* wal, float* war,
                    float* el, float* er, float* rst, int H, hipStream_t stream)
{
    prep_attn_kernel<<<1, 64, 0, stream>>>(W, al, ar, wal, war, H);
    gemm_tiled<<<(Ns + 127) / 128, 256, 0, stream>>>(h_src, W, nullptr, Psrc, Ns, 64, 0, 1);
    if (h_src == h_dst) {
        attnvec_kernel<<<(Ns + 3) / 4, 256, 0, stream>>>(h_src, wal, war, el, er, Ns, H);
    } else {
        attnvec_kernel<<<(Ns + 3) / 4, 256, 0, stream>>>(h_src, wal, nullptr, el, nullptr, Ns, H);
        attnvec_kernel<<<(Nd + 3) / 4, 256, 0, stream>>>(h_dst, nullptr, war, nullptr, er, Nd, H);
    }
    int hshift = (H == 4) ? 2 : 0;
    gat_csr_kernel<<<(Nd + 3) / 4, 256, 0, stream>>>(offs, csr, el, er, Psrc, rst, Nd, hshift);
}

extern "C" void kernel_launch(void* const* d_in, const int* in_sizes, int n_in,
                              void* d_out, int out_size, void* d_ws, size_t ws_size,
                              hipStream_t stream)
{
    const float* feat_a = (const float*)d_in[0];
    const float* feat_p = (const float*)d_in[1];
    const float* fmWa = (const float*)d_in[2];
    const float* fmba = (const float*)d_in[3];
    const float* fmWp = (const float*)d_in[4];
    const float* fmbp = (const float*)d_in[5];
    const float* g1w_W = (const float*)d_in[6];  const float* g1w_al = (const float*)d_in[7];
    const float* g1w_ar = (const float*)d_in[8]; const float* g1w_b = (const float*)d_in[9];
    const float* g2w_W = (const float*)d_in[10]; const float* g2w_al = (const float*)d_in[11];
    const float* g2w_ar = (const float*)d_in[12]; const float* g2w_b = (const float*)d_in[13];
    const float* g1wb_W = (const float*)d_in[14]; const float* g1wb_al = (const float*)d_in[15];
    const float* g1wb_ar = (const float*)d_in[16]; const float* g1wb_b = (const float*)d_in[17];
    const float* g2wb_W = (const float*)d_in[18]; const float* g2wb_al = (const float*)d_in[19];
    const float* g2wb_ar = (const float*)d_in[20]; const float* g2wb_b = (const float*)d_in[21];
    const float* g1c_W = (const float*)d_in[22]; const float* g1c_al = (const float*)d_in[23];
    const float* g1c_ar = (const float*)d_in[24]; const float* g1c_b = (const float*)d_in[25];
    const float* g2c_W = (const float*)d_in[26]; const float* g2c_al = (const float*)d_in[27];
    const float* g2c_ar = (const float*)d_in[28]; const float* g2c_b = (const float*)d_in[29];
    const int* w_src = (const int*)d_in[30];
    const int* w_dst = (const int*)d_in[31];
    const int* wb_src = (const int*)d_in[32];
    const int* wb_dst = (const int*)d_in[33];
    const int* c_src = (const int*)d_in[34];
    const int* c_dst = (const int*)d_in[35];

    float* ws = (float*)d_ws;
    size_t off = 0;
    auto alloc = [&](size_t n) { float* p = ws + off; off += n; return p; };
    float* h_a  = alloc(HA);
    float* h_p  = alloc(HP);
    unsigned short* Pa = (unsigned short*)alloc(HP / 2 + 16);   // HP bf16 elements
    float* h1_p = alloc(HP);
    float* h1_a = alloc(HA);
    float* elb  = alloc((size_t)N_P * 4);
    float* erb  = alloc((size_t)N_P * 4);
    float* wal  = alloc(256);
    float* war  = alloc(256);
    int* w_offs  = (int*)alloc(N_P + 1);
    int* c_offs  = (int*)alloc(N_P + 1);
    int* wb_offs = (int*)alloc(N_A + 1);
    int* bcnt    = (int*)alloc(256);
    int* bstart  = (int*)alloc(260);
    int* gcur    = (int*)alloc(256);
    int* w_csr   = (int*)alloc(E_W);
    int* wb_csr  = (int*)alloc(E_W);
    int* c_csr   = (int*)alloc(E_C);
    off = (off + 1) & ~(size_t)1;
    uint2* pairs = (uint2*)alloc((size_t)E_C * 2);
    float* h2_p = h_p;
    float* h2_a = h_a;

    build_csr2(w_src, w_dst, E_W, N_P, w_offs, w_csr, bcnt, bstart, gcur, pairs, stream);
    build_csr2(c_src, c_dst, E_C, N_P, c_offs, c_csr, bcnt, bstart, gcur, pairs, stream);
    build_csr2(wb_src, wb_dst, E_W, N_A, wb_offs, wb_csr, bcnt, bstart, gcur, pairs, stream);

    gemm_tiled<<<(N_A + 127) / 128, 256, 0, stream>>>(feat_a, fmWa, fmba, h_a, N_A, 128, 1, 0);
    gemm_tiled<<<(N_P + 127) / 128, 256, 0, stream>>>(feat_p, fmWp, fmbp, h_p, N_P, 256, 1, 0);

    // ---- Layer 1 (H=4) ----
    init_bias_kernel<<<((long)N_P * 64 + 255) / 256, 256, 0, stream>>>(h1_p, g1w_b, g1c_b, N_P);
    init_bias_kernel<<<((long)N_A * 64 + 255) / 256, 256, 0, stream>>>(h1_a, g1wb_b, nullptr, N_A);
    run_gat(h_a, h_p, N_A, N_P, w_offs, w_csr, g1w_W, g1w_al, g1w_ar,
            Pa, wal, war, elb, erb, h1_p, 4, stream);
    run_gat(h_p, h_p, N_P, N_P, c_offs, c_csr, g1c_W, g1c_al, g1c_ar,
            Pa, wal, war, elb, erb, h1_p, 4, stream);
    run_gat(h_p, h_a, N_P, N_A, wb_offs, wb_csr, g1wb_W, g1wb_al, g1wb_ar,
            Pa, wal, war, elb, erb, h1_a, 4, stream);

    // ---- Layer 2 (H=1) ----
    init_bias_kernel<<<((long)N_P * 64 + 255) / 256, 256, 0, stream>>>(h2_p, g2w_b, g2c_b, N_P);
    init_bias_kernel<<<((long)N_A * 64 + 255) / 256, 256, 0, stream>>>(h2_a, g2wb_b, nullptr, N_A);
    run_gat(h1_a, h1_p, N_A, N_P, w_offs, w_csr, g2w_W, g2w_al, g2w_ar,
            Pa, wal, war, elb, erb, h2_p, 1, stream);
    run_gat(h1_p, h1_p, N_P, N_P, c_offs, c_csr, g2c_W, g2c_al, g2c_ar,
            Pa, wal, war, elb, erb, h2_p, 1, stream);
    run_gat(h1_p, h1_a, N_P, N_A, wb_offs, wb_csr, g2wb_W, g2wb_al, g2wb_ar,
            Pa, wal, war, elb, erb, h2_a, 1, stream);

    float* out = (float*)d_out;
    l2norm_kernel<<<((long)N_A * 64 + 255) / 256, 256, 0, stream>>>(h2_a, out, N_A);
    l2norm_kernel<<<((long)N_P * 64 + 255) / 256, 256, 0, stream>>>(h2_p, out + HA, N_P);
}

// Round 6
// 1456.800 us; speedup vs baseline: 3.6953x; 1.2770x over previous
//
#include <hip/hip_runtime.h>
#include <hip/hip_bf16.h>

#define N_A 50000
#define N_P 100000
#define E_W 1600000
#define E_C 3200000
#define HA (N_A*64)
#define HP (N_P*64)

// ---------------- tiled fp32 GEMM: out[M,64] = act(X[M,K] @ W^T + b) ----------------
__global__ __launch_bounds__(256) void gemm_tiled(const float* __restrict__ X,
        const float* __restrict__ W, const float* __restrict__ bias,
        void* __restrict__ out, int M, int K, int doRelu, int outBf16)
{
    __shared__ float Xs[32 * 132];
    __shared__ float Wsh[32 * 68];
    int tid = threadIdx.x;
    int bm0 = blockIdx.x * 128;
    int tx = tid & 15, ty = tid >> 4;

    float acc[8][4];
#pragma unroll
    for (int i = 0; i < 8; ++i)
#pragma unroll
        for (int j = 0; j < 4; ++j) acc[i][j] = 0.f;

    for (int k0 = 0; k0 < K; k0 += 32) {
#pragma unroll
        for (int it = 0; it < 4; ++it) {
            int row = (tid & 31) + 32 * it;
            int chunk = tid >> 5;
            int rg = bm0 + row; rg = rg < M ? rg : M - 1;
            const float4 v = *reinterpret_cast<const float4*>(&X[(long)rg * K + k0 + chunk * 4]);
            int kb = chunk * 4;
            Xs[(kb + 0) * 132 + row] = v.x;
            Xs[(kb + 1) * 132 + row] = v.y;
            Xs[(kb + 2) * 132 + row] = v.z;
            Xs[(kb + 3) * 132 + row] = v.w;
        }
#pragma unroll
        for (int it = 0; it < 2; ++it) {
            int n = tid & 63;
            int chunk = (tid >> 6) + 4 * it;
            const float4 v = *reinterpret_cast<const float4*>(&W[(long)n * K + k0 + chunk * 4]);
            int kb = chunk * 4;
            Wsh[(kb + 0) * 68 + n] = v.x;
            Wsh[(kb + 1) * 68 + n] = v.y;
            Wsh[(kb + 2) * 68 + n] = v.z;
            Wsh[(kb + 3) * 68 + n] = v.w;
        }
        __syncthreads();
#pragma unroll
        for (int k = 0; k < 32; ++k) {
            float4 a0 = *reinterpret_cast<const float4*>(&Xs[k * 132 + ty * 8]);
            float4 a1 = *reinterpret_cast<const float4*>(&Xs[k * 132 + ty * 8 + 4]);
            float4 b  = *reinterpret_cast<const float4*>(&Wsh[k * 68 + tx * 4]);
            float av[8] = {a0.x, a0.y, a0.z, a0.w, a1.x, a1.y, a1.z, a1.w};
            float bv[4] = {b.x, b.y, b.z, b.w};
#pragma unroll
            for (int i = 0; i < 8; ++i)
#pragma unroll
                for (int j = 0; j < 4; ++j)
                    acc[i][j] = fmaf(av[i], bv[j], acc[i][j]);
        }
        __syncthreads();
    }

    float bj[4] = {0.f, 0.f, 0.f, 0.f};
    if (bias) {
        bj[0] = bias[tx * 4 + 0]; bj[1] = bias[tx * 4 + 1];
        bj[2] = bias[tx * 4 + 2]; bj[3] = bias[tx * 4 + 3];
    }
#pragma unroll
    for (int i = 0; i < 8; ++i) {
        int r = bm0 + ty * 8 + i;
        if (r < M) {
            float o[4];
            o[0] = acc[i][0] + bj[0]; o[1] = acc[i][1] + bj[1];
            o[2] = acc[i][2] + bj[2]; o[3] = acc[i][3] + bj[3];
            if (doRelu) {
#pragma unroll
                for (int j = 0; j < 4; ++j) o[j] = fmaxf(o[j], 0.f);
            }
            if (outBf16) {
                ushort4 u;
                __hip_bfloat16 b0 = __float2bfloat16(o[0]);
                __hip_bfloat16 b1 = __float2bfloat16(o[1]);
                __hip_bfloat16 b2 = __float2bfloat16(o[2]);
                __hip_bfloat16 b3 = __float2bfloat16(o[3]);
                u.x = *reinterpret_cast<unsigned short*>(&b0);
                u.y = *reinterpret_cast<unsigned short*>(&b1);
                u.z = *reinterpret_cast<unsigned short*>(&b2);
                u.w = *reinterpret_cast<unsigned short*>(&b3);
                *reinterpret_cast<ushort4*>((unsigned short*)out + (long)r * 64 + tx * 4) = u;
            } else {
                float4 o4; o4.x = o[0]; o4.y = o[1]; o4.z = o[2]; o4.w = o[3];
                *reinterpret_cast<float4*>((float*)out + (long)r * 64 + tx * 4) = o4;
            }
        }
    }
}

// ---------------- attention vector folding ----------------
__global__ void prep_attn_kernel(const float* __restrict__ W, const float* __restrict__ al,
                                 const float* __restrict__ ar, float* __restrict__ wal,
                                 float* __restrict__ war, int H)
{
    int k = threadIdx.x;
    int F = 64 / H;
    for (int hh = 0; hh < H; ++hh) {
        float sl = 0.f, sr = 0.f;
        for (int f = 0; f < F; ++f) {
            float w = W[(hh * F + f) * 64 + k];
            sl = fmaf(w, al[hh * F + f], sl);
            sr = fmaf(w, ar[hh * F + f], sr);
        }
        wal[k * H + hh] = sl;
        war[k * H + hh] = sr;
    }
}

__global__ void attnvec_kernel(const float* __restrict__ h,
                               const float* __restrict__ wal, const float* __restrict__ war,
                               float* __restrict__ el, float* __restrict__ er, int N, int H)
{
    int node = (blockIdx.x << 2) | (threadIdx.x >> 6);
    int lane = threadIdx.x & 63;
    if (node >= N) return;
    float v = h[(long)node * 64 + lane];
    for (int hh = 0; hh < H; ++hh) {
        if (el) {
            float p = v * wal[lane * H + hh];
            for (int o = 1; o < 64; o <<= 1) p += __shfl_xor(p, o, 64);
            if (lane == hh) el[node * H + hh] = p;
        }
        if (er) {
            float p = v * war[lane * H + hh];
            for (int o = 1; o < 64; o <<= 1) p += __shfl_xor(p, o, 64);
            if (lane == hh) er[node * H + hh] = p;
        }
    }
}

__global__ void init_bias_kernel(float* __restrict__ out, const float* __restrict__ b1,
                                 const float* __restrict__ b2, int N)
{
    long i = (long)blockIdx.x * blockDim.x + threadIdx.x;
    if (i >= (long)N * 64) return;
    int c = (int)(i & 63);
    out[i] = b1[c] + (b2 ? b2[c] : 0.f);
}

// ---------------- CSR build: locality-aware bucket sort ----------------
__global__ void bucket_hist(const int* __restrict__ dst, int* __restrict__ bcnt,
                            int E, int NB, int shift)
{
    __shared__ int h[256];
    int tid = threadIdx.x;
    for (int i = tid; i < NB; i += 256) h[i] = 0;
    __syncthreads();
    for (long i = (long)blockIdx.x * 256 + tid; i < E; i += (long)gridDim.x * 256)
        atomicAdd(&h[dst[i] >> shift], 1);
    __syncthreads();
    for (int i = tid; i < NB; i += 256) atomicAdd(&bcnt[i], h[i]);
}

__global__ void bucket_scan(const int* __restrict__ bcnt, int* __restrict__ bstart,
                            int* __restrict__ gcur, int* __restrict__ offs,
                            int NB, int E, int N)
{
    __shared__ int sc[256];
    int tid = threadIdx.x;
    int v = (tid < NB) ? bcnt[tid] : 0;
    sc[tid] = v;
    __syncthreads();
    for (int off = 1; off < 256; off <<= 1) {
        int t = (tid >= off) ? sc[tid - off] : 0;
        __syncthreads();
        sc[tid] += t;
        __syncthreads();
    }
    int excl = sc[tid] - v;
    if (tid < NB) { bstart[tid] = excl; gcur[tid] = excl; }
    if (tid == 0) { bstart[NB] = E; offs[N] = E; }
}

#define EPT 8
__global__ __launch_bounds__(256) void part_kernel(const int* __restrict__ src,
        const int* __restrict__ dst, int* __restrict__ gcur,
        uint2* __restrict__ pairs, int E, int NB, int shift)
{
    __shared__ int hcnt[256];
    __shared__ int hbase[256];
    int tid = threadIdx.x;
    long base = (long)blockIdx.x * (256 * EPT);
    for (int i = tid; i < NB; i += 256) hcnt[i] = 0;
    __syncthreads();
    int b[EPT], r[EPT], s[EPT], d[EPT];
#pragma unroll
    for (int k = 0; k < EPT; ++k) {
        long idx = base + k * 256 + tid;
        if (idx < E) {
            s[k] = src[idx]; d[k] = dst[idx];
            b[k] = d[k] >> shift;
            r[k] = atomicAdd(&hcnt[b[k]], 1);
        } else b[k] = -1;
    }
    __syncthreads();
    for (int i = tid; i < NB; i += 256) hbase[i] = atomicAdd(&gcur[i], hcnt[i]);
    __syncthreads();
#pragma unroll
    for (int k = 0; k < EPT; ++k) {
        if (b[k] >= 0)
            pairs[hbase[b[k]] + r[k]] = make_uint2((unsigned)s[k], (unsigned)d[k]);
    }
}

__global__ __launch_bounds__(512) void csr_finalize(const uint2* __restrict__ pairs,
        const int* __restrict__ bstart, int* __restrict__ offs, int* __restrict__ csr,
        int N, int shift)
{
    __shared__ int cnt[512];
    __shared__ int sc[512];
    int tid = threadIdx.x;
    int b = blockIdx.x;
    int d0 = b << shift;
    int pS = bstart[b], pE = bstart[b + 1];
    cnt[tid] = 0;
    __syncthreads();
    for (int i = pS + tid; i < pE; i += 512)
        atomicAdd(&cnt[pairs[i].y - d0], 1);
    __syncthreads();
    int v = cnt[tid];
    sc[tid] = v;
    __syncthreads();
    for (int off = 1; off < 512; off <<= 1) {
        int t = (tid >= off) ? sc[tid - off] : 0;
        __syncthreads();
        sc[tid] += t;
        __syncthreads();
    }
    int excl = sc[tid] - v;
    if (d0 + tid < N) offs[d0 + tid] = pS + excl;
    cnt[tid] = excl;
    __syncthreads();
    for (int i = pS + tid; i < pE; i += 512) {
        uint2 u = pairs[i];
        int p = atomicAdd(&cnt[u.y - d0], 1);
        csr[pS + p] = (int)u.x;
    }
}

// ---------------- fused GAT aggregation: 4-edges-per-micro-round gather ----------------
__global__ void gat_csr_kernel(const int* __restrict__ offs, const int* __restrict__ csr,
                               const float* __restrict__ el, const float* __restrict__ er,
                               const unsigned short* __restrict__ Fsrc, float* __restrict__ rst,
                               int Nd, int hshift)
{
    int d = (blockIdx.x << 2) | (threadIdx.x >> 6);
    int lane = threadIdx.x & 63;
    if (d >= Nd) return;
    int H = 1 << hshift;
    int off = offs[d];
    int n = offs[d + 1] - off;
    if (n == 0) return;

    // pass A: online softmax per head; lane handles edge (lane>>hshift), head (lane&(H-1))
    int h = lane & (H - 1);
    float erd = er[d * H + h];
    float m = -INFINITY, ssum = 0.f;
    int estep = 64 >> hshift;
    for (int i = lane >> hshift; i < n; i += estep) {
        int sn = csr[off + i];
        float v = el[sn * H + h] + erd;
        v = v > 0.f ? v : 0.2f * v;
        if (v > m) { ssum = ssum * __expf(m - v) + 1.f; m = v; }
        else       { ssum += __expf(v - m); }
    }
    for (int o = H; o < 64; o <<= 1) {
        float om = __shfl_xor(m, o, 64);
        float os = __shfl_xor(ssum, o, 64);
        float nm = fmaxf(m, om);
        float e1 = (m == nm) ? 1.f : __expf(m - nm);
        float e2 = (om == nm) ? 1.f : __expf(om - nm);
        ssum = ssum * e1 + os * e2;
        m = nm;
    }
    float rinv = 1.f / ssum;     // (m, rinv) valid for head lane&(H-1)

    // pass B layout: lane<5:4> = edge sub-slot g, lane<3:0> = feature quad
    int g = lane >> 4;
    int fb = (lane & 15) * 4;                           // feature base (quad)
    int hf = (hshift == 2) ? ((lane & 15) >> 2) : 0;    // head of my feature quad
    float acc0 = 0.f, acc1 = 0.f, acc2 = 0.f, acc3 = 0.f;

    for (int base = 0; base < n; base += estep) {
        // lane computes alpha for edge base+(lane>>hshift), head lane&(H-1)
        int i = base + (lane >> hshift);
        int sn = 0; float a = 0.f;
        if (i < n) {
            sn = csr[off + i];
            float v = el[sn * H + h] + erd;
            v = v > 0.f ? v : 0.2f * v;
            a = __expf(v - m) * rinv;
        }
        int rounds = min(estep, n - base);
        // micro-rounds: 4 edges each; OOB slots have a==0 from their source lane
#pragma unroll 4
        for (int r = 0; r * 4 < rounds; ++r) {
            int sl = r * 4 + g;              // edge slot in this macro-round
            int lsn = sl << hshift;          // lane holding sn for slot sl
            int s2 = __shfl(sn, lsn, 64);
            float a2 = __shfl(a, lsn | hf, 64);
            ushort4 u = *reinterpret_cast<const ushort4*>(&Fsrc[(long)s2 * 64 + fb]);
            acc0 = fmaf(__uint_as_float((unsigned)u.x << 16), a2, acc0);
            acc1 = fmaf(__uint_as_float((unsigned)u.y << 16), a2, acc1);
            acc2 = fmaf(__uint_as_float((unsigned)u.z << 16), a2, acc2);
            acc3 = fmaf(__uint_as_float((unsigned)u.w << 16), a2, acc3);
        }
    }
    // reduce over the 4 edge sub-slots (lane bits 4,5)
    acc0 += __shfl_xor(acc0, 16, 64); acc0 += __shfl_xor(acc0, 32, 64);
    acc1 += __shfl_xor(acc1, 16, 64); acc1 += __shfl_xor(acc1, 32, 64);
    acc2 += __shfl_xor(acc2, 16, 64); acc2 += __shfl_xor(acc2, 32, 64);
    acc3 += __shfl_xor(acc3, 16, 64); acc3 += __shfl_xor(acc3, 32, 64);
    if (lane < 16) {
        float4 r4 = *reinterpret_cast<float4*>(&rst[(long)d * 64 + fb]);
        r4.x += acc0; r4.y += acc1; r4.z += acc2; r4.w += acc3;
        *reinterpret_cast<float4*>(&rst[(long)d * 64 + fb]) = r4;
    }
}

__global__ void l2norm_kernel(const float* __restrict__ in, float* __restrict__ out, int N)
{
    long gt = (long)blockIdx.x * blockDim.x + threadIdx.x;
    int row = (int)(gt >> 6);
    int lane = threadIdx.x & 63;
    if (row >= N) return;
    float v = in[(long)row * 64 + lane];
    float ss = v * v;
    for (int off = 1; off < 64; off <<= 1) ss += __shfl_xor(ss, off, 64);
    out[(long)row * 64 + lane] = v / fmaxf(sqrtf(ss), 1e-12f);
}

// ---------------- host-side helpers ----------------
static void build_csr2(const int* src, const int* dst, int E, int N,
                       int* offs, int* csr, int* bcnt, int* bstart, int* gcur,
                       uint2* pairs, hipStream_t stream)
{
    const int SHIFT = 9;
    int NB = (N + 511) >> 9;
    hipMemsetAsync(bcnt, 0, NB * sizeof(int), stream);
    bucket_hist<<<512, 256, 0, stream>>>(dst, bcnt, E, NB, SHIFT);
    bucket_scan<<<1, 256, 0, stream>>>(bcnt, bstart, gcur, offs, NB, E, N);
    part_kernel<<<(E + 2047) / 2048, 256, 0, stream>>>(src, dst, gcur, pairs, E, NB, SHIFT);
    csr_finalize<<<NB, 512, 0, stream>>>(pairs, bstart, offs, csr, N, SHIFT);
}

static void run_gat(const float* h_src, const float* h_dst, int Ns, int Nd,
                    const int* offs, const int* csr,
                    const float* W, const float* al, const float* ar,
                    unsigned short* Psrc, float* wal, float* war,
                    float* el, float* er, float* rst, int H, hipStream_t stream)
{
    prep_attn_kernel<<<1, 64, 0, stream>>>(W, al, ar, wal, war, H);
    gemm_tiled<<<(Ns + 127) / 128, 256, 0, stream>>>(h_src, W, nullptr, Psrc, Ns, 64, 0, 1);
    if (h_src == h_dst) {
        attnvec_kernel<<<(Ns + 3) / 4, 256, 0, stream>>>(h_src, wal, war, el, er, Ns, H);
    } else {
        attnvec_kernel<<<(Ns + 3) / 4, 256, 0, stream>>>(h_src, wal, nullptr, el, nullptr, Ns, H);
        attnvec_kernel<<<(Nd + 3) / 4, 256, 0, stream>>>(h_dst, nullptr, war, nullptr, er, Nd, H);
    }
    int hshift = (H == 4) ? 2 : 0;
    gat_csr_kernel<<<(Nd + 3) / 4, 256, 0, stream>>>(offs, csr, el, er, Psrc, rst, Nd, hshift);
}

extern "C" void kernel_launch(void* const* d_in, const int* in_sizes, int n_in,
                              void* d_out, int out_size, void* d_ws, size_t ws_size,
                              hipStream_t stream)
{
    const float* feat_a = (const float*)d_in[0];
    const float* feat_p = (const float*)d_in[1];
    const float* fmWa = (const float*)d_in[2];
    const float* fmba = (const float*)d_in[3];
    const float* fmWp = (const float*)d_in[4];
    const float* fmbp = (const float*)d_in[5];
    const float* g1w_W = (const float*)d_in[6];  const float* g1w_al = (const float*)d_in[7];
    const float* g1w_ar = (const float*)d_in[8]; const float* g1w_b = (const float*)d_in[9];
    const float* g2w_W = (const float*)d_in[10]; const float* g2w_al = (const float*)d_in[11];
    const float* g2w_ar = (const float*)d_in[12]; const float* g2w_b = (const float*)d_in[13];
    const float* g1wb_W = (const float*)d_in[14]; const float* g1wb_al = (const float*)d_in[15];
    const float* g1wb_ar = (const float*)d_in[16]; const float* g1wb_b = (const float*)d_in[17];
    const float* g2wb_W = (const float*)d_in[18]; const float* g2wb_al = (const float*)d_in[19];
    const float* g2wb_ar = (const float*)d_in[20]; const float* g2wb_b = (const float*)d_in[21];
    const float* g1c_W = (const float*)d_in[22]; const float* g1c_al = (const float*)d_in[23];
    const float* g1c_ar = (const float*)d_in[24]; const float* g1c_b = (const float*)d_in[25];
    const float* g2c_W = (const float*)d_in[26]; const float* g2c_al = (const float*)d_in[27];
    const float* g2c_ar = (const float*)d_in[28]; const float* g2c_b = (const float*)d_in[29];
    const int* w_src = (const int*)d_in[30];
    const int* w_dst = (const int*)d_in[31];
    const int* wb_src = (const int*)d_in[32];
    const int* wb_dst = (const int*)d_in[33];
    const int* c_src = (const int*)d_in[34];
    const int* c_dst = (const int*)d_in[35];

    float* ws = (float*)d_ws;
    size_t off = 0;
    auto alloc = [&](size_t n) { float* p = ws + off; off += n; return p; };
    float* h_a  = alloc(HA);
    float* h_p  = alloc(HP);
    unsigned short* Pa = (unsigned short*)alloc(HP / 2 + 16);
    float* h1_p = alloc(HP);
    float* h1_a = alloc(HA);
    float* elb  = alloc((size_t)N_P * 4);
    float* erb  = alloc((size_t)N_P * 4);
    float* wal  = alloc(256);
    float* war  = alloc(256);
    int* w_offs  = (int*)alloc(N_P + 1);
    int* c_offs  = (int*)alloc(N_P + 1);
    int* wb_offs = (int*)alloc(N_A + 1);
    int* bcnt    = (int*)alloc(256);
    int* bstart  = (int*)alloc(260);
    int* gcur    = (int*)alloc(256);
    int* w_csr   = (int*)alloc(E_W);
    int* wb_csr  = (int*)alloc(E_W);
    int* c_csr   = (int*)alloc(E_C);
    off = (off + 1) & ~(size_t)1;
    uint2* pairs = (uint2*)alloc((size_t)E_C * 2);
    float* h2_p = h_p;
    float* h2_a = h_a;

    build_csr2(w_src, w_dst, E_W, N_P, w_offs, w_csr, bcnt, bstart, gcur, pairs, stream);
    build_csr2(c_src, c_dst, E_C, N_P, c_offs, c_csr, bcnt, bstart, gcur, pairs, stream);
    build_csr2(wb_src, wb_dst, E_W, N_A, wb_offs, wb_csr, bcnt, bstart, gcur, pairs, stream);

    gemm_tiled<<<(N_A + 127) / 128, 256, 0, stream>>>(feat_a, fmWa, fmba, h_a, N_A, 128, 1, 0);
    gemm_tiled<<<(N_P + 127) / 128, 256, 0, stream>>>(feat_p, fmWp, fmbp, h_p, N_P, 256, 1, 0);

    // ---- Layer 1 (H=4) ----
    init_bias_kernel<<<((long)N_P * 64 + 255) / 256, 256, 0, stream>>>(h1_p, g1w_b, g1c_b, N_P);
    init_bias_kernel<<<((long)N_A * 64 + 255) / 256, 256, 0, stream>>>(h1_a, g1wb_b, nullptr, N_A);
    run_gat(h_a, h_p, N_A, N_P, w_offs, w_csr, g1w_W, g1w_al, g1w_ar,
            Pa, wal, war, elb, erb, h1_p, 4, stream);
    run_gat(h_p, h_p, N_P, N_P, c_offs, c_csr, g1c_W, g1c_al, g1c_ar,
            Pa, wal, war, elb, erb, h1_p, 4, stream);
    run_gat(h_p, h_a, N_P, N_A, wb_offs, wb_csr, g1wb_W, g1wb_al, g1wb_ar,
            Pa, wal, war, elb, erb, h1_a, 4, stream);

    // ---- Layer 2 (H=1) ----
    init_bias_kernel<<<((long)N_P * 64 + 255) / 256, 256, 0, stream>>>(h2_p, g2w_b, g2c_b, N_P);
    init_bias_kernel<<<((long)N_A * 64 + 255) / 256, 256, 0, stream>>>(h2_a, g2wb_b, nullptr, N_A);
    run_gat(h1_a, h1_p, N_A, N_P, w_offs, w_csr, g2w_W, g2w_al, g2w_ar,
            Pa, wal, war, elb, erb, h2_p, 1, stream);
    run_gat(h1_p, h1_p, N_P, N_P, c_offs, c_csr, g2c_W, g2c_al, g2c_ar,
            Pa, wal, war, elb, erb, h2_p, 1, stream);
    run_gat(h1_p, h1_a, N_P, N_A, wb_offs, wb_csr, g2wb_W, g2wb_al, g2wb_ar,
            Pa, wal, war, elb, erb, h2_a, 1, stream);

    float* out = (float*)d_out;
    l2norm_kernel<<<((long)N_A * 64 + 255) / 256, 256, 0, stream>>>(h2_a, out, N_A);
    l2norm_kernel<<<((long)N_P * 64 + 255) / 256, 256, 0, stream>>>(h2_p, out + HA, N_P);
}

// Round 7
// 1330.769 us; speedup vs baseline: 4.0453x; 1.0947x over previous
//
#include <hip/hip_runtime.h>
#include <hip/hip_bf16.h>

#define N_A 50000
#define N_P 100000
#define E_W 1600000
#define E_C 3200000
#define HA (N_A*64)
#define HP (N_P*64)

// ---------------- tiled fp32 GEMM: out[M,64] = act(X[M,K] @ W^T + b) ----------------
__global__ __launch_bounds__(256) void gemm_tiled(const float* __restrict__ X,
        const float* __restrict__ W, const float* __restrict__ bias,
        void* __restrict__ out, int M, int K, int doRelu, int outBf16)
{
    __shared__ float Xs[32 * 132];
    __shared__ float Wsh[32 * 68];
    int tid = threadIdx.x;
    int bm0 = blockIdx.x * 128;
    int tx = tid & 15, ty = tid >> 4;

    float acc[8][4];
#pragma unroll
    for (int i = 0; i < 8; ++i)
#pragma unroll
        for (int j = 0; j < 4; ++j) acc[i][j] = 0.f;

    for (int k0 = 0; k0 < K; k0 += 32) {
#pragma unroll
        for (int it = 0; it < 4; ++it) {
            int row = (tid & 31) + 32 * it;
            int chunk = tid >> 5;
            int rg = bm0 + row; rg = rg < M ? rg : M - 1;
            const float4 v = *reinterpret_cast<const float4*>(&X[(long)rg * K + k0 + chunk * 4]);
            int kb = chunk * 4;
            Xs[(kb + 0) * 132 + row] = v.x;
            Xs[(kb + 1) * 132 + row] = v.y;
            Xs[(kb + 2) * 132 + row] = v.z;
            Xs[(kb + 3) * 132 + row] = v.w;
        }
#pragma unroll
        for (int it = 0; it < 2; ++it) {
            int n = tid & 63;
            int chunk = (tid >> 6) + 4 * it;
            const float4 v = *reinterpret_cast<const float4*>(&W[(long)n * K + k0 + chunk * 4]);
            int kb = chunk * 4;
            Wsh[(kb + 0) * 68 + n] = v.x;
            Wsh[(kb + 1) * 68 + n] = v.y;
            Wsh[(kb + 2) * 68 + n] = v.z;
            Wsh[(kb + 3) * 68 + n] = v.w;
        }
        __syncthreads();
#pragma unroll
        for (int k = 0; k < 32; ++k) {
            float4 a0 = *reinterpret_cast<const float4*>(&Xs[k * 132 + ty * 8]);
            float4 a1 = *reinterpret_cast<const float4*>(&Xs[k * 132 + ty * 8 + 4]);
            float4 b  = *reinterpret_cast<const float4*>(&Wsh[k * 68 + tx * 4]);
            float av[8] = {a0.x, a0.y, a0.z, a0.w, a1.x, a1.y, a1.z, a1.w};
            float bv[4] = {b.x, b.y, b.z, b.w};
#pragma unroll
            for (int i = 0; i < 8; ++i)
#pragma unroll
                for (int j = 0; j < 4; ++j)
                    acc[i][j] = fmaf(av[i], bv[j], acc[i][j]);
        }
        __syncthreads();
    }

    float bj[4] = {0.f, 0.f, 0.f, 0.f};
    if (bias) {
        bj[0] = bias[tx * 4 + 0]; bj[1] = bias[tx * 4 + 1];
        bj[2] = bias[tx * 4 + 2]; bj[3] = bias[tx * 4 + 3];
    }
#pragma unroll
    for (int i = 0; i < 8; ++i) {
        int r = bm0 + ty * 8 + i;
        if (r < M) {
            float o[4];
            o[0] = acc[i][0] + bj[0]; o[1] = acc[i][1] + bj[1];
            o[2] = acc[i][2] + bj[2]; o[3] = acc[i][3] + bj[3];
            if (doRelu) {
#pragma unroll
                for (int j = 0; j < 4; ++j) o[j] = fmaxf(o[j], 0.f);
            }
            if (outBf16) {
                ushort4 u;
                __hip_bfloat16 b0 = __float2bfloat16(o[0]);
                __hip_bfloat16 b1 = __float2bfloat16(o[1]);
                __hip_bfloat16 b2 = __float2bfloat16(o[2]);
                __hip_bfloat16 b3 = __float2bfloat16(o[3]);
                u.x = *reinterpret_cast<unsigned short*>(&b0);
                u.y = *reinterpret_cast<unsigned short*>(&b1);
                u.z = *reinterpret_cast<unsigned short*>(&b2);
                u.w = *reinterpret_cast<unsigned short*>(&b3);
                *reinterpret_cast<ushort4*>((unsigned short*)out + (long)r * 64 + tx * 4) = u;
            } else {
                float4 o4; o4.x = o[0]; o4.y = o[1]; o4.z = o[2]; o4.w = o[3];
                *reinterpret_cast<float4*>((float*)out + (long)r * 64 + tx * 4) = o4;
            }
        }
    }
}

// ---------------- attention vector folding ----------------
__global__ void prep_attn_kernel(const float* __restrict__ W, const float* __restrict__ al,
                                 const float* __restrict__ ar, float* __restrict__ wal,
                                 float* __restrict__ war, int H)
{
    int k = threadIdx.x;
    int F = 64 / H;
    for (int hh = 0; hh < H; ++hh) {
        float sl = 0.f, sr = 0.f;
        for (int f = 0; f < F; ++f) {
            float w = W[(hh * F + f) * 64 + k];
            sl = fmaf(w, al[hh * F + f], sl);
            sr = fmaf(w, ar[hh * F + f], sr);
        }
        wal[k * H + hh] = sl;
        war[k * H + hh] = sr;
    }
}

__global__ void attnvec_kernel(const float* __restrict__ h,
                               const float* __restrict__ wal, const float* __restrict__ war,
                               float* __restrict__ el, float* __restrict__ er, int N, int H)
{
    int node = (blockIdx.x << 2) | (threadIdx.x >> 6);
    int lane = threadIdx.x & 63;
    if (node >= N) return;
    float v = h[(long)node * 64 + lane];
    for (int hh = 0; hh < H; ++hh) {
        if (el) {
            float p = v * wal[lane * H + hh];
            for (int o = 1; o < 64; o <<= 1) p += __shfl_xor(p, o, 64);
            if (lane == hh) el[node * H + hh] = p;
        }
        if (er) {
            float p = v * war[lane * H + hh];
            for (int o = 1; o < 64; o <<= 1) p += __shfl_xor(p, o, 64);
            if (lane == hh) er[node * H + hh] = p;
        }
    }
}

// ---------------- CSR build: locality-aware bucket sort ----------------
__global__ void bucket_hist(const int* __restrict__ dst, int* __restrict__ bcnt,
                            int E, int NB, int shift)
{
    __shared__ int h[256];
    int tid = threadIdx.x;
    for (int i = tid; i < NB; i += 256) h[i] = 0;
    __syncthreads();
    for (long i = (long)blockIdx.x * 256 + tid; i < E; i += (long)gridDim.x * 256)
        atomicAdd(&h[dst[i] >> shift], 1);
    __syncthreads();
    for (int i = tid; i < NB; i += 256) atomicAdd(&bcnt[i], h[i]);
}

__global__ void bucket_scan(const int* __restrict__ bcnt, int* __restrict__ bstart,
                            int* __restrict__ gcur, int* __restrict__ offs,
                            int NB, int E, int N)
{
    __shared__ int sc[256];
    int tid = threadIdx.x;
    int v = (tid < NB) ? bcnt[tid] : 0;
    sc[tid] = v;
    __syncthreads();
    for (int off = 1; off < 256; off <<= 1) {
        int t = (tid >= off) ? sc[tid - off] : 0;
        __syncthreads();
        sc[tid] += t;
        __syncthreads();
    }
    int excl = sc[tid] - v;
    if (tid < NB) { bstart[tid] = excl; gcur[tid] = excl; }
    if (tid == 0) { bstart[NB] = E; offs[N] = E; }
}

#define EPT 8
__global__ __launch_bounds__(256) void part_kernel(const int* __restrict__ src,
        const int* __restrict__ dst, int* __restrict__ gcur,
        uint2* __restrict__ pairs, int E, int NB, int shift)
{
    __shared__ int hcnt[256];
    __shared__ int hbase[256];
    int tid = threadIdx.x;
    long base = (long)blockIdx.x * (256 * EPT);
    for (int i = tid; i < NB; i += 256) hcnt[i] = 0;
    __syncthreads();
    int b[EPT], r[EPT], s[EPT], d[EPT];
#pragma unroll
    for (int k = 0; k < EPT; ++k) {
        long idx = base + k * 256 + tid;
        if (idx < E) {
            s[k] = src[idx]; d[k] = dst[idx];
            b[k] = d[k] >> shift;
            r[k] = atomicAdd(&hcnt[b[k]], 1);
        } else b[k] = -1;
    }
    __syncthreads();
    for (int i = tid; i < NB; i += 256) hbase[i] = atomicAdd(&gcur[i], hcnt[i]);
    __syncthreads();
#pragma unroll
    for (int k = 0; k < EPT; ++k) {
        if (b[k] >= 0)
            pairs[hbase[b[k]] + r[k]] = make_uint2((unsigned)s[k], (unsigned)d[k]);
    }
}

__global__ __launch_bounds__(512) void csr_finalize(const uint2* __restrict__ pairs,
        const int* __restrict__ bstart, int* __restrict__ offs, int* __restrict__ csr,
        int N, int shift)
{
    __shared__ int cnt[512];
    __shared__ int sc[512];
    int tid = threadIdx.x;
    int b = blockIdx.x;
    int d0 = b << shift;
    int pS = bstart[b], pE = bstart[b + 1];
    cnt[tid] = 0;
    __syncthreads();
    for (int i = pS + tid; i < pE; i += 512)
        atomicAdd(&cnt[pairs[i].y - d0], 1);
    __syncthreads();
    int v = cnt[tid];
    sc[tid] = v;
    __syncthreads();
    for (int off = 1; off < 512; off <<= 1) {
        int t = (tid >= off) ? sc[tid - off] : 0;
        __syncthreads();
        sc[tid] += t;
        __syncthreads();
    }
    int excl = sc[tid] - v;
    if (d0 + tid < N) offs[d0 + tid] = pS + excl;
    cnt[tid] = excl;
    __syncthreads();
    for (int i = pS + tid; i < pE; i += 512) {
        uint2 u = pairs[i];
        int p = atomicAdd(&cnt[u.y - d0], 1);
        csr[pS + p] = (int)u.x;
    }
}

// ---------------- single-pass fused GAT aggregation ----------------
// acc = sum exp(v)*F[src]; s = sum exp(v); result = acc/s  (no max subtraction:
// logits are O(1), exact same softmax up to fp rounding).
// storeMode: write acc/s + bias0 (+bias1); n==0 writes bias. Else: RMW add.
__global__ void gat_csr_kernel(const int* __restrict__ offs, const int* __restrict__ csr,
                               const float* __restrict__ el, const float* __restrict__ er,
                               const unsigned short* __restrict__ Fsrc, float* __restrict__ rst,
                               int Nd, int hshift,
                               const float* __restrict__ bias0, const float* __restrict__ bias1)
{
    int d = (blockIdx.x << 2) | (threadIdx.x >> 6);
    int lane = threadIdx.x & 63;
    if (d >= Nd) return;
    int H = 1 << hshift;
    int off = offs[d];
    int n = offs[d + 1] - off;
    int g = lane >> 4;                                  // edge sub-slot for gather
    int fb = (lane & 15) * 4;                           // feature quad base
    int hf = (hshift == 2) ? ((lane & 15) >> 2) : 0;    // head of my feature quad

    if (n == 0) {
        if (bias0 && lane < 16) {
            float4 o;
            o.x = bias0[fb + 0]; o.y = bias0[fb + 1];
            o.z = bias0[fb + 2]; o.w = bias0[fb + 3];
            if (bias1) {
                o.x += bias1[fb + 0]; o.y += bias1[fb + 1];
                o.z += bias1[fb + 2]; o.w += bias1[fb + 3];
            }
            *reinterpret_cast<float4*>(&rst[(long)d * 64 + fb]) = o;
        }
        return;
    }

    int h = lane & (H - 1);
    float erd = er[d * H + h];
    int estep = 64 >> hshift;
    float acc0 = 0.f, acc1 = 0.f, acc2 = 0.f, acc3 = 0.f;
    float ssum = 0.f;

    for (int base = 0; base < n; base += estep) {
        // slot layout: lane computes exp-weight for edge base+(lane>>hshift), head lane&(H-1)
        int i = base + (lane >> hshift);
        int sn = 0; float a = 0.f;
        if (i < n) {
            sn = csr[off + i];
            float v = el[sn * H + h] + erd;
            v = v > 0.f ? v : 0.2f * v;
            a = __expf(v);
            ssum += a;
        }
        int rounds = min(estep, n - base);
        // micro-rounds: 4 edges each; lane<5:4> picks edge, lane<3:0> the feature quad
#pragma unroll 4
        for (int r = 0; r * 4 < rounds; ++r) {
            int sl = r * 4 + g;
            int lsn = sl << hshift;
            int s2 = __shfl(sn, lsn, 64);
            float a2 = __shfl(a, lsn | hf, 64);
            ushort4 u = *reinterpret_cast<const ushort4*>(&Fsrc[(long)s2 * 64 + fb]);
            acc0 = fmaf(__uint_as_float((unsigned)u.x << 16), a2, acc0);
            acc1 = fmaf(__uint_as_float((unsigned)u.y << 16), a2, acc1);
            acc2 = fmaf(__uint_as_float((unsigned)u.z << 16), a2, acc2);
            acc3 = fmaf(__uint_as_float((unsigned)u.w << 16), a2, acc3);
        }
    }

    // reduce ssum over slot bits (per head), then fetch my feature-quad's head total
    for (int o = H; o < 64; o <<= 1) ssum += __shfl_xor(ssum, o, 64);
    float rinv = 1.f / __shfl(ssum, hf, 64);

    // reduce accs over the 4 edge sub-slots (lane bits 4,5)
    acc0 += __shfl_xor(acc0, 16, 64); acc0 += __shfl_xor(acc0, 32, 64);
    acc1 += __shfl_xor(acc1, 16, 64); acc1 += __shfl_xor(acc1, 32, 64);
    acc2 += __shfl_xor(acc2, 16, 64); acc2 += __shfl_xor(acc2, 32, 64);
    acc3 += __shfl_xor(acc3, 16, 64); acc3 += __shfl_xor(acc3, 32, 64);
    if (lane < 16) {
        float4 o;
        if (bias0) {
            o.x = bias0[fb + 0]; o.y = bias0[fb + 1];
            o.z = bias0[fb + 2]; o.w = bias0[fb + 3];
            if (bias1) {
                o.x += bias1[fb + 0]; o.y += bias1[fb + 1];
                o.z += bias1[fb + 2]; o.w += bias1[fb + 3];
            }
        } else {
            o = *reinterpret_cast<float4*>(&rst[(long)d * 64 + fb]);
        }
        o.x = fmaf(acc0, rinv, o.x); o.y = fmaf(acc1, rinv, o.y);
        o.z = fmaf(acc2, rinv, o.z); o.w = fmaf(acc3, rinv, o.w);
        *reinterpret_cast<float4*>(&rst[(long)d * 64 + fb]) = o;
    }
}

__global__ void l2norm_kernel(const float* __restrict__ in, float* __restrict__ out, int N)
{
    long gt = (long)blockIdx.x * blockDim.x + threadIdx.x;
    int row = (int)(gt >> 6);
    int lane = threadIdx.x & 63;
    if (row >= N) return;
    float v = in[(long)row * 64 + lane];
    float ss = v * v;
    for (int off = 1; off < 64; off <<= 1) ss += __shfl_xor(ss, off, 64);
    out[(long)row * 64 + lane] = v / fmaxf(sqrtf(ss), 1e-12f);
}

// ---------------- host-side helpers ----------------
static void build_csr2(const int* src, const int* dst, int E, int N,
                       int* offs, int* csr, int* bcnt, int* bstart, int* gcur,
                       uint2* pairs, hipStream_t stream)
{
    const int SHIFT = 9;
    int NB = (N + 511) >> 9;
    hipMemsetAsync(bcnt, 0, NB * sizeof(int), stream);
    bucket_hist<<<512, 256, 0, stream>>>(dst, bcnt, E, NB, SHIFT);
    bucket_scan<<<1, 256, 0, stream>>>(bcnt, bstart, gcur, offs, NB, E, N);
    part_kernel<<<(E + 2047) / 2048, 256, 0, stream>>>(src, dst, gcur, pairs, E, NB, SHIFT);
    csr_finalize<<<NB, 512, 0, stream>>>(pairs, bstart, offs, csr, N, SHIFT);
}

static void run_gat(const float* h_src, const float* h_dst, int Ns, int Nd,
                    const int* offs, const int* csr,
                    const float* W, const float* al, const float* ar,
                    unsigned short* Psrc, float* wal, float* war,
                    float* el, float* er, float* rst, int H, hipStream_t stream,
                    const float* bias0, const float* bias1)
{
    prep_attn_kernel<<<1, 64, 0, stream>>>(W, al, ar, wal, war, H);
    gemm_tiled<<<(Ns + 127) / 128, 256, 0, stream>>>(h_src, W, nullptr, Psrc, Ns, 64, 0, 1);
    if (h_src == h_dst) {
        attnvec_kernel<<<(Ns + 3) / 4, 256, 0, stream>>>(h_src, wal, war, el, er, Ns, H);
    } else {
        attnvec_kernel<<<(Ns + 3) / 4, 256, 0, stream>>>(h_src, wal, nullptr, el, nullptr, Ns, H);
        attnvec_kernel<<<(Nd + 3) / 4, 256, 0, stream>>>(h_dst, nullptr, war, nullptr, er, Nd, H);
    }
    int hshift = (H == 4) ? 2 : 0;
    gat_csr_kernel<<<(Nd + 3) / 4, 256, 0, stream>>>(offs, csr, el, er, Psrc, rst, Nd, hshift,
                                                     bias0, bias1);
}

extern "C" void kernel_launch(void* const* d_in, const int* in_sizes, int n_in,
                              void* d_out, int out_size, void* d_ws, size_t ws_size,
                              hipStream_t stream)
{
    const float* feat_a = (const float*)d_in[0];
    const float* feat_p = (const float*)d_in[1];
    const float* fmWa = (const float*)d_in[2];
    const float* fmba = (const float*)d_in[3];
    const float* fmWp = (const float*)d_in[4];
    const float* fmbp = (const float*)d_in[5];
    const float* g1w_W = (const float*)d_in[6];  const float* g1w_al = (const float*)d_in[7];
    const float* g1w_ar = (const float*)d_in[8]; const float* g1w_b = (const float*)d_in[9];
    const float* g2w_W = (const float*)d_in[10]; const float* g2w_al = (const float*)d_in[11];
    const float* g2w_ar = (const float*)d_in[12]; const float* g2w_b = (const float*)d_in[13];
    const float* g1wb_W = (const float*)d_in[14]; const float* g1wb_al = (const float*)d_in[15];
    const float* g1wb_ar = (const float*)d_in[16]; const float* g1wb_b = (const float*)d_in[17];
    const float* g2wb_W = (const float*)d_in[18]; const float* g2wb_al = (const float*)d_in[19];
    const float* g2wb_ar = (const float*)d_in[20]; const float* g2wb_b = (const float*)d_in[21];
    const float* g1c_W = (const float*)d_in[22]; const float* g1c_al = (const float*)d_in[23];
    const float* g1c_ar = (const float*)d_in[24]; const float* g1c_b = (const float*)d_in[25];
    const float* g2c_W = (const float*)d_in[26]; const float* g2c_al = (const float*)d_in[27];
    const float* g2c_ar = (const float*)d_in[28]; const float* g2c_b = (const float*)d_in[29];
    const int* w_src = (const int*)d_in[30];
    const int* w_dst = (const int*)d_in[31];
    const int* wb_src = (const int*)d_in[32];
    const int* wb_dst = (const int*)d_in[33];
    const int* c_src = (const int*)d_in[34];
    const int* c_dst = (const int*)d_in[35];

    float* ws = (float*)d_ws;
    size_t off = 0;
    auto alloc = [&](size_t n) { float* p = ws + off; off += n; return p; };
    float* h_a  = alloc(HA);
    float* h_p  = alloc(HP);
    unsigned short* Pa = (unsigned short*)alloc(HP / 2 + 16);
    float* h1_p = alloc(HP);
    float* h1_a = alloc(HA);
    float* elb  = alloc((size_t)N_P * 4);
    float* erb  = alloc((size_t)N_P * 4);
    float* wal  = alloc(256);
    float* war  = alloc(256);
    int* w_offs  = (int*)alloc(N_P + 1);
    int* c_offs  = (int*)alloc(N_P + 1);
    int* wb_offs = (int*)alloc(N_A + 1);
    int* bcnt    = (int*)alloc(256);
    int* bstart  = (int*)alloc(260);
    int* gcur    = (int*)alloc(256);
    int* w_csr   = (int*)alloc(E_W);
    int* wb_csr  = (int*)alloc(E_W);
    int* c_csr   = (int*)alloc(E_C);
    off = (off + 1) & ~(size_t)1;
    uint2* pairs = (uint2*)alloc((size_t)E_C * 2);
    float* h2_p = h_p;
    float* h2_a = h_a;

    build_csr2(w_src, w_dst, E_W, N_P, w_offs, w_csr, bcnt, bstart, gcur, pairs, stream);
    build_csr2(c_src, c_dst, E_C, N_P, c_offs, c_csr, bcnt, bstart, gcur, pairs, stream);
    build_csr2(wb_src, wb_dst, E_W, N_A, wb_offs, wb_csr, bcnt, bstart, gcur, pairs, stream);

    gemm_tiled<<<(N_A + 127) / 128, 256, 0, stream>>>(feat_a, fmWa, fmba, h_a, N_A, 128, 1, 0);
    gemm_tiled<<<(N_P + 127) / 128, 256, 0, stream>>>(feat_p, fmWp, fmbp, h_p, N_P, 256, 1, 0);

    // ---- Layer 1 (H=4): writes (store, both biases) -> cites (RMW) -> written_by (store) ----
    run_gat(h_a, h_p, N_A, N_P, w_offs, w_csr, g1w_W, g1w_al, g1w_ar,
            Pa, wal, war, elb, erb, h1_p, 4, stream, g1w_b, g1c_b);
    run_gat(h_p, h_p, N_P, N_P, c_offs, c_csr, g1c_W, g1c_al, g1c_ar,
            Pa, wal, war, elb, erb, h1_p, 4, stream, nullptr, nullptr);
    run_gat(h_p, h_a, N_P, N_A, wb_offs, wb_csr, g1wb_W, g1wb_al, g1wb_ar,
            Pa, wal, war, elb, erb, h1_a, 4, stream, g1wb_b, nullptr);

    // ---- Layer 2 (H=1) ----
    run_gat(h1_a, h1_p, N_A, N_P, w_offs, w_csr, g2w_W, g2w_al, g2w_ar,
            Pa, wal, war, elb, erb, h2_p, 1, stream, g2w_b, g2c_b);
    run_gat(h1_p, h1_p, N_P, N_P, c_offs, c_csr, g2c_W, g2c_al, g2c_ar,
            Pa, wal, war, elb, erb, h2_p, 1, stream, nullptr, nullptr);
    run_gat(h1_p, h1_a, N_P, N_A, wb_offs, wb_csr, g2wb_W, g2wb_al, g2wb_ar,
            Pa, wal, war, elb, erb, h2_a, 1, stream, g2wb_b, nullptr);

    float* out = (float*)d_out;
    l2norm_kernel<<<((long)N_A * 64 + 255) / 256, 256, 0, stream>>>(h2_a, out, N_A);
    l2norm_kernel<<<((long)N_P * 64 + 255) / 256, 256, 0, stream>>>(h2_p, out + HA, N_P);
}

// Round 8
// 984.673 us; speedup vs baseline: 5.4671x; 1.3515x over previous
//
#include <hip/hip_runtime.h>
#include <hip/hip_bf16.h>

#define N_A 50000
#define N_P 100000
#define E_W 1600000
#define E_C 3200000
#define HA (N_A*64)
#define HP (N_P*64)

// ---------------- tiled fp32 GEMM with fused attention epilogue ----------------
// out[M,64] = act(X[M,K] @ W^T + b); if el: el[r,h] = sum_f fs*al (pre-bias acc);
// requires bias==null && doRelu==0 when el/er used (projection mode).
__global__ __launch_bounds__(256) void gemm_tiled(const float* __restrict__ X,
        const float* __restrict__ W, const float* __restrict__ bias,
        void* __restrict__ out, int M, int K, int doRelu, int outBf16,
        const float* __restrict__ al, float* __restrict__ el,
        const float* __restrict__ ar, float* __restrict__ er, int H)
{
    __shared__ float Xs[32 * 132];
    __shared__ float Wsh[32 * 68];
    int tid = threadIdx.x;
    int bm0 = blockIdx.x * 128;
    int tx = tid & 15, ty = tid >> 4;

    float acc[8][4];
#pragma unroll
    for (int i = 0; i < 8; ++i)
#pragma unroll
        for (int j = 0; j < 4; ++j) acc[i][j] = 0.f;

    for (int k0 = 0; k0 < K; k0 += 32) {
#pragma unroll
        for (int it = 0; it < 4; ++it) {
            int row = (tid & 31) + 32 * it;
            int chunk = tid >> 5;
            int rg = bm0 + row; rg = rg < M ? rg : M - 1;
            const float4 v = *reinterpret_cast<const float4*>(&X[(long)rg * K + k0 + chunk * 4]);
            int kb = chunk * 4;
            Xs[(kb + 0) * 132 + row] = v.x;
            Xs[(kb + 1) * 132 + row] = v.y;
            Xs[(kb + 2) * 132 + row] = v.z;
            Xs[(kb + 3) * 132 + row] = v.w;
        }
#pragma unroll
        for (int it = 0; it < 2; ++it) {
            int n = tid & 63;
            int chunk = (tid >> 6) + 4 * it;
            const float4 v = *reinterpret_cast<const float4*>(&W[(long)n * K + k0 + chunk * 4]);
            int kb = chunk * 4;
            Wsh[(kb + 0) * 68 + n] = v.x;
            Wsh[(kb + 1) * 68 + n] = v.y;
            Wsh[(kb + 2) * 68 + n] = v.z;
            Wsh[(kb + 3) * 68 + n] = v.w;
        }
        __syncthreads();
#pragma unroll
        for (int k = 0; k < 32; ++k) {
            float4 a0 = *reinterpret_cast<const float4*>(&Xs[k * 132 + ty * 8]);
            float4 a1 = *reinterpret_cast<const float4*>(&Xs[k * 132 + ty * 8 + 4]);
            float4 b  = *reinterpret_cast<const float4*>(&Wsh[k * 68 + tx * 4]);
            float av[8] = {a0.x, a0.y, a0.z, a0.w, a1.x, a1.y, a1.z, a1.w};
            float bv[4] = {b.x, b.y, b.z, b.w};
#pragma unroll
            for (int i = 0; i < 8; ++i)
#pragma unroll
                for (int j = 0; j < 4; ++j)
                    acc[i][j] = fmaf(av[i], bv[j], acc[i][j]);
        }
        __syncthreads();
    }

    float bj[4] = {0.f, 0.f, 0.f, 0.f};
    if (bias) {
        bj[0] = bias[tx * 4 + 0]; bj[1] = bias[tx * 4 + 1];
        bj[2] = bias[tx * 4 + 2]; bj[3] = bias[tx * 4 + 3];
    }
#pragma unroll
    for (int i = 0; i < 8; ++i) {
        int r = bm0 + ty * 8 + i;
        if (r < M) {
            float o[4];
            o[0] = acc[i][0] + bj[0]; o[1] = acc[i][1] + bj[1];
            o[2] = acc[i][2] + bj[2]; o[3] = acc[i][3] + bj[3];
            if (doRelu) {
#pragma unroll
                for (int j = 0; j < 4; ++j) o[j] = fmaxf(o[j], 0.f);
            }
            if (outBf16) {
                ushort4 u;
                __hip_bfloat16 b0 = __float2bfloat16(o[0]);
                __hip_bfloat16 b1 = __float2bfloat16(o[1]);
                __hip_bfloat16 b2 = __float2bfloat16(o[2]);
                __hip_bfloat16 b3 = __float2bfloat16(o[3]);
                u.x = *reinterpret_cast<unsigned short*>(&b0);
                u.y = *reinterpret_cast<unsigned short*>(&b1);
                u.z = *reinterpret_cast<unsigned short*>(&b2);
                u.w = *reinterpret_cast<unsigned short*>(&b3);
                *reinterpret_cast<ushort4*>((unsigned short*)out + (long)r * 64 + tx * 4) = u;
            } else {
                float4 o4; o4.x = o[0]; o4.y = o[1]; o4.z = o[2]; o4.w = o[3];
                *reinterpret_cast<float4*>((float*)out + (long)r * 64 + tx * 4) = o4;
            }
        }
    }

    // fused attention dot products (projection mode: acc == fs, no bias/relu)
    if (el) {
        float a0 = al[tx * 4 + 0], a1 = al[tx * 4 + 1], a2 = al[tx * 4 + 2], a3 = al[tx * 4 + 3];
#pragma unroll
        for (int i = 0; i < 8; ++i) {
            float p = acc[i][0] * a0 + acc[i][1] * a1 + acc[i][2] * a2 + acc[i][3] * a3;
            p += __shfl_xor(p, 1, 64);
            p += __shfl_xor(p, 2, 64);
            int r = bm0 + ty * 8 + i;
            if (H == 4) {
                if ((tx & 3) == 0 && r < M) el[r * 4 + (tx >> 2)] = p;
            } else {
                p += __shfl_xor(p, 4, 64);
                p += __shfl_xor(p, 8, 64);
                if (tx == 0 && r < M) el[r] = p;
            }
        }
    }
    if (er) {
        float a0 = ar[tx * 4 + 0], a1 = ar[tx * 4 + 1], a2 = ar[tx * 4 + 2], a3 = ar[tx * 4 + 3];
#pragma unroll
        for (int i = 0; i < 8; ++i) {
            float p = acc[i][0] * a0 + acc[i][1] * a1 + acc[i][2] * a2 + acc[i][3] * a3;
            p += __shfl_xor(p, 1, 64);
            p += __shfl_xor(p, 2, 64);
            int r = bm0 + ty * 8 + i;
            if (H == 4) {
                if ((tx & 3) == 0 && r < M) er[r * 4 + (tx >> 2)] = p;
            } else {
                p += __shfl_xor(p, 4, 64);
                p += __shfl_xor(p, 8, 64);
                if (tx == 0 && r < M) er[r] = p;
            }
        }
    }
}

// ---------------- batched fold of 4 war vectors ----------------
__global__ void prep_attn4(const float* __restrict__ W0, const float* __restrict__ r0,
                           float* __restrict__ o0, int H0,
                           const float* __restrict__ W1, const float* __restrict__ r1,
                           float* __restrict__ o1, int H1,
                           const float* __restrict__ W2, const float* __restrict__ r2,
                           float* __restrict__ o2, int H2,
                           const float* __restrict__ W3, const float* __restrict__ r3,
                           float* __restrict__ o3, int H3)
{
    int b = blockIdx.x;
    const float* W = b == 0 ? W0 : b == 1 ? W1 : b == 2 ? W2 : W3;
    const float* ar = b == 0 ? r0 : b == 1 ? r1 : b == 2 ? r2 : r3;
    float* war = b == 0 ? o0 : b == 1 ? o1 : b == 2 ? o2 : o3;
    int H = b == 0 ? H0 : b == 1 ? H1 : b == 2 ? H2 : H3;
    int k = threadIdx.x;
    int F = 64 / H;
    for (int hh = 0; hh < H; ++hh) {
        float s = 0.f;
        for (int f = 0; f < F; ++f)
            s = fmaf(W[(hh * F + f) * 64 + k], ar[hh * F + f], s);
        war[k * H + hh] = s;
    }
}

// er[i][h] = h_row . war[:,h]. One wave per node.
__global__ void attnvec_kernel(const float* __restrict__ h, const float* __restrict__ war,
                               float* __restrict__ er, int N, int H)
{
    int node = (blockIdx.x << 2) | (threadIdx.x >> 6);
    int lane = threadIdx.x & 63;
    if (node >= N) return;
    float v = h[(long)node * 64 + lane];
    for (int hh = 0; hh < H; ++hh) {
        float p = v * war[lane * H + hh];
        for (int o = 1; o < 64; o <<= 1) p += __shfl_xor(p, o, 64);
        if (lane == hh) er[node * H + hh] = p;
    }
}

// ---------------- CSR build: locality-aware bucket sort ----------------
__global__ void bucket_hist(const int* __restrict__ dst, int* __restrict__ bcnt,
                            int E, int NB, int shift)
{
    __shared__ int h[256];
    int tid = threadIdx.x;
    for (int i = tid; i < NB; i += 256) h[i] = 0;
    __syncthreads();
    for (long i = (long)blockIdx.x * 256 + tid; i < E; i += (long)gridDim.x * 256)
        atomicAdd(&h[dst[i] >> shift], 1);
    __syncthreads();
    for (int i = tid; i < NB; i += 256) atomicAdd(&bcnt[i], h[i]);
}

__global__ void bucket_scan(const int* __restrict__ bcnt, int* __restrict__ bstart,
                            int* __restrict__ gcur, int* __restrict__ offs,
                            int NB, int E, int N)
{
    __shared__ int sc[256];
    int tid = threadIdx.x;
    int v = (tid < NB) ? bcnt[tid] : 0;
    sc[tid] = v;
    __syncthreads();
    for (int off = 1; off < 256; off <<= 1) {
        int t = (tid >= off) ? sc[tid - off] : 0;
        __syncthreads();
        sc[tid] += t;
        __syncthreads();
    }
    int excl = sc[tid] - v;
    if (tid < NB) { bstart[tid] = excl; gcur[tid] = excl; }
    if (tid == 0) { bstart[NB] = E; offs[N] = E; }
}

#define EPT 8
__global__ __launch_bounds__(256) void part_kernel(const int* __restrict__ src,
        const int* __restrict__ dst, int* __restrict__ gcur,
        uint2* __restrict__ pairs, int E, int NB, int shift)
{
    __shared__ int hcnt[256];
    __shared__ int hbase[256];
    int tid = threadIdx.x;
    long base = (long)blockIdx.x * (256 * EPT);
    for (int i = tid; i < NB; i += 256) hcnt[i] = 0;
    __syncthreads();
    int b[EPT], r[EPT], s[EPT], d[EPT];
#pragma unroll
    for (int k = 0; k < EPT; ++k) {
        long idx = base + k * 256 + tid;
        if (idx < E) {
            s[k] = src[idx]; d[k] = dst[idx];
            b[k] = d[k] >> shift;
            r[k] = atomicAdd(&hcnt[b[k]], 1);
        } else b[k] = -1;
    }
    __syncthreads();
    for (int i = tid; i < NB; i += 256) hbase[i] = atomicAdd(&gcur[i], hcnt[i]);
    __syncthreads();
#pragma unroll
    for (int k = 0; k < EPT; ++k) {
        if (b[k] >= 0)
            pairs[hbase[b[k]] + r[k]] = make_uint2((unsigned)s[k], (unsigned)d[k]);
    }
}

__global__ __launch_bounds__(512) void csr_finalize(const uint2* __restrict__ pairs,
        const int* __restrict__ bstart, int* __restrict__ offs, int* __restrict__ csr,
        int N, int shift)
{
    __shared__ int cnt[512];
    __shared__ int sc[512];
    int tid = threadIdx.x;
    int b = blockIdx.x;
    int d0 = b << shift;
    int pS = bstart[b], pE = bstart[b + 1];
    cnt[tid] = 0;
    __syncthreads();
    for (int i = pS + tid; i < pE; i += 512)
        atomicAdd(&cnt[pairs[i].y - d0], 1);
    __syncthreads();
    int v = cnt[tid];
    sc[tid] = v;
    __syncthreads();
    for (int off = 1; off < 512; off <<= 1) {
        int t = (tid >= off) ? sc[tid - off] : 0;
        __syncthreads();
        sc[tid] += t;
        __syncthreads();
    }
    int excl = sc[tid] - v;
    if (d0 + tid < N) offs[d0 + tid] = pS + excl;
    cnt[tid] = excl;
    __syncthreads();
    for (int i = pS + tid; i < pE; i += 512) {
        uint2 u = pairs[i];
        int p = atomicAdd(&cnt[u.y - d0], 1);
        csr[pS + p] = (int)u.x;
    }
}

// ---------------- single-pass GAT aggregation: 8-edge micro-rounds ----------------
__global__ void gat_csr_kernel(const int* __restrict__ offs, const int* __restrict__ csr,
                               const float* __restrict__ el, const float* __restrict__ er,
                               const unsigned short* __restrict__ Fsrc, float* __restrict__ rst,
                               int Nd, int hshift,
                               const float* __restrict__ bias0, const float* __restrict__ bias1)
{
    int d = (blockIdx.x << 2) | (threadIdx.x >> 6);
    int lane = threadIdx.x & 63;
    if (d >= Nd) return;
    int H = 1 << hshift;
    int off = offs[d];
    int n = offs[d + 1] - off;
    int g8 = lane >> 3;                                 // edge sub-slot 0..7
    int fo = (lane & 7) * 8;                            // feature octet base
    int hf = (hshift == 2) ? ((lane & 7) >> 1) : 0;     // head of my octet

    if (n == 0) {
        if (bias0 && lane < 8) {
            float4 o0, o1;
            o0.x = bias0[fo + 0]; o0.y = bias0[fo + 1]; o0.z = bias0[fo + 2]; o0.w = bias0[fo + 3];
            o1.x = bias0[fo + 4]; o1.y = bias0[fo + 5]; o1.z = bias0[fo + 6]; o1.w = bias0[fo + 7];
            if (bias1) {
                o0.x += bias1[fo + 0]; o0.y += bias1[fo + 1]; o0.z += bias1[fo + 2]; o0.w += bias1[fo + 3];
                o1.x += bias1[fo + 4]; o1.y += bias1[fo + 5]; o1.z += bias1[fo + 6]; o1.w += bias1[fo + 7];
            }
            *reinterpret_cast<float4*>(&rst[(long)d * 64 + fo]) = o0;
            *reinterpret_cast<float4*>(&rst[(long)d * 64 + fo + 4]) = o1;
        }
        return;
    }

    int h = lane & (H - 1);
    float erd = er[d * H + h];
    int estep = 64 >> hshift;
    float acc[8];
#pragma unroll
    for (int q = 0; q < 8; ++q) acc[q] = 0.f;
    float ssum = 0.f;

    for (int base = 0; base < n; base += estep) {
        int i = base + (lane >> hshift);
        int sn = 0; float a = 0.f;
        if (i < n) {
            sn = csr[off + i];
            float v = el[sn * H + h] + erd;
            v = v > 0.f ? v : 0.2f * v;
            a = __expf(v);
            ssum += a;
        }
        int rounds = min(estep, n - base);
        // 8 edges per micro-round; lane<5:3> = edge, lane<2:0> = feature octet
#pragma unroll 2
        for (int r = 0; r * 8 < rounds; ++r) {
            int sl = r * 8 + g8;
            int lsn = sl << hshift;
            int s2 = __shfl(sn, lsn, 64);
            float a2 = __shfl(a, lsn | hf, 64);
            uint4 u = *reinterpret_cast<const uint4*>(&Fsrc[(long)s2 * 64 + fo]);
            acc[0] = fmaf(__uint_as_float(u.x << 16), a2, acc[0]);
            acc[1] = fmaf(__uint_as_float(u.x & 0xffff0000u), a2, acc[1]);
            acc[2] = fmaf(__uint_as_float(u.y << 16), a2, acc[2]);
            acc[3] = fmaf(__uint_as_float(u.y & 0xffff0000u), a2, acc[3]);
            acc[4] = fmaf(__uint_as_float(u.z << 16), a2, acc[4]);
            acc[5] = fmaf(__uint_as_float(u.z & 0xffff0000u), a2, acc[5]);
            acc[6] = fmaf(__uint_as_float(u.w << 16), a2, acc[6]);
            acc[7] = fmaf(__uint_as_float(u.w & 0xffff0000u), a2, acc[7]);
        }
    }

    for (int o = H; o < 64; o <<= 1) ssum += __shfl_xor(ssum, o, 64);
    float rinv = 1.f / __shfl(ssum, hf, 64);

#pragma unroll
    for (int q = 0; q < 8; ++q) {
        acc[q] += __shfl_xor(acc[q], 8, 64);
        acc[q] += __shfl_xor(acc[q], 16, 64);
        acc[q] += __shfl_xor(acc[q], 32, 64);
    }
    if (lane < 8) {
        float4 o0, o1;
        if (bias0) {
            o0.x = bias0[fo + 0]; o0.y = bias0[fo + 1]; o0.z = bias0[fo + 2]; o0.w = bias0[fo + 3];
            o1.x = bias0[fo + 4]; o1.y = bias0[fo + 5]; o1.z = bias0[fo + 6]; o1.w = bias0[fo + 7];
            if (bias1) {
                o0.x += bias1[fo + 0]; o0.y += bias1[fo + 1]; o0.z += bias1[fo + 2]; o0.w += bias1[fo + 3];
                o1.x += bias1[fo + 4]; o1.y += bias1[fo + 5]; o1.z += bias1[fo + 6]; o1.w += bias1[fo + 7];
            }
        } else {
            o0 = *reinterpret_cast<float4*>(&rst[(long)d * 64 + fo]);
            o1 = *reinterpret_cast<float4*>(&rst[(long)d * 64 + fo + 4]);
        }
        o0.x = fmaf(acc[0], rinv, o0.x); o0.y = fmaf(acc[1], rinv, o0.y);
        o0.z = fmaf(acc[2], rinv, o0.z); o0.w = fmaf(acc[3], rinv, o0.w);
        o1.x = fmaf(acc[4], rinv, o1.x); o1.y = fmaf(acc[5], rinv, o1.y);
        o1.z = fmaf(acc[6], rinv, o1.z); o1.w = fmaf(acc[7], rinv, o1.w);
        *reinterpret_cast<float4*>(&rst[(long)d * 64 + fo]) = o0;
        *reinterpret_cast<float4*>(&rst[(long)d * 64 + fo + 4]) = o1;
    }
}

__global__ void l2norm_kernel(const float* __restrict__ in, float* __restrict__ out, int N)
{
    long gt = (long)blockIdx.x * blockDim.x + threadIdx.x;
    int row = (int)(gt >> 6);
    int lane = threadIdx.x & 63;
    if (row >= N) return;
    float v = in[(long)row * 64 + lane];
    float ss = v * v;
    for (int off = 1; off < 64; off <<= 1) ss += __shfl_xor(ss, off, 64);
    out[(long)row * 64 + lane] = v / fmaxf(sqrtf(ss), 1e-12f);
}

// ---------------- host-side helpers ----------------
static void build_csr2(const int* src, const int* dst, int E, int N,
                       int* offs, int* csr, int* bcnt, int* bstart, int* gcur,
                       uint2* pairs, hipStream_t stream)
{
    const int SHIFT = 9;
    int NB = (N + 511) >> 9;
    hipMemsetAsync(bcnt, 0, NB * sizeof(int), stream);
    bucket_hist<<<512, 256, 0, stream>>>(dst, bcnt, E, NB, SHIFT);
    bucket_scan<<<1, 256, 0, stream>>>(bcnt, bstart, gcur, offs, NB, E, N);
    part_kernel<<<(E + 2047) / 2048, 256, 0, stream>>>(src, dst, gcur, pairs, E, NB, SHIFT);
    csr_finalize<<<NB, 512, 0, stream>>>(pairs, bstart, offs, csr, N, SHIFT);
}

// war: precomputed fold vector for dst side (null when src==dst -> fused in gemm)
static void run_gat(const float* h_src, const float* h_dst, int Ns, int Nd,
                    const int* offs, const int* csr,
                    const float* al, const float* ar, const float* war,
                    const float* W, unsigned short* Psrc,
                    float* el, float* er, float* rst, int H, hipStream_t stream,
                    const float* bias0, const float* bias1)
{
    if (h_src == h_dst) {
        gemm_tiled<<<(Ns + 127) / 128, 256, 0, stream>>>(h_src, W, nullptr, Psrc, Ns, 64, 0, 1,
                                                         al, el, ar, er, H);
    } else {
        gemm_tiled<<<(Ns + 127) / 128, 256, 0, stream>>>(h_src, W, nullptr, Psrc, Ns, 64, 0, 1,
                                                         al, el, nullptr, nullptr, H);
        attnvec_kernel<<<(Nd + 3) / 4, 256, 0, stream>>>(h_dst, war, er, Nd, H);
    }
    int hshift = (H == 4) ? 2 : 0;
    gat_csr_kernel<<<(Nd + 3) / 4, 256, 0, stream>>>(offs, csr, el, er, Psrc, rst, Nd, hshift,
                                                     bias0, bias1);
}

extern "C" void kernel_launch(void* const* d_in, const int* in_sizes, int n_in,
                              void* d_out, int out_size, void* d_ws, size_t ws_size,
                              hipStream_t stream)
{
    const float* feat_a = (const float*)d_in[0];
    const float* feat_p = (const float*)d_in[1];
    const float* fmWa = (const float*)d_in[2];
    const float* fmba = (const float*)d_in[3];
    const float* fmWp = (const float*)d_in[4];
    const float* fmbp = (const float*)d_in[5];
    const float* g1w_W = (const float*)d_in[6];  const float* g1w_al = (const float*)d_in[7];
    const float* g1w_ar = (const float*)d_in[8]; const float* g1w_b = (const float*)d_in[9];
    const float* g2w_W = (const float*)d_in[10]; const float* g2w_al = (const float*)d_in[11];
    const float* g2w_ar = (const float*)d_in[12]; const float* g2w_b = (const float*)d_in[13];
    const float* g1wb_W = (const float*)d_in[14]; const float* g1wb_al = (const float*)d_in[15];
    const float* g1wb_ar = (const float*)d_in[16]; const float* g1wb_b = (const float*)d_in[17];
    const float* g2wb_W = (const float*)d_in[18]; const float* g2wb_al = (const float*)d_in[19];
    const float* g2wb_ar = (const float*)d_in[20]; const float* g2wb_b = (const float*)d_in[21];
    const float* g1c_W = (const float*)d_in[22]; const float* g1c_al = (const float*)d_in[23];
    const float* g1c_ar = (const float*)d_in[24]; const float* g1c_b = (const float*)d_in[25];
    const float* g2c_W = (const float*)d_in[26]; const float* g2c_al = (const float*)d_in[27];
    const float* g2c_ar = (const float*)d_in[28]; const float* g2c_b = (const float*)d_in[29];
    const int* w_src = (const int*)d_in[30];
    const int* w_dst = (const int*)d_in[31];
    const int* wb_src = (const int*)d_in[32];
    const int* wb_dst = (const int*)d_in[33];
    const int* c_src = (const int*)d_in[34];
    const int* c_dst = (const int*)d_in[35];

    float* ws = (float*)d_ws;
    size_t off = 0;
    auto alloc = [&](size_t n) { float* p = ws + off; off += n; return p; };
    float* h_a  = alloc(HA);
    float* h_p  = alloc(HP);
    unsigned short* Pa = (unsigned short*)alloc(HP / 2 + 16);
    float* h1_p = alloc(HP);
    float* h1_a = alloc(HA);
    float* elb  = alloc((size_t)N_P * 4);
    float* erb  = alloc((size_t)N_P * 4);
    float* war_w1  = alloc(256);
    float* war_wb1 = alloc(256);
    float* war_w2  = alloc(256);
    float* war_wb2 = alloc(256);
    int* w_offs  = (int*)alloc(N_P + 1);
    int* c_offs  = (int*)alloc(N_P + 1);
    int* wb_offs = (int*)alloc(N_A + 1);
    int* bcnt    = (int*)alloc(256);
    int* bstart  = (int*)alloc(260);
    int* gcur    = (int*)alloc(256);
    int* w_csr   = (int*)alloc(E_W);
    int* wb_csr  = (int*)alloc(E_W);
    int* c_csr   = (int*)alloc(E_C);
    off = (off + 1) & ~(size_t)1;
    uint2* pairs = (uint2*)alloc((size_t)E_C * 2);
    float* h2_p = h_p;
    float* h2_a = h_a;

    build_csr2(w_src, w_dst, E_W, N_P, w_offs, w_csr, bcnt, bstart, gcur, pairs, stream);
    build_csr2(c_src, c_dst, E_C, N_P, c_offs, c_csr, bcnt, bstart, gcur, pairs, stream);
    build_csr2(wb_src, wb_dst, E_W, N_A, wb_offs, wb_csr, bcnt, bstart, gcur, pairs, stream);

    // fold war vectors for the 4 dst-side (non-self) er computations
    prep_attn4<<<4, 64, 0, stream>>>(g1w_W, g1w_ar, war_w1, 4,
                                     g1wb_W, g1wb_ar, war_wb1, 4,
                                     g2w_W, g2w_ar, war_w2, 1,
                                     g2wb_W, g2wb_ar, war_wb2, 1);

    gemm_tiled<<<(N_A + 127) / 128, 256, 0, stream>>>(feat_a, fmWa, fmba, h_a, N_A, 128, 1, 0,
                                                      nullptr, nullptr, nullptr, nullptr, 4);
    gemm_tiled<<<(N_P + 127) / 128, 256, 0, stream>>>(feat_p, fmWp, fmbp, h_p, N_P, 256, 1, 0,
                                                      nullptr, nullptr, nullptr, nullptr, 4);

    // ---- Layer 1 (H=4): writes (store both biases) -> cites (RMW) -> written_by (store) ----
    run_gat(h_a, h_p, N_A, N_P, w_offs, w_csr, g1w_al, g1w_ar, war_w1, g1w_W,
            Pa, elb, erb, h1_p, 4, stream, g1w_b, g1c_b);
    run_gat(h_p, h_p, N_P, N_P, c_offs, c_csr, g1c_al, g1c_ar, nullptr, g1c_W,
            Pa, elb, erb, h1_p, 4, stream, nullptr, nullptr);
    run_gat(h_p, h_a, N_P, N_A, wb_offs, wb_csr, g1wb_al, g1wb_ar, war_wb1, g1wb_W,
            Pa, elb, erb, h1_a, 4, stream, g1wb_b, nullptr);

    // ---- Layer 2 (H=1) ----
    run_gat(h1_a, h1_p, N_A, N_P, w_offs, w_csr, g2w_al, g2w_ar, war_w2, g2w_W,
            Pa, elb, erb, h2_p, 1, stream, g2w_b, g2c_b);
    run_gat(h1_p, h1_p, N_P, N_P, c_offs, c_csr, g2c_al, g2c_ar, nullptr, g2c_W,
            Pa, elb, erb, h2_p, 1, stream, nullptr, nullptr);
    run_gat(h1_p, h1_a, N_P, N_A, wb_offs, wb_csr, g2wb_al, g2wb_ar, war_wb2, g2wb_W,
            Pa, elb, erb, h2_a, 1, stream, g2wb_b, nullptr);

    float* out = (float*)d_out;
    l2norm_kernel<<<((long)N_A * 64 + 255) / 256, 256, 0, stream>>>(h2_a, out, N_A);
    l2norm_kernel<<<((long)N_P * 64 + 255) / 256, 256, 0, stream>>>(h2_p, out + HA, N_P);
}

// Round 9
// 942.566 us; speedup vs baseline: 5.7113x; 1.0447x over previous
//
#include <hip/hip_runtime.h>
#include <hip/hip_bf16.h>

#define N_A 50000
#define N_P 100000
#define E_W 1600000
#define E_C 3200000
#define HA (N_A*64)
#define HP (N_P*64)

typedef __attribute__((ext_vector_type(8))) short short8_t;
typedef __attribute__((ext_vector_type(4))) float f32x4;

__device__ __forceinline__ unsigned short f2b(float f)
{
    __hip_bfloat16 b = __float2bfloat16(f);
    return *reinterpret_cast<unsigned short*>(&b);
}

// ---------------- MFMA GEMM: out[M,64] = act(X[M,K](fp32) @ W[64,K]^T + b) ----------------
// BM=128, 256 threads = 4 waves; wave: 32 rows x 64 cols (2x4 16x16 tiles); K chunks of 64.
__global__ __launch_bounds__(256) void gemm_mfma(const float* __restrict__ X,
        const float* __restrict__ W, const float* __restrict__ bias,
        void* __restrict__ out, int M, int K, int doRelu, int outBf16)
{
    __shared__ unsigned short Xs[128][72];   // bf16, stride 72 (bank-safe, 16B aligned rows)
    __shared__ unsigned short Wsh[64][72];
    int tid = threadIdx.x, lane = tid & 63, wv = tid >> 6;
    int row0 = blockIdx.x * 128;
    int m = lane & 15, kb = lane >> 4;

    f32x4 acc[2][4];
#pragma unroll
    for (int rb = 0; rb < 2; ++rb)
#pragma unroll
        for (int cb = 0; cb < 4; ++cb) acc[rb][cb] = (f32x4){0.f, 0.f, 0.f, 0.f};

    for (int k0 = 0; k0 < K; k0 += 64) {
        {   // stage X tile (128x64) fp32 -> bf16
            int rbase = (tid >> 4) * 8;
            int c4 = (tid & 15) * 4;
#pragma unroll
            for (int i = 0; i < 8; ++i) {
                int rg = row0 + rbase + i; if (rg >= M) rg = M - 1;
                float4 v = *reinterpret_cast<const float4*>(&X[(long)rg * K + k0 + c4]);
                Xs[rbase + i][c4 + 0] = f2b(v.x);
                Xs[rbase + i][c4 + 1] = f2b(v.y);
                Xs[rbase + i][c4 + 2] = f2b(v.z);
                Xs[rbase + i][c4 + 3] = f2b(v.w);
            }
            // stage W chunk (64x64)
            int wr = tid >> 2;
            int wc = (tid & 3) * 16;
#pragma unroll
            for (int q = 0; q < 4; ++q) {
                float4 v = *reinterpret_cast<const float4*>(&W[(long)wr * K + k0 + wc + q * 4]);
                Wsh[wr][wc + q * 4 + 0] = f2b(v.x);
                Wsh[wr][wc + q * 4 + 1] = f2b(v.y);
                Wsh[wr][wc + q * 4 + 2] = f2b(v.z);
                Wsh[wr][wc + q * 4 + 3] = f2b(v.w);
            }
        }
        __syncthreads();
#pragma unroll
        for (int kc = 0; kc < 2; ++kc) {
            short8_t a0 = *reinterpret_cast<const short8_t*>(&Xs[wv * 32 + m][kc * 32 + kb * 8]);
            short8_t a1 = *reinterpret_cast<const short8_t*>(&Xs[wv * 32 + 16 + m][kc * 32 + kb * 8]);
#pragma unroll
            for (int cb = 0; cb < 4; ++cb) {
                short8_t b = *reinterpret_cast<const short8_t*>(&Wsh[cb * 16 + m][kc * 32 + kb * 8]);
                acc[0][cb] = __builtin_amdgcn_mfma_f32_16x16x32_bf16(a0, b, acc[0][cb], 0, 0, 0);
                acc[1][cb] = __builtin_amdgcn_mfma_f32_16x16x32_bf16(a1, b, acc[1][cb], 0, 0, 0);
            }
        }
        __syncthreads();
    }

#pragma unroll
    for (int rb = 0; rb < 2; ++rb)
#pragma unroll
    for (int j = 0; j < 4; ++j) {
        int r = row0 + wv * 32 + rb * 16 + (lane >> 4) * 4 + j;
        if (r < M) {
#pragma unroll
            for (int cb = 0; cb < 4; ++cb) {
                int c = cb * 16 + m;
                float v = acc[rb][cb][j];
                if (bias) v += bias[c];
                if (doRelu) v = fmaxf(v, 0.f);
                if (outBf16) ((unsigned short*)out)[(long)r * 64 + c] = f2b(v);
                else         ((float*)out)[(long)r * 64 + c] = v;
            }
        }
    }
}

// ---------------- fold W*a for 12 attention vectors ----------------
struct PA { const float* W; const float* a; float* o; int H; };
__global__ void prep_attn12(PA p0, PA p1, PA p2, PA p3, PA p4, PA p5,
                            PA p6, PA p7, PA p8, PA p9, PA p10, PA p11)
{
    PA p;
    switch (blockIdx.x) {
        case 0: p = p0; break;  case 1: p = p1; break;  case 2: p = p2; break;
        case 3: p = p3; break;  case 4: p = p4; break;  case 5: p = p5; break;
        case 6: p = p6; break;  case 7: p = p7; break;  case 8: p = p8; break;
        case 9: p = p9; break;  case 10: p = p10; break; default: p = p11; break;
    }
    int k = threadIdx.x;
    int F = 64 / p.H;
    for (int hh = 0; hh < p.H; ++hh) {
        float s = 0.f;
        for (int f = 0; f < F; ++f)
            s = fmaf(p.W[(hh * F + f) * 64 + k], p.a[hh * F + f], s);
        p.o[k * p.H + hh] = s;
    }
}

__device__ __forceinline__ void fold_store(float v, const float* __restrict__ wvec,
                                           float* __restrict__ o, int node, int H, int lane)
{
    for (int hh = 0; hh < H; ++hh) {
        float p = v * wvec[lane * H + hh];
        for (int off = 1; off < 64; off <<= 1) p += __shfl_xor(p, off, 64);
        if (lane == hh) o[node * H + hh] = p;
    }
}

// one dispatch: 4 folds over hP (papers) + 2 folds over hA (authors)
__global__ void attnvec6(const float* __restrict__ hP, int NPn,
        const float* __restrict__ v0, float* __restrict__ o0,
        const float* __restrict__ v1, float* __restrict__ o1,
        const float* __restrict__ v2, float* __restrict__ o2,
        const float* __restrict__ v3, float* __restrict__ o3,
        const float* __restrict__ hA, int NAn,
        const float* __restrict__ v4, float* __restrict__ o4,
        const float* __restrict__ v5, float* __restrict__ o5, int H)
{
    int blocksP = (NPn + 3) >> 2;
    int lane = threadIdx.x & 63;
    int sub = threadIdx.x >> 6;
    if ((int)blockIdx.x < blocksP) {
        int node = ((int)blockIdx.x << 2) | sub;
        if (node >= NPn) return;
        float v = hP[(long)node * 64 + lane];
        fold_store(v, v0, o0, node, H, lane);
        fold_store(v, v1, o1, node, H, lane);
        fold_store(v, v2, o2, node, H, lane);
        fold_store(v, v3, o3, node, H, lane);
    } else {
        int node = (((int)blockIdx.x - blocksP) << 2) | sub;
        if (node >= NAn) return;
        float v = hA[(long)node * 64 + lane];
        fold_store(v, v4, o4, node, H, lane);
        fold_store(v, v5, o5, node, H, lane);
    }
}

// ---------------- CSR build: locality-aware bucket sort (batched hist/scan) ----------------
__global__ void bucket_hist3(const int* __restrict__ d0, int E0, int* __restrict__ b0,
                             const int* __restrict__ d1, int E1, int* __restrict__ b1,
                             const int* __restrict__ d2, int E2, int* __restrict__ b2,
                             int shift, int blocksPer)
{
    int g = blockIdx.x / blocksPer, bb = blockIdx.x - g * blocksPer;
    const int* dst = g == 0 ? d0 : g == 1 ? d1 : d2;
    int E = g == 0 ? E0 : g == 1 ? E1 : E2;
    int* bcnt = g == 0 ? b0 : g == 1 ? b1 : b2;
    __shared__ int h[256];
    int tid = threadIdx.x;
    h[tid] = 0;
    __syncthreads();
    for (long i = (long)bb * 256 + tid; i < E; i += (long)blocksPer * 256)
        atomicAdd(&h[dst[i] >> shift], 1);
    __syncthreads();
    if (h[tid]) atomicAdd(&bcnt[tid], h[tid]);
}

__global__ void bucket_scan3(int* __restrict__ bcnt, int* __restrict__ bstart,
                             int* __restrict__ gcur,
                             int* __restrict__ o0, int Nn0, int Ee0,
                             int* __restrict__ o1, int Nn1, int Ee1,
                             int* __restrict__ o2, int Nn2, int Ee2)
{
    int g = blockIdx.x;
    int* bc = bcnt + g * 256;
    int* bs = bstart + g * 257;
    int* gc = gcur + g * 256;
    int* offs = g == 0 ? o0 : g == 1 ? o1 : o2;
    int N = g == 0 ? Nn0 : g == 1 ? Nn1 : Nn2;
    int E = g == 0 ? Ee0 : g == 1 ? Ee1 : Ee2;
    __shared__ int sc[256];
    int tid = threadIdx.x;
    int v = bc[tid];
    sc[tid] = v;
    __syncthreads();
    for (int off = 1; off < 256; off <<= 1) {
        int t = (tid >= off) ? sc[tid - off] : 0;
        __syncthreads();
        sc[tid] += t;
        __syncthreads();
    }
    int excl = sc[tid] - v;
    bs[tid] = excl;
    gc[tid] = excl;
    if (tid == 255) bs[256] = E;
    if (tid == 0) offs[N] = E;
}

#define EPT 8
__global__ __launch_bounds__(256) void part_kernel(const int* __restrict__ src,
        const int* __restrict__ dst, int* __restrict__ gcur,
        uint2* __restrict__ pairs, int E, int NB, int shift)
{
    __shared__ int hcnt[256];
    __shared__ int hbase[256];
    int tid = threadIdx.x;
    long base = (long)blockIdx.x * (256 * EPT);
    for (int i = tid; i < NB; i += 256) hcnt[i] = 0;
    __syncthreads();
    int b[EPT], r[EPT], s[EPT], d[EPT];
#pragma unroll
    for (int k = 0; k < EPT; ++k) {
        long idx = base + k * 256 + tid;
        if (idx < E) {
            s[k] = src[idx]; d[k] = dst[idx];
            b[k] = d[k] >> shift;
            r[k] = atomicAdd(&hcnt[b[k]], 1);
        } else b[k] = -1;
    }
    __syncthreads();
    for (int i = tid; i < NB; i += 256) {
        if (hcnt[i]) hbase[i] = atomicAdd(&gcur[i], hcnt[i]);
    }
    __syncthreads();
#pragma unroll
    for (int k = 0; k < EPT; ++k) {
        if (b[k] >= 0)
            pairs[hbase[b[k]] + r[k]] = make_uint2((unsigned)s[k], (unsigned)d[k]);
    }
}

__global__ __launch_bounds__(512) void csr_finalize(const uint2* __restrict__ pairs,
        const int* __restrict__ bstart, int* __restrict__ offs, int* __restrict__ csr,
        int N, int shift)
{
    __shared__ int cnt[512];
    __shared__ int sc[512];
    int tid = threadIdx.x;
    int b = blockIdx.x;
    int d0 = b << shift;
    int pS = bstart[b], pE = bstart[b + 1];
    cnt[tid] = 0;
    __syncthreads();
    for (int i = pS + tid; i < pE; i += 512)
        atomicAdd(&cnt[pairs[i].y - d0], 1);
    __syncthreads();
    int v = cnt[tid];
    sc[tid] = v;
    __syncthreads();
    for (int off = 1; off < 512; off <<= 1) {
        int t = (tid >= off) ? sc[tid - off] : 0;
        __syncthreads();
        sc[tid] += t;
        __syncthreads();
    }
    int excl = sc[tid] - v;
    if (d0 + tid < N) offs[d0 + tid] = pS + excl;
    cnt[tid] = excl;
    __syncthreads();
    for (int i = pS + tid; i < pE; i += 512) {
        uint2 u = pairs[i];
        int p = atomicAdd(&cnt[u.y - d0], 1);
        csr[pS + p] = (int)u.x;
    }
}

// ---------------- single-pass GAT aggregation: 8-edge micro-rounds ----------------
__global__ void gat_csr_kernel(const int* __restrict__ offs, const int* __restrict__ csr,
                               const float* __restrict__ el, const float* __restrict__ er,
                               const unsigned short* __restrict__ Fsrc, float* __restrict__ rst,
                               int Nd, int hshift,
                               const float* __restrict__ bias0, const float* __restrict__ bias1)
{
    int d = (blockIdx.x << 2) | (threadIdx.x >> 6);
    int lane = threadIdx.x & 63;
    if (d >= Nd) return;
    int H = 1 << hshift;
    int off = offs[d];
    int n = offs[d + 1] - off;
    int g8 = lane >> 3;
    int fo = (lane & 7) * 8;
    int hf = (hshift == 2) ? ((lane & 7) >> 1) : 0;

    if (n == 0) {
        if (bias0 && lane < 8) {
            float4 o0, o1;
            o0.x = bias0[fo + 0]; o0.y = bias0[fo + 1]; o0.z = bias0[fo + 2]; o0.w = bias0[fo + 3];
            o1.x = bias0[fo + 4]; o1.y = bias0[fo + 5]; o1.z = bias0[fo + 6]; o1.w = bias0[fo + 7];
            if (bias1) {
                o0.x += bias1[fo + 0]; o0.y += bias1[fo + 1]; o0.z += bias1[fo + 2]; o0.w += bias1[fo + 3];
                o1.x += bias1[fo + 4]; o1.y += bias1[fo + 5]; o1.z += bias1[fo + 6]; o1.w += bias1[fo + 7];
            }
            *reinterpret_cast<float4*>(&rst[(long)d * 64 + fo]) = o0;
            *reinterpret_cast<float4*>(&rst[(long)d * 64 + fo + 4]) = o1;
        }
        return;
    }

    int h = lane & (H - 1);
    float erd = er[d * H + h];
    int estep = 64 >> hshift;
    float acc[8];
#pragma unroll
    for (int q = 0; q < 8; ++q) acc[q] = 0.f;
    float ssum = 0.f;

    for (int base = 0; base < n; base += estep) {
        int i = base + (lane >> hshift);
        int sn = 0; float a = 0.f;
        if (i < n) {
            sn = csr[off + i];
            float v = el[sn * H + h] + erd;
            v = v > 0.f ? v : 0.2f * v;
            a = __expf(v);
            ssum += a;
        }
        int rounds = min(estep, n - base);
#pragma unroll 2
        for (int r = 0; r * 8 < rounds; ++r) {
            int sl = r * 8 + g8;
            int lsn = sl << hshift;
            int s2 = __shfl(sn, lsn, 64);
            float a2 = __shfl(a, lsn | hf, 64);
            uint4 u = *reinterpret_cast<const uint4*>(&Fsrc[(long)s2 * 64 + fo]);
            acc[0] = fmaf(__uint_as_float(u.x << 16), a2, acc[0]);
            acc[1] = fmaf(__uint_as_float(u.x & 0xffff0000u), a2, acc[1]);
            acc[2] = fmaf(__uint_as_float(u.y << 16), a2, acc[2]);
            acc[3] = fmaf(__uint_as_float(u.y & 0xffff0000u), a2, acc[3]);
            acc[4] = fmaf(__uint_as_float(u.z << 16), a2, acc[4]);
            acc[5] = fmaf(__uint_as_float(u.z & 0xffff0000u), a2, acc[5]);
            acc[6] = fmaf(__uint_as_float(u.w << 16), a2, acc[6]);
            acc[7] = fmaf(__uint_as_float(u.w & 0xffff0000u), a2, acc[7]);
        }
    }

    for (int o = H; o < 64; o <<= 1) ssum += __shfl_xor(ssum, o, 64);
    float rinv = 1.f / __shfl(ssum, hf, 64);

#pragma unroll
    for (int q = 0; q < 8; ++q) {
        acc[q] += __shfl_xor(acc[q], 8, 64);
        acc[q] += __shfl_xor(acc[q], 16, 64);
        acc[q] += __shfl_xor(acc[q], 32, 64);
    }
    if (lane < 8) {
        float4 o0, o1;
        if (bias0) {
            o0.x = bias0[fo + 0]; o0.y = bias0[fo + 1]; o0.z = bias0[fo + 2]; o0.w = bias0[fo + 3];
            o1.x = bias0[fo + 4]; o1.y = bias0[fo + 5]; o1.z = bias0[fo + 6]; o1.w = bias0[fo + 7];
            if (bias1) {
                o0.x += bias1[fo + 0]; o0.y += bias1[fo + 1]; o0.z += bias1[fo + 2]; o0.w += bias1[fo + 3];
                o1.x += bias1[fo + 4]; o1.y += bias1[fo + 5]; o1.z += bias1[fo + 6]; o1.w += bias1[fo + 7];
            }
        } else {
            o0 = *reinterpret_cast<float4*>(&rst[(long)d * 64 + fo]);
            o1 = *reinterpret_cast<float4*>(&rst[(long)d * 64 + fo + 4]);
        }
        o0.x = fmaf(acc[0], rinv, o0.x); o0.y = fmaf(acc[1], rinv, o0.y);
        o0.z = fmaf(acc[2], rinv, o0.z); o0.w = fmaf(acc[3], rinv, o0.w);
        o1.x = fmaf(acc[4], rinv, o1.x); o1.y = fmaf(acc[5], rinv, o1.y);
        o1.z = fmaf(acc[6], rinv, o1.z); o1.w = fmaf(acc[7], rinv, o1.w);
        *reinterpret_cast<float4*>(&rst[(long)d * 64 + fo]) = o0;
        *reinterpret_cast<float4*>(&rst[(long)d * 64 + fo + 4]) = o1;
    }
}

// merged L2-normalize of both outputs (authors rows [0,N_A), papers after)
__global__ void l2norm2(const float* __restrict__ inA, const float* __restrict__ inP,
                        float* __restrict__ out, int NAn, int NPn)
{
    long gt = (long)blockIdx.x * blockDim.x + threadIdx.x;
    int row = (int)(gt >> 6);
    int lane = threadIdx.x & 63;
    if (row >= NAn + NPn) return;
    float v = (row < NAn) ? inA[(long)row * 64 + lane]
                          : inP[(long)(row - NAn) * 64 + lane];
    float ss = v * v;
    for (int off = 1; off < 64; off <<= 1) ss += __shfl_xor(ss, off, 64);
    out[(long)row * 64 + lane] = v / fmaxf(sqrtf(ss), 1e-12f);
}

extern "C" void kernel_launch(void* const* d_in, const int* in_sizes, int n_in,
                              void* d_out, int out_size, void* d_ws, size_t ws_size,
                              hipStream_t stream)
{
    const float* feat_a = (const float*)d_in[0];
    const float* feat_p = (const float*)d_in[1];
    const float* fmWa = (const float*)d_in[2];
    const float* fmba = (const float*)d_in[3];
    const float* fmWp = (const float*)d_in[4];
    const float* fmbp = (const float*)d_in[5];
    const float* g1w_W = (const float*)d_in[6];  const float* g1w_al = (const float*)d_in[7];
    const float* g1w_ar = (const float*)d_in[8]; const float* g1w_b = (const float*)d_in[9];
    const float* g2w_W = (const float*)d_in[10]; const float* g2w_al = (const float*)d_in[11];
    const float* g2w_ar = (const float*)d_in[12]; const float* g2w_b = (const float*)d_in[13];
    const float* g1wb_W = (const float*)d_in[14]; const float* g1wb_al = (const float*)d_in[15];
    const float* g1wb_ar = (const float*)d_in[16]; const float* g1wb_b = (const float*)d_in[17];
    const float* g2wb_W = (const float*)d_in[18]; const float* g2wb_al = (const float*)d_in[19];
    const float* g2wb_ar = (const float*)d_in[20]; const float* g2wb_b = (const float*)d_in[21];
    const float* g1c_W = (const float*)d_in[22]; const float* g1c_al = (const float*)d_in[23];
    const float* g1c_ar = (const float*)d_in[24]; const float* g1c_b = (const float*)d_in[25];
    const float* g2c_W = (const float*)d_in[26]; const float* g2c_al = (const float*)d_in[27];
    const float* g2c_ar = (const float*)d_in[28]; const float* g2c_b = (const float*)d_in[29];
    const int* w_src = (const int*)d_in[30];
    const int* w_dst = (const int*)d_in[31];
    const int* wb_src = (const int*)d_in[32];
    const int* wb_dst = (const int*)d_in[33];
    const int* c_src = (const int*)d_in[34];
    const int* c_dst = (const int*)d_in[35];

    float* ws = (float*)d_ws;
    size_t off = 0;
    auto alloc = [&](size_t n) { float* p = ws + off; off += n; return p; };
    float* h_a  = alloc(HA);
    float* h_p  = alloc(HP);
    unsigned short* Pa = (unsigned short*)alloc(HP / 2 + 16);   // shared proj buffer (bf16)
    float* h1_p = alloc(HP);
    float* h1_a = alloc(HA);
    float* el_w  = alloc((size_t)N_A * 4);
    float* er_w  = alloc((size_t)N_P * 4);
    float* el_c  = alloc((size_t)N_P * 4);
    float* er_c  = alloc((size_t)N_P * 4);
    float* el_wb = alloc((size_t)N_P * 4);
    float* er_wb = alloc((size_t)N_A * 4);
    float* fold  = alloc(12 * 256);   // 12 folded attention vectors
    int* w_offs  = (int*)alloc(N_P + 1);
    int* c_offs  = (int*)alloc(N_P + 1);
    int* wb_offs = (int*)alloc(N_A + 1);
    int* bcnt3   = (int*)alloc(3 * 256);
    int* bstart3 = (int*)alloc(3 * 257);
    int* gcur3   = (int*)alloc(3 * 256);
    int* w_csr   = (int*)alloc(E_W);
    int* c_csr   = (int*)alloc(E_C);
    int* wb_csr  = (int*)alloc(E_W);
    off = (off + 1) & ~(size_t)1;
    uint2* pairs = (uint2*)alloc((size_t)E_C * 2);
    float* h2_p = h_p;   // reuse: layer-1 h dead after layer-1 attnvec/proj
    float* h2_a = h_a;

    // fold vectors: [0..5]=layer1 {wal_w,war_w,wal_c,war_c,wal_wb,war_wb}, [6..11]=layer2
    float* wal_w1 = fold + 0*256,  *war_w1 = fold + 1*256;
    float* wal_c1 = fold + 2*256,  *war_c1 = fold + 3*256;
    float* wal_b1 = fold + 4*256,  *war_b1 = fold + 5*256;
    float* wal_w2 = fold + 6*256,  *war_w2 = fold + 7*256;
    float* wal_c2 = fold + 8*256,  *war_c2 = fold + 9*256;
    float* wal_b2 = fold + 10*256, *war_b2 = fold + 11*256;

    const int SHIFT = 9;
    int NB_P = (N_P + 511) >> 9;   // 196
    int NB_A = (N_A + 511) >> 9;   // 98

    // ---- CSR build (3 graphs; batched hist+scan, sequential part+finalize sharing pairs) ----
    hipMemsetAsync(bcnt3, 0, 3 * 256 * sizeof(int), stream);
    bucket_hist3<<<3 * 256, 256, 0, stream>>>(w_dst, E_W, bcnt3,
                                              c_dst, E_C, bcnt3 + 256,
                                              wb_dst, E_W, bcnt3 + 512, SHIFT, 256);
    bucket_scan3<<<3, 256, 0, stream>>>(bcnt3, bstart3, gcur3,
                                        w_offs, N_P, E_W,
                                        c_offs, N_P, E_C,
                                        wb_offs, N_A, E_W);
    part_kernel<<<(E_W + 2047) / 2048, 256, 0, stream>>>(w_src, w_dst, gcur3, pairs, E_W, NB_P, SHIFT);
    csr_finalize<<<NB_P, 512, 0, stream>>>(pairs, bstart3, w_offs, w_csr, N_P, SHIFT);
    part_kernel<<<(E_C + 2047) / 2048, 256, 0, stream>>>(c_src, c_dst, gcur3 + 256, pairs, E_C, NB_P, SHIFT);
    csr_finalize<<<NB_P, 512, 0, stream>>>(pairs, bstart3 + 257, c_offs, c_csr, N_P, SHIFT);
    part_kernel<<<(E_W + 2047) / 2048, 256, 0, stream>>>(wb_src, wb_dst, gcur3 + 512, pairs, E_W, NB_A, SHIFT);
    csr_finalize<<<NB_A, 512, 0, stream>>>(pairs, bstart3 + 514, wb_offs, wb_csr, N_A, SHIFT);

    // ---- fold all 12 attention vectors ----
    prep_attn12<<<12, 64, 0, stream>>>(
        PA{g1w_W,  g1w_al,  wal_w1, 4}, PA{g1w_W,  g1w_ar,  war_w1, 4},
        PA{g1c_W,  g1c_al,  wal_c1, 4}, PA{g1c_W,  g1c_ar,  war_c1, 4},
        PA{g1wb_W, g1wb_al, wal_b1, 4}, PA{g1wb_W, g1wb_ar, war_b1, 4},
        PA{g2w_W,  g2w_al,  wal_w2, 1}, PA{g2w_W,  g2w_ar,  war_w2, 1},
        PA{g2c_W,  g2c_al,  wal_c2, 1}, PA{g2c_W,  g2c_ar,  war_c2, 1},
        PA{g2wb_W, g2wb_al, wal_b2, 1}, PA{g2wb_W, g2wb_ar, war_b2, 1});

    // ---- feature mapping (MFMA): h = relu(feat @ W^T + b), fp32 out ----
    gemm_mfma<<<(N_A + 127) / 128, 256, 0, stream>>>(feat_a, fmWa, fmba, h_a, N_A, 128, 1, 0);
    gemm_mfma<<<(N_P + 127) / 128, 256, 0, stream>>>(feat_p, fmWp, fmbp, h_p, N_P, 256, 1, 0);

    // ---- Layer 1 (H=4) ----
    attnvec6<<<(N_P + 3) / 4 + (N_A + 3) / 4, 256, 0, stream>>>(
        h_p, N_P, wal_c1, el_c, war_c1, er_c, war_w1, er_w, wal_b1, el_wb,
        h_a, N_A, wal_w1, el_w, war_b1, er_wb, 4);
    gemm_mfma<<<(N_A + 127) / 128, 256, 0, stream>>>(h_a, g1w_W, nullptr, Pa, N_A, 64, 0, 1);
    gat_csr_kernel<<<(N_P + 3) / 4, 256, 0, stream>>>(w_offs, w_csr, el_w, er_w, Pa, h1_p,
                                                      N_P, 2, g1w_b, g1c_b);
    gemm_mfma<<<(N_P + 127) / 128, 256, 0, stream>>>(h_p, g1c_W, nullptr, Pa, N_P, 64, 0, 1);
    gat_csr_kernel<<<(N_P + 3) / 4, 256, 0, stream>>>(c_offs, c_csr, el_c, er_c, Pa, h1_p,
                                                      N_P, 2, nullptr, nullptr);
    gemm_mfma<<<(N_P + 127) / 128, 256, 0, stream>>>(h_p, g1wb_W, nullptr, Pa, N_P, 64, 0, 1);
    gat_csr_kernel<<<(N_A + 3) / 4, 256, 0, stream>>>(wb_offs, wb_csr, el_wb, er_wb, Pa, h1_a,
                                                      N_A, 2, g1wb_b, nullptr);

    // ---- Layer 2 (H=1) ----
    attnvec6<<<(N_P + 3) / 4 + (N_A + 3) / 4, 256, 0, stream>>>(
        h1_p, N_P, wal_c2, el_c, war_c2, er_c, war_w2, er_w, wal_b2, el_wb,
        h1_a, N_A, wal_w2, el_w, war_b2, er_wb, 1);
    gemm_mfma<<<(N_A + 127) / 128, 256, 0, stream>>>(h1_a, g2w_W, nullptr, Pa, N_A, 64, 0, 1);
    gat_csr_kernel<<<(N_P + 3) / 4, 256, 0, stream>>>(w_offs, w_csr, el_w, er_w, Pa, h2_p,
                                                      N_P, 0, g2w_b, g2c_b);
    gemm_mfma<<<(N_P + 127) / 128, 256, 0, stream>>>(h1_p, g2c_W, nullptr, Pa, N_P, 64, 0, 1);
    gat_csr_kernel<<<(N_P + 3) / 4, 256, 0, stream>>>(c_offs, c_csr, el_c, er_c, Pa, h2_p,
                                                      N_P, 0, nullptr, nullptr);
    gemm_mfma<<<(N_P + 127) / 128, 256, 0, stream>>>(h1_p, g2wb_W, nullptr, Pa, N_P, 64, 0, 1);
    gat_csr_kernel<<<(N_A + 3) / 4, 256, 0, stream>>>(wb_offs, wb_csr, el_wb, er_wb, Pa, h2_a,
                                                      N_A, 0, g2wb_b, nullptr);

    // ---- L2 normalize (single dispatch) ----
    l2norm2<<<(((long)(N_A + N_P)) * 64 + 255) / 256, 256, 0, stream>>>(
        h2_a, h2_p, (float*)d_out, N_A, N_P);
}

// Round 10
// 843.782 us; speedup vs baseline: 6.3800x; 1.1171x over previous
//
#include <hip/hip_runtime.h>
#include <hip/hip_bf16.h>

#define N_A 50000
#define N_P 100000
#define E_W 1600000
#define E_C 3200000
#define HA (N_A*64)
#define HP (N_P*64)

typedef __attribute__((ext_vector_type(8))) short short8_t;
typedef __attribute__((ext_vector_type(4))) float f32x4;

__device__ __forceinline__ unsigned short f2b(float f)
{
    __hip_bfloat16 b = __float2bfloat16(f);
    return *reinterpret_cast<unsigned short*>(&b);
}

// ---------------- MFMA GEMM: out[M,64] = act(X[M,K](fp32) @ W[64,K]^T + b) ----------------
__global__ __launch_bounds__(256) void gemm_mfma(const float* __restrict__ X,
        const float* __restrict__ W, const float* __restrict__ bias,
        void* __restrict__ out, int M, int K, int doRelu, int outBf16)
{
    __shared__ unsigned short Xs[128][72];
    __shared__ unsigned short Wsh[64][72];
    int tid = threadIdx.x, lane = tid & 63, wv = tid >> 6;
    int row0 = blockIdx.x * 128;
    int m = lane & 15, kb = lane >> 4;

    f32x4 acc[2][4];
#pragma unroll
    for (int rb = 0; rb < 2; ++rb)
#pragma unroll
        for (int cb = 0; cb < 4; ++cb) acc[rb][cb] = (f32x4){0.f, 0.f, 0.f, 0.f};

    for (int k0 = 0; k0 < K; k0 += 64) {
        {
            int rbase = (tid >> 4) * 8;
            int c4 = (tid & 15) * 4;
#pragma unroll
            for (int i = 0; i < 8; ++i) {
                int rg = row0 + rbase + i; if (rg >= M) rg = M - 1;
                float4 v = *reinterpret_cast<const float4*>(&X[(long)rg * K + k0 + c4]);
                Xs[rbase + i][c4 + 0] = f2b(v.x);
                Xs[rbase + i][c4 + 1] = f2b(v.y);
                Xs[rbase + i][c4 + 2] = f2b(v.z);
                Xs[rbase + i][c4 + 3] = f2b(v.w);
            }
            int wr = tid >> 2;
            int wc = (tid & 3) * 16;
#pragma unroll
            for (int q = 0; q < 4; ++q) {
                float4 v = *reinterpret_cast<const float4*>(&W[(long)wr * K + k0 + wc + q * 4]);
                Wsh[wr][wc + q * 4 + 0] = f2b(v.x);
                Wsh[wr][wc + q * 4 + 1] = f2b(v.y);
                Wsh[wr][wc + q * 4 + 2] = f2b(v.z);
                Wsh[wr][wc + q * 4 + 3] = f2b(v.w);
            }
        }
        __syncthreads();
#pragma unroll
        for (int kc = 0; kc < 2; ++kc) {
            short8_t a0 = *reinterpret_cast<const short8_t*>(&Xs[wv * 32 + m][kc * 32 + kb * 8]);
            short8_t a1 = *reinterpret_cast<const short8_t*>(&Xs[wv * 32 + 16 + m][kc * 32 + kb * 8]);
#pragma unroll
            for (int cb = 0; cb < 4; ++cb) {
                short8_t b = *reinterpret_cast<const short8_t*>(&Wsh[cb * 16 + m][kc * 32 + kb * 8]);
                acc[0][cb] = __builtin_amdgcn_mfma_f32_16x16x32_bf16(a0, b, acc[0][cb], 0, 0, 0);
                acc[1][cb] = __builtin_amdgcn_mfma_f32_16x16x32_bf16(a1, b, acc[1][cb], 0, 0, 0);
            }
        }
        __syncthreads();
    }

#pragma unroll
    for (int rb = 0; rb < 2; ++rb)
#pragma unroll
    for (int j = 0; j < 4; ++j) {
        int r = row0 + wv * 32 + rb * 16 + (lane >> 4) * 4 + j;
        if (r < M) {
#pragma unroll
            for (int cb = 0; cb < 4; ++cb) {
                int c = cb * 16 + m;
                float v = acc[rb][cb][j];
                if (bias) v += bias[c];
                if (doRelu) v = fmaxf(v, 0.f);
                if (outBf16) ((unsigned short*)out)[(long)r * 64 + c] = f2b(v);
                else         ((float*)out)[(long)r * 64 + c] = v;
            }
        }
    }
}

// ---------------- fold W*a for 12 attention vectors ----------------
struct PA { const float* W; const float* a; float* o; int H; };
__global__ void prep_attn12(PA p0, PA p1, PA p2, PA p3, PA p4, PA p5,
                            PA p6, PA p7, PA p8, PA p9, PA p10, PA p11)
{
    PA p;
    switch (blockIdx.x) {
        case 0: p = p0; break;  case 1: p = p1; break;  case 2: p = p2; break;
        case 3: p = p3; break;  case 4: p = p4; break;  case 5: p = p5; break;
        case 6: p = p6; break;  case 7: p = p7; break;  case 8: p = p8; break;
        case 9: p = p9; break;  case 10: p = p10; break; default: p = p11; break;
    }
    int k = threadIdx.x;
    int F = 64 / p.H;
    for (int hh = 0; hh < p.H; ++hh) {
        float s = 0.f;
        for (int f = 0; f < F; ++f)
            s = fmaf(p.W[(hh * F + f) * 64 + k], p.a[hh * F + f], s);
        p.o[k * p.H + hh] = s;
    }
}

// ---------------- el/er via tall-skinny GEMV: thread = (node, col), no shuffles ------------
// Paper side: 4 folds x H; Author side: 2 folds x H. Rows staged in LDS (stride 66,
// bank-distinct across a wave's rows). Fold vectors are 4KB L1-resident.
__global__ __launch_bounds__(256) void attnvec_mat(
        const float* __restrict__ hP, int NPn,
        const float* __restrict__ fP0, float* __restrict__ oP0,
        const float* __restrict__ fP1, float* __restrict__ oP1,
        const float* __restrict__ fP2, float* __restrict__ oP2,
        const float* __restrict__ fP3, float* __restrict__ oP3,
        const float* __restrict__ hA, int NAn,
        const float* __restrict__ fA0, float* __restrict__ oA0,
        const float* __restrict__ fA1, float* __restrict__ oA1,
        int H, int hb)
{
    __shared__ float hs[64 * 66];
    int tid = threadIdx.x;
    int slotsP = (H == 4) ? 16 : 4;
    int npbP = 256 / slotsP;
    int blocksP = (NPn + npbP - 1) / npbP;

    const float* hsrc; int node0, npb, slots, ncols, N;
    const float* fv0; const float* fv1; const float* fv2; const float* fv3;
    float* ov0; float* ov1; float* ov2; float* ov3;
    if ((int)blockIdx.x < blocksP) {
        hsrc = hP; N = NPn; slots = slotsP; npb = npbP;
        node0 = blockIdx.x * npb;
        ncols = 4 * H;
        fv0 = fP0; ov0 = oP0; fv1 = fP1; ov1 = oP1;
        fv2 = fP2; ov2 = oP2; fv3 = fP3; ov3 = oP3;
    } else {
        int b = (int)blockIdx.x - blocksP;
        hsrc = hA; N = NAn;
        slots = (H == 4) ? 8 : 4; npb = 256 / slots;
        node0 = b * npb;
        ncols = 2 * H;
        fv0 = fA0; ov0 = oA0; fv1 = fA1; ov1 = oA1;
        fv2 = fA0; ov2 = oA0; fv3 = fA1; ov3 = oA1;   // unused slots masked below
    }

    for (int idx = tid; idx < npb * 64; idx += 256) {
        int row = idx >> 6, k = idx & 63;
        int g = node0 + row; if (g >= N) g = N - 1;
        hs[row * 66 + k] = hsrc[(long)g * 64 + k];
    }
    __syncthreads();

    int sshift = (slots == 16) ? 4 : (slots == 8) ? 3 : 2;
    int nl = tid >> sshift;
    int c = tid & (slots - 1);
    int node = node0 + nl;
    if (node >= N || c >= ncols || nl >= npb) return;
    int f = c >> hb;
    int hh = c & (H - 1);
    const float* fv = (f == 0) ? fv0 : (f == 1) ? fv1 : (f == 2) ? fv2 : fv3;
    float* ov = (f == 0) ? ov0 : (f == 1) ? ov1 : (f == 2) ? ov2 : ov3;

    float s = 0.f;
    const float* hrow = &hs[nl * 66];
#pragma unroll 8
    for (int k = 0; k < 64; ++k)
        s = fmaf(hrow[k], fv[k * H + hh], s);
    ov[(long)node * H + hh] = s;
}

// ---------------- CSR build: locality-aware bucket sort (batched hist/scan) ----------------
__global__ void bucket_hist3(const int* __restrict__ d0, int E0, int* __restrict__ b0,
                             const int* __restrict__ d1, int E1, int* __restrict__ b1,
                             const int* __restrict__ d2, int E2, int* __restrict__ b2,
                             int shift, int blocksPer)
{
    int g = blockIdx.x / blocksPer, bb = blockIdx.x - g * blocksPer;
    const int* dst = g == 0 ? d0 : g == 1 ? d1 : d2;
    int E = g == 0 ? E0 : g == 1 ? E1 : E2;
    int* bcnt = g == 0 ? b0 : g == 1 ? b1 : b2;
    __shared__ int h[256];
    int tid = threadIdx.x;
    h[tid] = 0;
    __syncthreads();
    for (long i = (long)bb * 256 + tid; i < E; i += (long)blocksPer * 256)
        atomicAdd(&h[dst[i] >> shift], 1);
    __syncthreads();
    if (h[tid]) atomicAdd(&bcnt[tid], h[tid]);
}

__global__ void bucket_scan3(int* __restrict__ bcnt, int* __restrict__ bstart,
                             int* __restrict__ gcur,
                             int* __restrict__ o0, int Nn0, int Ee0,
                             int* __restrict__ o1, int Nn1, int Ee1,
                             int* __restrict__ o2, int Nn2, int Ee2)
{
    int g = blockIdx.x;
    int* bc = bcnt + g * 256;
    int* bs = bstart + g * 257;
    int* gc = gcur + g * 256;
    int* offs = g == 0 ? o0 : g == 1 ? o1 : o2;
    int N = g == 0 ? Nn0 : g == 1 ? Nn1 : Nn2;
    int E = g == 0 ? Ee0 : g == 1 ? Ee1 : Ee2;
    __shared__ int sc[256];
    int tid = threadIdx.x;
    int v = bc[tid];
    sc[tid] = v;
    __syncthreads();
    for (int off = 1; off < 256; off <<= 1) {
        int t = (tid >= off) ? sc[tid - off] : 0;
        __syncthreads();
        sc[tid] += t;
        __syncthreads();
    }
    int excl = sc[tid] - v;
    bs[tid] = excl;
    gc[tid] = excl;
    if (tid == 255) bs[256] = E;
    if (tid == 0) offs[N] = E;
}

#define EPT 8
__global__ __launch_bounds__(256) void part_kernel(const int* __restrict__ src,
        const int* __restrict__ dst, int* __restrict__ gcur,
        uint2* __restrict__ pairs, int E, int NB, int shift)
{
    __shared__ int hcnt[256];
    __shared__ int hbase[256];
    int tid = threadIdx.x;
    long base = (long)blockIdx.x * (256 * EPT);
    for (int i = tid; i < NB; i += 256) hcnt[i] = 0;
    __syncthreads();
    int b[EPT], r[EPT], s[EPT], d[EPT];
#pragma unroll
    for (int k = 0; k < EPT; ++k) {
        long idx = base + k * 256 + tid;
        if (idx < E) {
            s[k] = src[idx]; d[k] = dst[idx];
            b[k] = d[k] >> shift;
            r[k] = atomicAdd(&hcnt[b[k]], 1);
        } else b[k] = -1;
    }
    __syncthreads();
    for (int i = tid; i < NB; i += 256) {
        if (hcnt[i]) hbase[i] = atomicAdd(&gcur[i], hcnt[i]);
    }
    __syncthreads();
#pragma unroll
    for (int k = 0; k < EPT; ++k) {
        if (b[k] >= 0)
            pairs[hbase[b[k]] + r[k]] = make_uint2((unsigned)s[k], (unsigned)d[k]);
    }
}

__global__ __launch_bounds__(512) void csr_finalize(const uint2* __restrict__ pairs,
        const int* __restrict__ bstart, int* __restrict__ offs, int* __restrict__ csr,
        int N, int shift)
{
    __shared__ int cnt[512];
    __shared__ int sc[512];
    int tid = threadIdx.x;
    int b = blockIdx.x;
    int d0 = b << shift;
    int pS = bstart[b], pE = bstart[b + 1];
    cnt[tid] = 0;
    __syncthreads();
    for (int i = pS + tid; i < pE; i += 512)
        atomicAdd(&cnt[pairs[i].y - d0], 1);
    __syncthreads();
    int v = cnt[tid];
    sc[tid] = v;
    __syncthreads();
    for (int off = 1; off < 512; off <<= 1) {
        int t = (tid >= off) ? sc[tid - off] : 0;
        __syncthreads();
        sc[tid] += t;
        __syncthreads();
    }
    int excl = sc[tid] - v;
    if (d0 + tid < N) offs[d0 + tid] = pS + excl;
    cnt[tid] = excl;
    __syncthreads();
    for (int i = pS + tid; i < pE; i += 512) {
        uint2 u = pairs[i];
        int p = atomicAdd(&cnt[u.y - d0], 1);
        csr[pS + p] = (int)u.x;
    }
}

// ---------------- single-pass GAT aggregation: 8-edge micro-rounds ----------------
__global__ void gat_csr_kernel(const int* __restrict__ offs, const int* __restrict__ csr,
                               const float* __restrict__ el, const float* __restrict__ er,
                               const unsigned short* __restrict__ Fsrc, float* __restrict__ rst,
                               int Nd, int hshift,
                               const float* __restrict__ bias0, const float* __restrict__ bias1)
{
    int d = (blockIdx.x << 2) | (threadIdx.x >> 6);
    int lane = threadIdx.x & 63;
    if (d >= Nd) return;
    int H = 1 << hshift;
    int off = offs[d];
    int n = offs[d + 1] - off;
    int g8 = lane >> 3;
    int fo = (lane & 7) * 8;
    int hf = (hshift == 2) ? ((lane & 7) >> 1) : 0;

    if (n == 0) {
        if (bias0 && lane < 8) {
            float4 o0, o1;
            o0.x = bias0[fo + 0]; o0.y = bias0[fo + 1]; o0.z = bias0[fo + 2]; o0.w = bias0[fo + 3];
            o1.x = bias0[fo + 4]; o1.y = bias0[fo + 5]; o1.z = bias0[fo + 6]; o1.w = bias0[fo + 7];
            if (bias1) {
                o0.x += bias1[fo + 0]; o0.y += bias1[fo + 1]; o0.z += bias1[fo + 2]; o0.w += bias1[fo + 3];
                o1.x += bias1[fo + 4]; o1.y += bias1[fo + 5]; o1.z += bias1[fo + 6]; o1.w += bias1[fo + 7];
            }
            *reinterpret_cast<float4*>(&rst[(long)d * 64 + fo]) = o0;
            *reinterpret_cast<float4*>(&rst[(long)d * 64 + fo + 4]) = o1;
        }
        return;
    }

    int h = lane & (H - 1);
    float erd = er[d * H + h];
    int estep = 64 >> hshift;
    float acc[8];
#pragma unroll
    for (int q = 0; q < 8; ++q) acc[q] = 0.f;
    float ssum = 0.f;

    for (int base = 0; base < n; base += estep) {
        int i = base + (lane >> hshift);
        int sn = 0; float a = 0.f;
        if (i < n) {
            sn = csr[off + i];
            float v = el[sn * H + h] + erd;
            v = v > 0.f ? v : 0.2f * v;
            a = __expf(v);
            ssum += a;
        }
        int rounds = min(estep, n - base);
#pragma unroll 2
        for (int r = 0; r * 8 < rounds; ++r) {
            int sl = r * 8 + g8;
            int lsn = sl << hshift;
            int s2 = __shfl(sn, lsn, 64);
            float a2 = __shfl(a, lsn | hf, 64);
            uint4 u = *reinterpret_cast<const uint4*>(&Fsrc[(long)s2 * 64 + fo]);
            acc[0] = fmaf(__uint_as_float(u.x << 16), a2, acc[0]);
            acc[1] = fmaf(__uint_as_float(u.x & 0xffff0000u), a2, acc[1]);
            acc[2] = fmaf(__uint_as_float(u.y << 16), a2, acc[2]);
            acc[3] = fmaf(__uint_as_float(u.y & 0xffff0000u), a2, acc[3]);
            acc[4] = fmaf(__uint_as_float(u.z << 16), a2, acc[4]);
            acc[5] = fmaf(__uint_as_float(u.z & 0xffff0000u), a2, acc[5]);
            acc[6] = fmaf(__uint_as_float(u.w << 16), a2, acc[6]);
            acc[7] = fmaf(__uint_as_float(u.w & 0xffff0000u), a2, acc[7]);
        }
    }

    for (int o = H; o < 64; o <<= 1) ssum += __shfl_xor(ssum, o, 64);
    float rinv = 1.f / __shfl(ssum, hf, 64);

#pragma unroll
    for (int q = 0; q < 8; ++q) {
        acc[q] += __shfl_xor(acc[q], 8, 64);
        acc[q] += __shfl_xor(acc[q], 16, 64);
        acc[q] += __shfl_xor(acc[q], 32, 64);
    }
    if (lane < 8) {
        float4 o0, o1;
        if (bias0) {
            o0.x = bias0[fo + 0]; o0.y = bias0[fo + 1]; o0.z = bias0[fo + 2]; o0.w = bias0[fo + 3];
            o1.x = bias0[fo + 4]; o1.y = bias0[fo + 5]; o1.z = bias0[fo + 6]; o1.w = bias0[fo + 7];
            if (bias1) {
                o0.x += bias1[fo + 0]; o0.y += bias1[fo + 1]; o0.z += bias1[fo + 2]; o0.w += bias1[fo + 3];
                o1.x += bias1[fo + 4]; o1.y += bias1[fo + 5]; o1.z += bias1[fo + 6]; o1.w += bias1[fo + 7];
            }
        } else {
            o0 = *reinterpret_cast<float4*>(&rst[(long)d * 64 + fo]);
            o1 = *reinterpret_cast<float4*>(&rst[(long)d * 64 + fo + 4]);
        }
        o0.x = fmaf(acc[0], rinv, o0.x); o0.y = fmaf(acc[1], rinv, o0.y);
        o0.z = fmaf(acc[2], rinv, o0.z); o0.w = fmaf(acc[3], rinv, o0.w);
        o1.x = fmaf(acc[4], rinv, o1.x); o1.y = fmaf(acc[5], rinv, o1.y);
        o1.z = fmaf(acc[6], rinv, o1.z); o1.w = fmaf(acc[7], rinv, o1.w);
        *reinterpret_cast<float4*>(&rst[(long)d * 64 + fo]) = o0;
        *reinterpret_cast<float4*>(&rst[(long)d * 64 + fo + 4]) = o1;
    }
}

// merged L2-normalize of both outputs
__global__ void l2norm2(const float* __restrict__ inA, const float* __restrict__ inP,
                        float* __restrict__ out, int NAn, int NPn)
{
    long gt = (long)blockIdx.x * blockDim.x + threadIdx.x;
    int row = (int)(gt >> 6);
    int lane = threadIdx.x & 63;
    if (row >= NAn + NPn) return;
    float v = (row < NAn) ? inA[(long)row * 64 + lane]
                          : inP[(long)(row - NAn) * 64 + lane];
    float ss = v * v;
    for (int off = 1; off < 64; off <<= 1) ss += __shfl_xor(ss, off, 64);
    out[(long)row * 64 + lane] = v / fmaxf(sqrtf(ss), 1e-12f);
}

extern "C" void kernel_launch(void* const* d_in, const int* in_sizes, int n_in,
                              void* d_out, int out_size, void* d_ws, size_t ws_size,
                              hipStream_t stream)
{
    const float* feat_a = (const float*)d_in[0];
    const float* feat_p = (const float*)d_in[1];
    const float* fmWa = (const float*)d_in[2];
    const float* fmba = (const float*)d_in[3];
    const float* fmWp = (const float*)d_in[4];
    const float* fmbp = (const float*)d_in[5];
    const float* g1w_W = (const float*)d_in[6];  const float* g1w_al = (const float*)d_in[7];
    const float* g1w_ar = (const float*)d_in[8]; const float* g1w_b = (const float*)d_in[9];
    const float* g2w_W = (const float*)d_in[10]; const float* g2w_al = (const float*)d_in[11];
    const float* g2w_ar = (const float*)d_in[12]; const float* g2w_b = (const float*)d_in[13];
    const float* g1wb_W = (const float*)d_in[14]; const float* g1wb_al = (const float*)d_in[15];
    const float* g1wb_ar = (const float*)d_in[16]; const float* g1wb_b = (const float*)d_in[17];
    const float* g2wb_W = (const float*)d_in[18]; const float* g2wb_al = (const float*)d_in[19];
    const float* g2wb_ar = (const float*)d_in[20]; const float* g2wb_b = (const float*)d_in[21];
    const float* g1c_W = (const float*)d_in[22]; const float* g1c_al = (const float*)d_in[23];
    const float* g1c_ar = (const float*)d_in[24]; const float* g1c_b = (const float*)d_in[25];
    const float* g2c_W = (const float*)d_in[26]; const float* g2c_al = (const float*)d_in[27];
    const float* g2c_ar = (const float*)d_in[28]; const float* g2c_b = (const float*)d_in[29];
    const int* w_src = (const int*)d_in[30];
    const int* w_dst = (const int*)d_in[31];
    const int* wb_src = (const int*)d_in[32];
    const int* wb_dst = (const int*)d_in[33];
    const int* c_src = (const int*)d_in[34];
    const int* c_dst = (const int*)d_in[35];

    float* ws = (float*)d_ws;
    size_t off = 0;
    auto alloc = [&](size_t n) { float* p = ws + off; off += n; return p; };
    float* h_a  = alloc(HA);
    float* h_p  = alloc(HP);
    unsigned short* Pa = (unsigned short*)alloc(HP / 2 + 16);
    float* h1_p = alloc(HP);
    float* h1_a = alloc(HA);
    float* el_w  = alloc((size_t)N_A * 4);
    float* er_w  = alloc((size_t)N_P * 4);
    float* el_c  = alloc((size_t)N_P * 4);
    float* er_c  = alloc((size_t)N_P * 4);
    float* el_wb = alloc((size_t)N_P * 4);
    float* er_wb = alloc((size_t)N_A * 4);
    float* fold  = alloc(12 * 256);
    int* w_offs  = (int*)alloc(N_P + 1);
    int* c_offs  = (int*)alloc(N_P + 1);
    int* wb_offs = (int*)alloc(N_A + 1);
    int* bcnt3   = (int*)alloc(3 * 256);
    int* bstart3 = (int*)alloc(3 * 257);
    int* gcur3   = (int*)alloc(3 * 256);
    int* w_csr   = (int*)alloc(E_W);
    int* c_csr   = (int*)alloc(E_C);
    int* wb_csr  = (int*)alloc(E_W);
    off = (off + 1) & ~(size_t)1;
    uint2* pairs = (uint2*)alloc((size_t)E_C * 2);
    float* h2_p = h_p;
    float* h2_a = h_a;

    float* wal_w1 = fold + 0*256,  *war_w1 = fold + 1*256;
    float* wal_c1 = fold + 2*256,  *war_c1 = fold + 3*256;
    float* wal_b1 = fold + 4*256,  *war_b1 = fold + 5*256;
    float* wal_w2 = fold + 6*256,  *war_w2 = fold + 7*256;
    float* wal_c2 = fold + 8*256,  *war_c2 = fold + 9*256;
    float* wal_b2 = fold + 10*256, *war_b2 = fold + 11*256;

    const int SHIFT = 9;
    int NB_P = (N_P + 511) >> 9;
    int NB_A = (N_A + 511) >> 9;

    hipMemsetAsync(bcnt3, 0, 3 * 256 * sizeof(int), stream);
    bucket_hist3<<<3 * 256, 256, 0, stream>>>(w_dst, E_W, bcnt3,
                                              c_dst, E_C, bcnt3 + 256,
                                              wb_dst, E_W, bcnt3 + 512, SHIFT, 256);
    bucket_scan3<<<3, 256, 0, stream>>>(bcnt3, bstart3, gcur3,
                                        w_offs, N_P, E_W,
                                        c_offs, N_P, E_C,
                                        wb_offs, N_A, E_W);
    part_kernel<<<(E_W + 2047) / 2048, 256, 0, stream>>>(w_src, w_dst, gcur3, pairs, E_W, NB_P, SHIFT);
    csr_finalize<<<NB_P, 512, 0, stream>>>(pairs, bstart3, w_offs, w_csr, N_P, SHIFT);
    part_kernel<<<(E_C + 2047) / 2048, 256, 0, stream>>>(c_src, c_dst, gcur3 + 256, pairs, E_C, NB_P, SHIFT);
    csr_finalize<<<NB_P, 512, 0, stream>>>(pairs, bstart3 + 257, c_offs, c_csr, N_P, SHIFT);
    part_kernel<<<(E_W + 2047) / 2048, 256, 0, stream>>>(wb_src, wb_dst, gcur3 + 512, pairs, E_W, NB_A, SHIFT);
    csr_finalize<<<NB_A, 512, 0, stream>>>(pairs, bstart3 + 514, wb_offs, wb_csr, N_A, SHIFT);

    prep_attn12<<<12, 64, 0, stream>>>(
        PA{g1w_W,  g1w_al,  wal_w1, 4}, PA{g1w_W,  g1w_ar,  war_w1, 4},
        PA{g1c_W,  g1c_al,  wal_c1, 4}, PA{g1c_W,  g1c_ar,  war_c1, 4},
        PA{g1wb_W, g1wb_al, wal_b1, 4}, PA{g1wb_W, g1wb_ar, war_b1, 4},
        PA{g2w_W,  g2w_al,  wal_w2, 1}, PA{g2w_W,  g2w_ar,  war_w2, 1},
        PA{g2c_W,  g2c_al,  wal_c2, 1}, PA{g2c_W,  g2c_ar,  war_c2, 1},
        PA{g2wb_W, g2wb_al, wal_b2, 1}, PA{g2wb_W, g2wb_ar, war_b2, 1});

    gemm_mfma<<<(N_A + 127) / 128, 256, 0, stream>>>(feat_a, fmWa, fmba, h_a, N_A, 128, 1, 0);
    gemm_mfma<<<(N_P + 127) / 128, 256, 0, stream>>>(feat_p, fmWp, fmbp, h_p, N_P, 256, 1, 0);

    // ---- Layer 1 (H=4) ----
    {
        int npbP = 16, npbA = 32;
        int grid = (N_P + npbP - 1) / npbP + (N_A + npbA - 1) / npbA;
        attnvec_mat<<<grid, 256, 0, stream>>>(
            h_p, N_P, wal_c1, el_c, war_c1, er_c, war_w1, er_w, wal_b1, el_wb,
            h_a, N_A, wal_w1, el_w, war_b1, er_wb, 4, 2);
    }
    gemm_mfma<<<(N_A + 127) / 128, 256, 0, stream>>>(h_a, g1w_W, nullptr, Pa, N_A, 64, 0, 1);
    gat_csr_kernel<<<(N_P + 3) / 4, 256, 0, stream>>>(w_offs, w_csr, el_w, er_w, Pa, h1_p,
                                                      N_P, 2, g1w_b, g1c_b);
    gemm_mfma<<<(N_P + 127) / 128, 256, 0, stream>>>(h_p, g1c_W, nullptr, Pa, N_P, 64, 0, 1);
    gat_csr_kernel<<<(N_P + 3) / 4, 256, 0, stream>>>(c_offs, c_csr, el_c, er_c, Pa, h1_p,
                                                      N_P, 2, nullptr, nullptr);
    gemm_mfma<<<(N_P + 127) / 128, 256, 0, stream>>>(h_p, g1wb_W, nullptr, Pa, N_P, 64, 0, 1);
    gat_csr_kernel<<<(N_A + 3) / 4, 256, 0, stream>>>(wb_offs, wb_csr, el_wb, er_wb, Pa, h1_a,
                                                      N_A, 2, g1wb_b, nullptr);

    // ---- Layer 2 (H=1) ----
    {
        int npbP = 64, npbA = 64;
        int grid = (N_P + npbP - 1) / npbP + (N_A + npbA - 1) / npbA;
        attnvec_mat<<<grid, 256, 0, stream>>>(
            h1_p, N_P, wal_c2, el_c, war_c2, er_c, war_w2, er_w, wal_b2, el_wb,
            h1_a, N_A, wal_w2, el_w, war_b2, er_wb, 1, 0);
    }
    gemm_mfma<<<(N_A + 127) / 128, 256, 0, stream>>>(h1_a, g2w_W, nullptr, Pa, N_A, 64, 0, 1);
    gat_csr_kernel<<<(N_P + 3) / 4, 256, 0, stream>>>(w_offs, w_csr, el_w, er_w, Pa, h2_p,
                                                      N_P, 0, g2w_b, g2c_b);
    gemm_mfma<<<(N_P + 127) / 128, 256, 0, stream>>>(h1_p, g2c_W, nullptr, Pa, N_P, 64, 0, 1);
    gat_csr_kernel<<<(N_P + 3) / 4, 256, 0, stream>>>(c_offs, c_csr, el_c, er_c, Pa, h2_p,
                                                      N_P, 0, nullptr, nullptr);
    gemm_mfma<<<(N_P + 127) / 128, 256, 0, stream>>>(h1_p, g2wb_W, nullptr, Pa, N_P, 64, 0, 1);
    gat_csr_kernel<<<(N_A + 3) / 4, 256, 0, stream>>>(wb_offs, wb_csr, el_wb, er_wb, Pa, h2_a,
                                                      N_A, 0, g2wb_b, nullptr);

    l2norm2<<<(((long)(N_A + N_P)) * 64 + 255) / 256, 256, 0, stream>>>(
        h2_a, h2_p, (float*)d_out, N_A, N_P);
}

// Round 11
// 785.636 us; speedup vs baseline: 6.8522x; 1.0740x over previous
//
#include <hip/hip_runtime.h>
#include <hip/hip_bf16.h>

#define N_A 50000
#define N_P 100000
#define E_W 1600000
#define E_C 3200000
#define HA (N_A*64)
#define HP (N_P*64)

typedef __attribute__((ext_vector_type(8))) short short8_t;
typedef __attribute__((ext_vector_type(4))) float f32x4;

__device__ __forceinline__ unsigned short f2b(float f)
{
    __hip_bfloat16 b = __float2bfloat16(f);
    return *reinterpret_cast<unsigned short*>(&b);
}

// ---------------- fused feature-mapping GEMM (2 segments, fp32 out, relu) ----------------
__global__ __launch_bounds__(256) void gemm_fm2(
        const float* __restrict__ X0, const float* __restrict__ W0,
        const float* __restrict__ b0, float* __restrict__ out0, int M0, int K0, int nb0,
        const float* __restrict__ X1, const float* __restrict__ W1,
        const float* __restrict__ b1, float* __restrict__ out1, int M1, int K1)
{
    __shared__ unsigned short Xs[128][72];
    __shared__ unsigned short Wsh[64][72];
    const float *X, *W, *bias; float* out; int M, K, row0;
    if ((int)blockIdx.x < nb0) {
        X = X0; W = W0; bias = b0; out = out0; M = M0; K = K0; row0 = blockIdx.x * 128;
    } else {
        X = X1; W = W1; bias = b1; out = out1; M = M1; K = K1;
        row0 = ((int)blockIdx.x - nb0) * 128;
    }
    int tid = threadIdx.x, lane = tid & 63, wv = tid >> 6;
    int m = lane & 15, kb = lane >> 4;

    f32x4 acc[2][4];
#pragma unroll
    for (int rb = 0; rb < 2; ++rb)
#pragma unroll
        for (int cb = 0; cb < 4; ++cb) acc[rb][cb] = (f32x4){0.f, 0.f, 0.f, 0.f};

    for (int k0 = 0; k0 < K; k0 += 64) {
        int rbase = (tid >> 4) * 8;
        int c4 = (tid & 15) * 4;
#pragma unroll
        for (int i = 0; i < 8; ++i) {
            int rg = row0 + rbase + i; if (rg >= M) rg = M - 1;
            float4 v = *reinterpret_cast<const float4*>(&X[(long)rg * K + k0 + c4]);
            Xs[rbase + i][c4 + 0] = f2b(v.x);
            Xs[rbase + i][c4 + 1] = f2b(v.y);
            Xs[rbase + i][c4 + 2] = f2b(v.z);
            Xs[rbase + i][c4 + 3] = f2b(v.w);
        }
        int wr = tid >> 2;
        int wc = (tid & 3) * 16;
#pragma unroll
        for (int q = 0; q < 4; ++q) {
            float4 v = *reinterpret_cast<const float4*>(&W[(long)wr * K + k0 + wc + q * 4]);
            Wsh[wr][wc + q * 4 + 0] = f2b(v.x);
            Wsh[wr][wc + q * 4 + 1] = f2b(v.y);
            Wsh[wr][wc + q * 4 + 2] = f2b(v.z);
            Wsh[wr][wc + q * 4 + 3] = f2b(v.w);
        }
        __syncthreads();
#pragma unroll
        for (int kc = 0; kc < 2; ++kc) {
            short8_t a0 = *reinterpret_cast<const short8_t*>(&Xs[wv * 32 + m][kc * 32 + kb * 8]);
            short8_t a1 = *reinterpret_cast<const short8_t*>(&Xs[wv * 32 + 16 + m][kc * 32 + kb * 8]);
#pragma unroll
            for (int cb = 0; cb < 4; ++cb) {
                short8_t b = *reinterpret_cast<const short8_t*>(&Wsh[cb * 16 + m][kc * 32 + kb * 8]);
                acc[0][cb] = __builtin_amdgcn_mfma_f32_16x16x32_bf16(a0, b, acc[0][cb], 0, 0, 0);
                acc[1][cb] = __builtin_amdgcn_mfma_f32_16x16x32_bf16(a1, b, acc[1][cb], 0, 0, 0);
            }
        }
        __syncthreads();
    }

#pragma unroll
    for (int rb = 0; rb < 2; ++rb)
#pragma unroll
    for (int j = 0; j < 4; ++j) {
        int r = row0 + wv * 32 + rb * 16 + (lane >> 4) * 4 + j;
        if (r < M) {
#pragma unroll
            for (int cb = 0; cb < 4; ++cb) {
                int c = cb * 16 + m;
                float v = acc[rb][cb][j] + bias[c];
                out[(long)r * 64 + c] = fmaxf(v, 0.f);
            }
        }
    }
}

// ---------------- fused 3-projection GEMM (K=64, bf16 out) ----------------
__global__ __launch_bounds__(256) void proj3(
        const float* __restrict__ X0, const float* __restrict__ W0,
        unsigned short* __restrict__ o0, int M0, int nb0,
        const float* __restrict__ X1, const float* __restrict__ W1,
        unsigned short* __restrict__ o1, int M1, int nb1,
        const float* __restrict__ X2, const float* __restrict__ W2,
        unsigned short* __restrict__ o2, int M2)
{
    __shared__ unsigned short Xs[128][72];
    __shared__ unsigned short Wsh[64][72];
    const float *X, *W; unsigned short* out; int M, row0;
    if ((int)blockIdx.x < nb0) {
        X = X0; W = W0; out = o0; M = M0; row0 = blockIdx.x * 128;
    } else if ((int)blockIdx.x < nb0 + nb1) {
        X = X1; W = W1; out = o1; M = M1; row0 = ((int)blockIdx.x - nb0) * 128;
    } else {
        X = X2; W = W2; out = o2; M = M2; row0 = ((int)blockIdx.x - nb0 - nb1) * 128;
    }
    int tid = threadIdx.x, lane = tid & 63, wv = tid >> 6;
    int m = lane & 15, kb = lane >> 4;

    int rbase = (tid >> 4) * 8;
    int c4 = (tid & 15) * 4;
#pragma unroll
    for (int i = 0; i < 8; ++i) {
        int rg = row0 + rbase + i; if (rg >= M) rg = M - 1;
        float4 v = *reinterpret_cast<const float4*>(&X[(long)rg * 64 + c4]);
        Xs[rbase + i][c4 + 0] = f2b(v.x);
        Xs[rbase + i][c4 + 1] = f2b(v.y);
        Xs[rbase + i][c4 + 2] = f2b(v.z);
        Xs[rbase + i][c4 + 3] = f2b(v.w);
    }
    int wr = tid >> 2;
    int wc = (tid & 3) * 16;
#pragma unroll
    for (int q = 0; q < 4; ++q) {
        float4 v = *reinterpret_cast<const float4*>(&W[(long)wr * 64 + wc + q * 4]);
        Wsh[wr][wc + q * 4 + 0] = f2b(v.x);
        Wsh[wr][wc + q * 4 + 1] = f2b(v.y);
        Wsh[wr][wc + q * 4 + 2] = f2b(v.z);
        Wsh[wr][wc + q * 4 + 3] = f2b(v.w);
    }
    __syncthreads();

    f32x4 acc[2][4];
#pragma unroll
    for (int rb = 0; rb < 2; ++rb)
#pragma unroll
        for (int cb = 0; cb < 4; ++cb) acc[rb][cb] = (f32x4){0.f, 0.f, 0.f, 0.f};
#pragma unroll
    for (int kc = 0; kc < 2; ++kc) {
        short8_t a0 = *reinterpret_cast<const short8_t*>(&Xs[wv * 32 + m][kc * 32 + kb * 8]);
        short8_t a1 = *reinterpret_cast<const short8_t*>(&Xs[wv * 32 + 16 + m][kc * 32 + kb * 8]);
#pragma unroll
        for (int cb = 0; cb < 4; ++cb) {
            short8_t b = *reinterpret_cast<const short8_t*>(&Wsh[cb * 16 + m][kc * 32 + kb * 8]);
            acc[0][cb] = __builtin_amdgcn_mfma_f32_16x16x32_bf16(a0, b, acc[0][cb], 0, 0, 0);
            acc[1][cb] = __builtin_amdgcn_mfma_f32_16x16x32_bf16(a1, b, acc[1][cb], 0, 0, 0);
        }
    }
#pragma unroll
    for (int rb = 0; rb < 2; ++rb)
#pragma unroll
    for (int j = 0; j < 4; ++j) {
        int r = row0 + wv * 32 + rb * 16 + (lane >> 4) * 4 + j;
        if (r < M) {
#pragma unroll
            for (int cb = 0; cb < 4; ++cb)
                out[(long)r * 64 + cb * 16 + m] = f2b(acc[rb][cb][j]);
        }
    }
}

// ---------------- fold W*a for 12 attention vectors ----------------
struct PA { const float* W; const float* a; float* o; int H; };
__global__ void prep_attn12(PA p0, PA p1, PA p2, PA p3, PA p4, PA p5,
                            PA p6, PA p7, PA p8, PA p9, PA p10, PA p11)
{
    PA p;
    switch (blockIdx.x) {
        case 0: p = p0; break;  case 1: p = p1; break;  case 2: p = p2; break;
        case 3: p = p3; break;  case 4: p = p4; break;  case 5: p = p5; break;
        case 6: p = p6; break;  case 7: p = p7; break;  case 8: p = p8; break;
        case 9: p = p9; break;  case 10: p = p10; break; default: p = p11; break;
    }
    int k = threadIdx.x;
    int F = 64 / p.H;
    for (int hh = 0; hh < p.H; ++hh) {
        float s = 0.f;
        for (int f = 0; f < F; ++f)
            s = fmaf(p.W[(hh * F + f) * 64 + k], p.a[hh * F + f], s);
        p.o[k * p.H + hh] = s;
    }
}

// ---------------- el/er via tall-skinny GEMV ----------------
__global__ __launch_bounds__(256) void attnvec_mat(
        const float* __restrict__ hP, int NPn,
        const float* __restrict__ fP0, float* __restrict__ oP0,
        const float* __restrict__ fP1, float* __restrict__ oP1,
        const float* __restrict__ fP2, float* __restrict__ oP2,
        const float* __restrict__ fP3, float* __restrict__ oP3,
        const float* __restrict__ hA, int NAn,
        const float* __restrict__ fA0, float* __restrict__ oA0,
        const float* __restrict__ fA1, float* __restrict__ oA1,
        int H, int hb)
{
    __shared__ float hs[64 * 66];
    int tid = threadIdx.x;
    int slotsP = (H == 4) ? 16 : 4;
    int npbP = 256 / slotsP;
    int blocksP = (NPn + npbP - 1) / npbP;

    const float* hsrc; int node0, npb, slots, ncols, N;
    const float* fv0; const float* fv1; const float* fv2; const float* fv3;
    float* ov0; float* ov1; float* ov2; float* ov3;
    if ((int)blockIdx.x < blocksP) {
        hsrc = hP; N = NPn; slots = slotsP; npb = npbP;
        node0 = blockIdx.x * npb;
        ncols = 4 * H;
        fv0 = fP0; ov0 = oP0; fv1 = fP1; ov1 = oP1;
        fv2 = fP2; ov2 = oP2; fv3 = fP3; ov3 = oP3;
    } else {
        int b = (int)blockIdx.x - blocksP;
        hsrc = hA; N = NAn;
        slots = (H == 4) ? 8 : 4; npb = 256 / slots;
        node0 = b * npb;
        ncols = 2 * H;
        fv0 = fA0; ov0 = oA0; fv1 = fA1; ov1 = oA1;
        fv2 = fA0; ov2 = oA0; fv3 = fA1; ov3 = oA1;
    }

    for (int idx = tid; idx < npb * 64; idx += 256) {
        int row = idx >> 6, k = idx & 63;
        int g = node0 + row; if (g >= N) g = N - 1;
        hs[row * 66 + k] = hsrc[(long)g * 64 + k];
    }
    __syncthreads();

    int sshift = (slots == 16) ? 4 : (slots == 8) ? 3 : 2;
    int nl = tid >> sshift;
    int c = tid & (slots - 1);
    int node = node0 + nl;
    if (node >= N || c >= ncols || nl >= npb) return;
    int f = c >> hb;
    int hh = c & (H - 1);
    const float* fv = (f == 0) ? fv0 : (f == 1) ? fv1 : (f == 2) ? fv2 : fv3;
    float* ov = (f == 0) ? ov0 : (f == 1) ? ov1 : (f == 2) ? ov2 : ov3;

    float s = 0.f;
    const float* hrow = &hs[nl * 66];
#pragma unroll 8
    for (int k = 0; k < 64; ++k)
        s = fmaf(hrow[k], fv[k * H + hh], s);
    ov[(long)node * H + hh] = s;
}

// ---------------- CSR build ----------------
__global__ void bucket_hist3(const int* __restrict__ d0, int E0, int* __restrict__ b0,
                             const int* __restrict__ d1, int E1, int* __restrict__ b1,
                             const int* __restrict__ d2, int E2, int* __restrict__ b2,
                             int shift, int blocksPer)
{
    int g = blockIdx.x / blocksPer, bb = blockIdx.x - g * blocksPer;
    const int* dst = g == 0 ? d0 : g == 1 ? d1 : d2;
    int E = g == 0 ? E0 : g == 1 ? E1 : E2;
    int* bcnt = g == 0 ? b0 : g == 1 ? b1 : b2;
    __shared__ int h[256];
    int tid = threadIdx.x;
    h[tid] = 0;
    __syncthreads();
    for (long i = (long)bb * 256 + tid; i < E; i += (long)blocksPer * 256)
        atomicAdd(&h[dst[i] >> shift], 1);
    __syncthreads();
    if (h[tid]) atomicAdd(&bcnt[tid], h[tid]);
}

__global__ void bucket_scan3(int* __restrict__ bcnt, int* __restrict__ bstart,
                             int* __restrict__ gcur,
                             int* __restrict__ o0, int Nn0, int Ee0,
                             int* __restrict__ o1, int Nn1, int Ee1,
                             int* __restrict__ o2, int Nn2, int Ee2)
{
    int g = blockIdx.x;
    int* bc = bcnt + g * 256;
    int* bs = bstart + g * 257;
    int* gc = gcur + g * 256;
    int* offs = g == 0 ? o0 : g == 1 ? o1 : o2;
    int N = g == 0 ? Nn0 : g == 1 ? Nn1 : Nn2;
    int E = g == 0 ? Ee0 : g == 1 ? Ee1 : Ee2;
    __shared__ int sc[256];
    int tid = threadIdx.x;
    int v = bc[tid];
    sc[tid] = v;
    __syncthreads();
    for (int off = 1; off < 256; off <<= 1) {
        int t = (tid >= off) ? sc[tid - off] : 0;
        __syncthreads();
        sc[tid] += t;
        __syncthreads();
    }
    int excl = sc[tid] - v;
    bs[tid] = excl;
    gc[tid] = excl;
    if (tid == 255) bs[256] = E;
    if (tid == 0) offs[N] = E;
}

#define EPT 8
__global__ __launch_bounds__(256) void part_kernel(const int* __restrict__ src,
        const int* __restrict__ dst, int* __restrict__ gcur,
        uint2* __restrict__ pairs, int E, int NB, int shift)
{
    __shared__ int hcnt[256];
    __shared__ int hbase[256];
    int tid = threadIdx.x;
    long base = (long)blockIdx.x * (256 * EPT);
    for (int i = tid; i < NB; i += 256) hcnt[i] = 0;
    __syncthreads();
    int b[EPT], r[EPT], s[EPT], d[EPT];
#pragma unroll
    for (int k = 0; k < EPT; ++k) {
        long idx = base + k * 256 + tid;
        if (idx < E) {
            s[k] = src[idx]; d[k] = dst[idx];
            b[k] = d[k] >> shift;
            r[k] = atomicAdd(&hcnt[b[k]], 1);
        } else b[k] = -1;
    }
    __syncthreads();
    for (int i = tid; i < NB; i += 256) {
        if (hcnt[i]) hbase[i] = atomicAdd(&gcur[i], hcnt[i]);
    }
    __syncthreads();
#pragma unroll
    for (int k = 0; k < EPT; ++k) {
        if (b[k] >= 0)
            pairs[hbase[b[k]] + r[k]] = make_uint2((unsigned)s[k], (unsigned)d[k]);
    }
}

__global__ __launch_bounds__(512) void csr_finalize(const uint2* __restrict__ pairs,
        const int* __restrict__ bstart, int* __restrict__ offs, int* __restrict__ csr,
        int N, int shift)
{
    __shared__ int cnt[512];
    __shared__ int sc[512];
    int tid = threadIdx.x;
    int b = blockIdx.x;
    int d0 = b << shift;
    int pS = bstart[b], pE = bstart[b + 1];
    cnt[tid] = 0;
    __syncthreads();
    for (int i = pS + tid; i < pE; i += 512)
        atomicAdd(&cnt[pairs[i].y - d0], 1);
    __syncthreads();
    int v = cnt[tid];
    sc[tid] = v;
    __syncthreads();
    for (int off = 1; off < 512; off <<= 1) {
        int t = (tid >= off) ? sc[tid - off] : 0;
        __syncthreads();
        sc[tid] += t;
        __syncthreads();
    }
    int excl = sc[tid] - v;
    if (d0 + tid < N) offs[d0 + tid] = pS + excl;
    cnt[tid] = excl;
    __syncthreads();
    for (int i = pS + tid; i < pE; i += 512) {
        uint2 u = pairs[i];
        int p = atomicAdd(&cnt[u.y - d0], 1);
        csr[pS + p] = (int)u.x;
    }
}

// ---------------- fused GAT layer: one dispatch ----------------
// Per-graph normalized contribution accumulated into o[8] (feature octet per lane&7).
__device__ __forceinline__ void gat_graph(int d, const int* __restrict__ offs,
        const int* __restrict__ csr, const float* __restrict__ el,
        const float* __restrict__ er, const unsigned short* __restrict__ P,
        int hshift, int lane, float* o)
{
    int H = 1 << hshift;
    int off = offs[d];
    int n = offs[d + 1] - off;
    if (n == 0) return;
    int g8 = lane >> 3;
    int fo = (lane & 7) * 8;
    int hf = (hshift == 2) ? ((lane & 7) >> 1) : 0;
    int h = lane & (H - 1);
    float erd = er[d * H + h];
    int estep = 64 >> hshift;
    float acc[8];
#pragma unroll
    for (int q = 0; q < 8; ++q) acc[q] = 0.f;
    float ssum = 0.f;

    for (int base = 0; base < n; base += estep) {
        int i = base + (lane >> hshift);
        int sn = 0; float a = 0.f;
        if (i < n) {
            sn = csr[off + i];
            float v = el[sn * H + h] + erd;
            v = v > 0.f ? v : 0.2f * v;
            a = __expf(v);
            ssum += a;
        }
        int rounds = min(estep, n - base);
#pragma unroll 2
        for (int r = 0; r * 8 < rounds; ++r) {
            int sl = r * 8 + g8;
            int lsn = sl << hshift;
            int s2 = __shfl(sn, lsn, 64);
            float a2 = __shfl(a, lsn | hf, 64);
            uint4 u = *reinterpret_cast<const uint4*>(&P[(long)s2 * 64 + fo]);
            acc[0] = fmaf(__uint_as_float(u.x << 16), a2, acc[0]);
            acc[1] = fmaf(__uint_as_float(u.x & 0xffff0000u), a2, acc[1]);
            acc[2] = fmaf(__uint_as_float(u.y << 16), a2, acc[2]);
            acc[3] = fmaf(__uint_as_float(u.y & 0xffff0000u), a2, acc[3]);
            acc[4] = fmaf(__uint_as_float(u.z << 16), a2, acc[4]);
            acc[5] = fmaf(__uint_as_float(u.z & 0xffff0000u), a2, acc[5]);
            acc[6] = fmaf(__uint_as_float(u.w << 16), a2, acc[6]);
            acc[7] = fmaf(__uint_as_float(u.w & 0xffff0000u), a2, acc[7]);
        }
    }

    for (int oo = H; oo < 64; oo <<= 1) ssum += __shfl_xor(ssum, oo, 64);
    float rinv = 1.f / __shfl(ssum, hf, 64);
#pragma unroll
    for (int q = 0; q < 8; ++q) {
        acc[q] += __shfl_xor(acc[q], 8, 64);
        acc[q] += __shfl_xor(acc[q], 16, 64);
        acc[q] += __shfl_xor(acc[q], 32, 64);
        o[q] = fmaf(acc[q], rinv, o[q]);
    }
}

__global__ void gat_fused(
        int NPn, const int* __restrict__ w_offs, const int* __restrict__ w_csr,
        const float* __restrict__ el_w, const float* __restrict__ er_w,
        const unsigned short* __restrict__ Pw,
        const int* __restrict__ c_offs, const int* __restrict__ c_csr,
        const float* __restrict__ el_c, const float* __restrict__ er_c,
        const unsigned short* __restrict__ Pc,
        const float* __restrict__ bP0, const float* __restrict__ bP1,
        float* __restrict__ outP,
        int NAn, const int* __restrict__ wb_offs, const int* __restrict__ wb_csr,
        const float* __restrict__ el_wb, const float* __restrict__ er_wb,
        const unsigned short* __restrict__ Pwb,
        const float* __restrict__ bA0, float* __restrict__ outA,
        int hshift, int doNorm)
{
    int blocksP = (NPn + 3) >> 2;
    int lane = threadIdx.x & 63;
    int sub = threadIdx.x >> 6;
    int fo = (lane & 7) * 8;
    float o[8];
    float* dst;

    if ((int)blockIdx.x < blocksP) {
        int d = ((int)blockIdx.x << 2) | sub;
        if (d >= NPn) return;
#pragma unroll
        for (int q = 0; q < 8; ++q) o[q] = bP0[fo + q] + bP1[fo + q];
        gat_graph(d, w_offs, w_csr, el_w, er_w, Pw, hshift, lane, o);
        gat_graph(d, c_offs, c_csr, el_c, er_c, Pc, hshift, lane, o);
        dst = outP + (long)d * 64;
    } else {
        int d = (((int)blockIdx.x - blocksP) << 2) | sub;
        if (d >= NAn) return;
#pragma unroll
        for (int q = 0; q < 8; ++q) o[q] = bA0[fo + q];
        gat_graph(d, wb_offs, wb_csr, el_wb, er_wb, Pwb, hshift, lane, o);
        dst = outA + (long)d * 64;
    }

    if (doNorm) {
        float ss = 0.f;
#pragma unroll
        for (int q = 0; q < 8; ++q) ss = fmaf(o[q], o[q], ss);
        ss += __shfl_xor(ss, 1, 64);
        ss += __shfl_xor(ss, 2, 64);
        ss += __shfl_xor(ss, 4, 64);
        float sc = 1.f / fmaxf(sqrtf(ss), 1e-12f);
#pragma unroll
        for (int q = 0; q < 8; ++q) o[q] *= sc;
    }
    if (lane < 8) {
        float4 o0, o1;
        o0.x = o[0]; o0.y = o[1]; o0.z = o[2]; o0.w = o[3];
        o1.x = o[4]; o1.y = o[5]; o1.z = o[6]; o1.w = o[7];
        *reinterpret_cast<float4*>(dst + fo) = o0;
        *reinterpret_cast<float4*>(dst + fo + 4) = o1;
    }
}

extern "C" void kernel_launch(void* const* d_in, const int* in_sizes, int n_in,
                              void* d_out, int out_size, void* d_ws, size_t ws_size,
                              hipStream_t stream)
{
    const float* feat_a = (const float*)d_in[0];
    const float* feat_p = (const float*)d_in[1];
    const float* fmWa = (const float*)d_in[2];
    const float* fmba = (const float*)d_in[3];
    const float* fmWp = (const float*)d_in[4];
    const float* fmbp = (const float*)d_in[5];
    const float* g1w_W = (const float*)d_in[6];  const float* g1w_al = (const float*)d_in[7];
    const float* g1w_ar = (const float*)d_in[8]; const float* g1w_b = (const float*)d_in[9];
    const float* g2w_W = (const float*)d_in[10]; const float* g2w_al = (const float*)d_in[11];
    const float* g2w_ar = (const float*)d_in[12]; const float* g2w_b = (const float*)d_in[13];
    const float* g1wb_W = (const float*)d_in[14]; const float* g1wb_al = (const float*)d_in[15];
    const float* g1wb_ar = (const float*)d_in[16]; const float* g1wb_b = (const float*)d_in[17];
    const float* g2wb_W = (const float*)d_in[18]; const float* g2wb_al = (const float*)d_in[19];
    const float* g2wb_ar = (const float*)d_in[20]; const float* g2wb_b = (const float*)d_in[21];
    const float* g1c_W = (const float*)d_in[22]; const float* g1c_al = (const float*)d_in[23];
    const float* g1c_ar = (const float*)d_in[24]; const float* g1c_b = (const float*)d_in[25];
    const float* g2c_W = (const float*)d_in[26]; const float* g2c_al = (const float*)d_in[27];
    const float* g2c_ar = (const float*)d_in[28]; const float* g2c_b = (const float*)d_in[29];
    const int* w_src = (const int*)d_in[30];
    const int* w_dst = (const int*)d_in[31];
    const int* wb_src = (const int*)d_in[32];
    const int* wb_dst = (const int*)d_in[33];
    const int* c_src = (const int*)d_in[34];
    const int* c_dst = (const int*)d_in[35];

    float* ws = (float*)d_ws;
    size_t off = 0;
    auto alloc = [&](size_t n) { float* p = ws + off; off += n; return p; };
    float* h_a  = alloc(HA);
    float* h_p  = alloc(HP);
    float* h1_p = alloc(HP);
    float* h1_a = alloc(HA);
    unsigned short* Pw  = (unsigned short*)alloc(HA / 2 + 16);
    unsigned short* Pc  = (unsigned short*)alloc(HP / 2 + 16);
    unsigned short* Pwb = (unsigned short*)alloc(HP / 2 + 16);
    float* el_w  = alloc((size_t)N_A * 4);
    float* er_w  = alloc((size_t)N_P * 4);
    float* el_c  = alloc((size_t)N_P * 4);
    float* er_c  = alloc((size_t)N_P * 4);
    float* el_wb = alloc((size_t)N_P * 4);
    float* er_wb = alloc((size_t)N_A * 4);
    float* fold  = alloc(12 * 256);
    int* w_offs  = (int*)alloc(N_P + 1);
    int* c_offs  = (int*)alloc(N_P + 1);
    int* wb_offs = (int*)alloc(N_A + 1);
    int* bcnt3   = (int*)alloc(3 * 256);
    int* bstart3 = (int*)alloc(3 * 257);
    int* gcur3   = (int*)alloc(3 * 256);
    int* w_csr   = (int*)alloc(E_W);
    int* c_csr   = (int*)alloc(E_C);
    int* wb_csr  = (int*)alloc(E_W);
    off = (off + 1) & ~(size_t)1;
    uint2* pairs = (uint2*)alloc((size_t)E_C * 2);

    float* wal_w1 = fold + 0*256,  *war_w1 = fold + 1*256;
    float* wal_c1 = fold + 2*256,  *war_c1 = fold + 3*256;
    float* wal_b1 = fold + 4*256,  *war_b1 = fold + 5*256;
    float* wal_w2 = fold + 6*256,  *war_w2 = fold + 7*256;
    float* wal_c2 = fold + 8*256,  *war_c2 = fold + 9*256;
    float* wal_b2 = fold + 10*256, *war_b2 = fold + 11*256;

    const int SHIFT = 9;
    int NB_P = (N_P + 511) >> 9;
    int NB_A = (N_A + 511) >> 9;

    // ---- CSR build ----
    hipMemsetAsync(bcnt3, 0, 3 * 256 * sizeof(int), stream);
    bucket_hist3<<<3 * 256, 256, 0, stream>>>(w_dst, E_W, bcnt3,
                                              c_dst, E_C, bcnt3 + 256,
                                              wb_dst, E_W, bcnt3 + 512, SHIFT, 256);
    bucket_scan3<<<3, 256, 0, stream>>>(bcnt3, bstart3, gcur3,
                                        w_offs, N_P, E_W,
                                        c_offs, N_P, E_C,
                                        wb_offs, N_A, E_W);
    part_kernel<<<(E_W + 2047) / 2048, 256, 0, stream>>>(w_src, w_dst, gcur3, pairs, E_W, NB_P, SHIFT);
    csr_finalize<<<NB_P, 512, 0, stream>>>(pairs, bstart3, w_offs, w_csr, N_P, SHIFT);
    part_kernel<<<(E_C + 2047) / 2048, 256, 0, stream>>>(c_src, c_dst, gcur3 + 256, pairs, E_C, NB_P, SHIFT);
    csr_finalize<<<NB_P, 512, 0, stream>>>(pairs, bstart3 + 257, c_offs, c_csr, N_P, SHIFT);
    part_kernel<<<(E_W + 2047) / 2048, 256, 0, stream>>>(wb_src, wb_dst, gcur3 + 512, pairs, E_W, NB_A, SHIFT);
    csr_finalize<<<NB_A, 512, 0, stream>>>(pairs, bstart3 + 514, wb_offs, wb_csr, N_A, SHIFT);

    prep_attn12<<<12, 64, 0, stream>>>(
        PA{g1w_W,  g1w_al,  wal_w1, 4}, PA{g1w_W,  g1w_ar,  war_w1, 4},
        PA{g1c_W,  g1c_al,  wal_c1, 4}, PA{g1c_W,  g1c_ar,  war_c1, 4},
        PA{g1wb_W, g1wb_al, wal_b1, 4}, PA{g1wb_W, g1wb_ar, war_b1, 4},
        PA{g2w_W,  g2w_al,  wal_w2, 1}, PA{g2w_W,  g2w_ar,  war_w2, 1},
        PA{g2c_W,  g2c_al,  wal_c2, 1}, PA{g2c_W,  g2c_ar,  war_c2, 1},
        PA{g2wb_W, g2wb_al, wal_b2, 1}, PA{g2wb_W, g2wb_ar, war_b2, 1});

    // ---- feature mapping (one dispatch) ----
    {
        int nb0 = (N_A + 127) / 128;
        int nb1 = (N_P + 127) / 128;
        gemm_fm2<<<nb0 + nb1, 256, 0, stream>>>(feat_a, fmWa, fmba, h_a, N_A, 128, nb0,
                                                feat_p, fmWp, fmbp, h_p, N_P, 256);
    }

    int nbA = (N_A + 127) / 128, nbP = (N_P + 127) / 128;
    int gatGrid = (N_P + 3) / 4 + (N_A + 3) / 4;

    // ---- Layer 1 (H=4) ----
    {
        int npbP = 16, npbA = 32;
        int grid = (N_P + npbP - 1) / npbP + (N_A + npbA - 1) / npbA;
        attnvec_mat<<<grid, 256, 0, stream>>>(
            h_p, N_P, wal_c1, el_c, war_c1, er_c, war_w1, er_w, wal_b1, el_wb,
            h_a, N_A, wal_w1, el_w, war_b1, er_wb, 4, 2);
    }
    proj3<<<nbA + 2 * nbP, 256, 0, stream>>>(h_a, g1w_W, Pw, N_A, nbA,
                                             h_p, g1c_W, Pc, N_P, nbP,
                                             h_p, g1wb_W, Pwb, N_P);
    gat_fused<<<gatGrid, 256, 0, stream>>>(
        N_P, w_offs, w_csr, el_w, er_w, Pw,
        c_offs, c_csr, el_c, er_c, Pc, g1w_b, g1c_b, h1_p,
        N_A, wb_offs, wb_csr, el_wb, er_wb, Pwb, g1wb_b, h1_a, 2, 0);

    // ---- Layer 2 (H=1), normalized output straight to d_out ----
    {
        int npbP = 64, npbA = 64;
        int grid = (N_P + npbP - 1) / npbP + (N_A + npbA - 1) / npbA;
        attnvec_mat<<<grid, 256, 0, stream>>>(
            h1_p, N_P, wal_c2, el_c, war_c2, er_c, war_w2, er_w, wal_b2, el_wb,
            h1_a, N_A, wal_w2, el_w, war_b2, er_wb, 1, 0);
    }
    proj3<<<nbA + 2 * nbP, 256, 0, stream>>>(h1_a, g2w_W, Pw, N_A, nbA,
                                             h1_p, g2c_W, Pc, N_P, nbP,
                                             h1_p, g2wb_W, Pwb, N_P);
    float* out = (float*)d_out;
    gat_fused<<<gatGrid, 256, 0, stream>>>(
        N_P, w_offs, w_csr, el_w, er_w, Pw,
        c_offs, c_csr, el_c, er_c, Pc, g2w_b, g2c_b, out + HA,
        N_A, wb_offs, wb_csr, el_wb, er_wb, Pwb, g2wb_b, out, 0, 1);
}

// Round 12
// 735.425 us; speedup vs baseline: 7.3200x; 1.0683x over previous
//
#include <hip/hip_runtime.h>
#include <hip/hip_bf16.h>

#define N_A 50000
#define N_P 100000
#define E_W 1600000
#define E_C 3200000
#define HA (N_A*64)
#define HP (N_P*64)

typedef __attribute__((ext_vector_type(8))) short short8_t;
typedef __attribute__((ext_vector_type(4))) float f32x4;

__device__ __forceinline__ unsigned short f2b(float f)
{
    __hip_bfloat16 b = __float2bfloat16(f);
    return *reinterpret_cast<unsigned short*>(&b);
}

// ---------------- fused feature-mapping GEMM (2 segments, fp32 out, relu) ----------------
__global__ __launch_bounds__(256) void gemm_fm2(
        const float* __restrict__ X0, const float* __restrict__ W0,
        const float* __restrict__ b0, float* __restrict__ out0, int M0, int K0, int nb0,
        const float* __restrict__ X1, const float* __restrict__ W1,
        const float* __restrict__ b1, float* __restrict__ out1, int M1, int K1)
{
    __shared__ unsigned short Xs[128][72];
    __shared__ unsigned short Wsh[64][72];
    const float *X, *W, *bias; float* out; int M, K, row0;
    if ((int)blockIdx.x < nb0) {
        X = X0; W = W0; bias = b0; out = out0; M = M0; K = K0; row0 = blockIdx.x * 128;
    } else {
        X = X1; W = W1; bias = b1; out = out1; M = M1; K = K1;
        row0 = ((int)blockIdx.x - nb0) * 128;
    }
    int tid = threadIdx.x, lane = tid & 63, wv = tid >> 6;
    int m = lane & 15, kb = lane >> 4;

    f32x4 acc[2][4];
#pragma unroll
    for (int rb = 0; rb < 2; ++rb)
#pragma unroll
        for (int cb = 0; cb < 4; ++cb) acc[rb][cb] = (f32x4){0.f, 0.f, 0.f, 0.f};

    for (int k0 = 0; k0 < K; k0 += 64) {
        int rbase = (tid >> 4) * 8;
        int c4 = (tid & 15) * 4;
#pragma unroll
        for (int i = 0; i < 8; ++i) {
            int rg = row0 + rbase + i; if (rg >= M) rg = M - 1;
            float4 v = *reinterpret_cast<const float4*>(&X[(long)rg * K + k0 + c4]);
            Xs[rbase + i][c4 + 0] = f2b(v.x);
            Xs[rbase + i][c4 + 1] = f2b(v.y);
            Xs[rbase + i][c4 + 2] = f2b(v.z);
            Xs[rbase + i][c4 + 3] = f2b(v.w);
        }
        int wr = tid >> 2;
        int wc = (tid & 3) * 16;
#pragma unroll
        for (int q = 0; q < 4; ++q) {
            float4 v = *reinterpret_cast<const float4*>(&W[(long)wr * K + k0 + wc + q * 4]);
            Wsh[wr][wc + q * 4 + 0] = f2b(v.x);
            Wsh[wr][wc + q * 4 + 1] = f2b(v.y);
            Wsh[wr][wc + q * 4 + 2] = f2b(v.z);
            Wsh[wr][wc + q * 4 + 3] = f2b(v.w);
        }
        __syncthreads();
#pragma unroll
        for (int kc = 0; kc < 2; ++kc) {
            short8_t a0 = *reinterpret_cast<const short8_t*>(&Xs[wv * 32 + m][kc * 32 + kb * 8]);
            short8_t a1 = *reinterpret_cast<const short8_t*>(&Xs[wv * 32 + 16 + m][kc * 32 + kb * 8]);
#pragma unroll
            for (int cb = 0; cb < 4; ++cb) {
                short8_t b = *reinterpret_cast<const short8_t*>(&Wsh[cb * 16 + m][kc * 32 + kb * 8]);
                acc[0][cb] = __builtin_amdgcn_mfma_f32_16x16x32_bf16(a0, b, acc[0][cb], 0, 0, 0);
                acc[1][cb] = __builtin_amdgcn_mfma_f32_16x16x32_bf16(a1, b, acc[1][cb], 0, 0, 0);
            }
        }
        __syncthreads();
    }

#pragma unroll
    for (int rb = 0; rb < 2; ++rb)
#pragma unroll
    for (int j = 0; j < 4; ++j) {
        int r = row0 + wv * 32 + rb * 16 + (lane >> 4) * 4 + j;
        if (r < M) {
#pragma unroll
            for (int cb = 0; cb < 4; ++cb) {
                int c = cb * 16 + m;
                float v = acc[rb][cb][j] + bias[c];
                out[(long)r * 64 + c] = fmaxf(v, 0.f);
            }
        }
    }
}

// ---------------- fused 3-projection GEMM (K=64, bf16 out) ----------------
__global__ __launch_bounds__(256) void proj3(
        const float* __restrict__ X0, const float* __restrict__ W0,
        unsigned short* __restrict__ o0, int M0, int nb0,
        const float* __restrict__ X1, const float* __restrict__ W1,
        unsigned short* __restrict__ o1, int M1, int nb1,
        const float* __restrict__ X2, const float* __restrict__ W2,
        unsigned short* __restrict__ o2, int M2)
{
    __shared__ unsigned short Xs[128][72];
    __shared__ unsigned short Wsh[64][72];
    const float *X, *W; unsigned short* out; int M, row0;
    if ((int)blockIdx.x < nb0) {
        X = X0; W = W0; out = o0; M = M0; row0 = blockIdx.x * 128;
    } else if ((int)blockIdx.x < nb0 + nb1) {
        X = X1; W = W1; out = o1; M = M1; row0 = ((int)blockIdx.x - nb0) * 128;
    } else {
        X = X2; W = W2; out = o2; M = M2; row0 = ((int)blockIdx.x - nb0 - nb1) * 128;
    }
    int tid = threadIdx.x, lane = tid & 63, wv = tid >> 6;
    int m = lane & 15, kb = lane >> 4;

    int rbase = (tid >> 4) * 8;
    int c4 = (tid & 15) * 4;
#pragma unroll
    for (int i = 0; i < 8; ++i) {
        int rg = row0 + rbase + i; if (rg >= M) rg = M - 1;
        float4 v = *reinterpret_cast<const float4*>(&X[(long)rg * 64 + c4]);
        Xs[rbase + i][c4 + 0] = f2b(v.x);
        Xs[rbase + i][c4 + 1] = f2b(v.y);
        Xs[rbase + i][c4 + 2] = f2b(v.z);
        Xs[rbase + i][c4 + 3] = f2b(v.w);
    }
    int wr = tid >> 2;
    int wc = (tid & 3) * 16;
#pragma unroll
    for (int q = 0; q < 4; ++q) {
        float4 v = *reinterpret_cast<const float4*>(&W[(long)wr * 64 + wc + q * 4]);
        Wsh[wr][wc + q * 4 + 0] = f2b(v.x);
        Wsh[wr][wc + q * 4 + 1] = f2b(v.y);
        Wsh[wr][wc + q * 4 + 2] = f2b(v.z);
        Wsh[wr][wc + q * 4 + 3] = f2b(v.w);
    }
    __syncthreads();

    f32x4 acc[2][4];
#pragma unroll
    for (int rb = 0; rb < 2; ++rb)
#pragma unroll
        for (int cb = 0; cb < 4; ++cb) acc[rb][cb] = (f32x4){0.f, 0.f, 0.f, 0.f};
#pragma unroll
    for (int kc = 0; kc < 2; ++kc) {
        short8_t a0 = *reinterpret_cast<const short8_t*>(&Xs[wv * 32 + m][kc * 32 + kb * 8]);
        short8_t a1 = *reinterpret_cast<const short8_t*>(&Xs[wv * 32 + 16 + m][kc * 32 + kb * 8]);
#pragma unroll
        for (int cb = 0; cb < 4; ++cb) {
            short8_t b = *reinterpret_cast<const short8_t*>(&Wsh[cb * 16 + m][kc * 32 + kb * 8]);
            acc[0][cb] = __builtin_amdgcn_mfma_f32_16x16x32_bf16(a0, b, acc[0][cb], 0, 0, 0);
            acc[1][cb] = __builtin_amdgcn_mfma_f32_16x16x32_bf16(a1, b, acc[1][cb], 0, 0, 0);
        }
    }
#pragma unroll
    for (int rb = 0; rb < 2; ++rb)
#pragma unroll
    for (int j = 0; j < 4; ++j) {
        int r = row0 + wv * 32 + rb * 16 + (lane >> 4) * 4 + j;
        if (r < M) {
#pragma unroll
            for (int cb = 0; cb < 4; ++cb)
                out[(long)r * 64 + cb * 16 + m] = f2b(acc[rb][cb][j]);
        }
    }
}

// ---------------- fold W*a for 12 attention vectors ----------------
struct PA { const float* W; const float* a; float* o; int H; };
__global__ void prep_attn12(PA p0, PA p1, PA p2, PA p3, PA p4, PA p5,
                            PA p6, PA p7, PA p8, PA p9, PA p10, PA p11)
{
    PA p;
    switch (blockIdx.x) {
        case 0: p = p0; break;  case 1: p = p1; break;  case 2: p = p2; break;
        case 3: p = p3; break;  case 4: p = p4; break;  case 5: p = p5; break;
        case 6: p = p6; break;  case 7: p = p7; break;  case 8: p = p8; break;
        case 9: p = p9; break;  case 10: p = p10; break; default: p = p11; break;
    }
    int k = threadIdx.x;
    int F = 64 / p.H;
    for (int hh = 0; hh < p.H; ++hh) {
        float s = 0.f;
        for (int f = 0; f < F; ++f)
            s = fmaf(p.W[(hh * F + f) * 64 + k], p.a[hh * F + f], s);
        p.o[k * p.H + hh] = s;
    }
}

// ---------------- el/er via tall-skinny GEMV ----------------
__global__ __launch_bounds__(256) void attnvec_mat(
        const float* __restrict__ hP, int NPn,
        const float* __restrict__ fP0, float* __restrict__ oP0,
        const float* __restrict__ fP1, float* __restrict__ oP1,
        const float* __restrict__ fP2, float* __restrict__ oP2,
        const float* __restrict__ fP3, float* __restrict__ oP3,
        const float* __restrict__ hA, int NAn,
        const float* __restrict__ fA0, float* __restrict__ oA0,
        const float* __restrict__ fA1, float* __restrict__ oA1,
        int H, int hb)
{
    __shared__ float hs[64 * 66];
    int tid = threadIdx.x;
    int slotsP = (H == 4) ? 16 : 4;
    int npbP = 256 / slotsP;
    int blocksP = (NPn + npbP - 1) / npbP;

    const float* hsrc; int node0, npb, slots, ncols, N;
    const float* fv0; const float* fv1; const float* fv2; const float* fv3;
    float* ov0; float* ov1; float* ov2; float* ov3;
    if ((int)blockIdx.x < blocksP) {
        hsrc = hP; N = NPn; slots = slotsP; npb = npbP;
        node0 = blockIdx.x * npb;
        ncols = 4 * H;
        fv0 = fP0; ov0 = oP0; fv1 = fP1; ov1 = oP1;
        fv2 = fP2; ov2 = oP2; fv3 = fP3; ov3 = oP3;
    } else {
        int b = (int)blockIdx.x - blocksP;
        hsrc = hA; N = NAn;
        slots = (H == 4) ? 8 : 4; npb = 256 / slots;
        node0 = b * npb;
        ncols = 2 * H;
        fv0 = fA0; ov0 = oA0; fv1 = fA1; ov1 = oA1;
        fv2 = fA0; ov2 = oA0; fv3 = fA1; ov3 = oA1;
    }

    for (int idx = tid; idx < npb * 64; idx += 256) {
        int row = idx >> 6, k = idx & 63;
        int g = node0 + row; if (g >= N) g = N - 1;
        hs[row * 66 + k] = hsrc[(long)g * 64 + k];
    }
    __syncthreads();

    int sshift = (slots == 16) ? 4 : (slots == 8) ? 3 : 2;
    int nl = tid >> sshift;
    int c = tid & (slots - 1);
    int node = node0 + nl;
    if (node >= N || c >= ncols || nl >= npb) return;
    int f = c >> hb;
    int hh = c & (H - 1);
    const float* fv = (f == 0) ? fv0 : (f == 1) ? fv1 : (f == 2) ? fv2 : fv3;
    float* ov = (f == 0) ? ov0 : (f == 1) ? ov1 : (f == 2) ? ov2 : ov3;

    float s = 0.f;
    const float* hrow = &hs[nl * 66];
#pragma unroll 8
    for (int k = 0; k < 64; ++k)
        s = fmaf(hrow[k], fv[k * H + hh], s);
    ov[(long)node * H + hh] = s;
}

// ---------------- CSR build ----------------
__global__ void bucket_hist3(const int* __restrict__ d0, int E0, int* __restrict__ b0,
                             const int* __restrict__ d1, int E1, int* __restrict__ b1,
                             const int* __restrict__ d2, int E2, int* __restrict__ b2,
                             int shift, int blocksPer)
{
    int g = blockIdx.x / blocksPer, bb = blockIdx.x - g * blocksPer;
    const int* dst = g == 0 ? d0 : g == 1 ? d1 : d2;
    int E = g == 0 ? E0 : g == 1 ? E1 : E2;
    int* bcnt = g == 0 ? b0 : g == 1 ? b1 : b2;
    __shared__ int h[256];
    int tid = threadIdx.x;
    h[tid] = 0;
    __syncthreads();
    for (long i = (long)bb * 256 + tid; i < E; i += (long)blocksPer * 256)
        atomicAdd(&h[dst[i] >> shift], 1);
    __syncthreads();
    if (h[tid]) atomicAdd(&bcnt[tid], h[tid]);
}

__global__ void bucket_scan3(int* __restrict__ bcnt, int* __restrict__ bstart,
                             int* __restrict__ gcur,
                             int* __restrict__ o0, int Nn0, int Ee0,
                             int* __restrict__ o1, int Nn1, int Ee1,
                             int* __restrict__ o2, int Nn2, int Ee2)
{
    int g = blockIdx.x;
    int* bc = bcnt + g * 256;
    int* bs = bstart + g * 257;
    int* gc = gcur + g * 256;
    int* offs = g == 0 ? o0 : g == 1 ? o1 : o2;
    int N = g == 0 ? Nn0 : g == 1 ? Nn1 : Nn2;
    int E = g == 0 ? Ee0 : g == 1 ? Ee1 : Ee2;
    __shared__ int sc[256];
    int tid = threadIdx.x;
    int v = bc[tid];
    sc[tid] = v;
    __syncthreads();
    for (int off = 1; off < 256; off <<= 1) {
        int t = (tid >= off) ? sc[tid - off] : 0;
        __syncthreads();
        sc[tid] += t;
        __syncthreads();
    }
    int excl = sc[tid] - v;
    bs[tid] = excl;
    gc[tid] = excl;
    if (tid == 255) bs[256] = E;
    if (tid == 0) offs[N] = E;
}

#define EPT 8
// 3 graphs in one dispatch; each block handles a tile of one graph's edges
__global__ __launch_bounds__(256) void part3(
        const int* __restrict__ s0, const int* __restrict__ d0, int E0, int nb0,
        uint2* __restrict__ p0,
        const int* __restrict__ s1, const int* __restrict__ d1, int E1, int nb1,
        uint2* __restrict__ p1,
        const int* __restrict__ s2g, const int* __restrict__ d2g, int E2,
        uint2* __restrict__ p2,
        int* __restrict__ gcur3, int shift)
{
    const int* src; const int* dst; int E; uint2* pairs; int* gcur; long base;
    if ((int)blockIdx.x < nb0) {
        src = s0; dst = d0; E = E0; pairs = p0; gcur = gcur3;
        base = (long)blockIdx.x * (256 * EPT);
    } else if ((int)blockIdx.x < nb0 + nb1) {
        src = s1; dst = d1; E = E1; pairs = p1; gcur = gcur3 + 256;
        base = (long)((int)blockIdx.x - nb0) * (256 * EPT);
    } else {
        src = s2g; dst = d2g; E = E2; pairs = p2; gcur = gcur3 + 512;
        base = (long)((int)blockIdx.x - nb0 - nb1) * (256 * EPT);
    }
    __shared__ int hcnt[256];
    __shared__ int hbase[256];
    int tid = threadIdx.x;
    hcnt[tid] = 0;
    __syncthreads();
    int b[EPT], r[EPT], s[EPT], d[EPT];
#pragma unroll
    for (int k = 0; k < EPT; ++k) {
        long idx = base + k * 256 + tid;
        if (idx < E) {
            s[k] = src[idx]; d[k] = dst[idx];
            b[k] = d[k] >> shift;
            r[k] = atomicAdd(&hcnt[b[k]], 1);
        } else b[k] = -1;
    }
    __syncthreads();
    if (hcnt[tid]) hbase[tid] = atomicAdd(&gcur[tid], hcnt[tid]);
    __syncthreads();
#pragma unroll
    for (int k = 0; k < EPT; ++k) {
        if (b[k] >= 0)
            pairs[hbase[b[k]] + r[k]] = make_uint2((unsigned)s[k], (unsigned)d[k]);
    }
}

// 3 graphs in one dispatch; one block per bucket
__global__ __launch_bounds__(512) void csr_fin3(
        const uint2* __restrict__ p0, const int* __restrict__ bs0,
        int* __restrict__ of0, int* __restrict__ c0, int N0, int NB0,
        const uint2* __restrict__ p1, const int* __restrict__ bs1,
        int* __restrict__ of1, int* __restrict__ c1, int N1, int NB1,
        const uint2* __restrict__ p2, const int* __restrict__ bs2,
        int* __restrict__ of2, int* __restrict__ c2, int N2,
        int shift)
{
    const uint2* pairs; const int* bstart; int* offs; int* csr; int N, b;
    if ((int)blockIdx.x < NB0) {
        pairs = p0; bstart = bs0; offs = of0; csr = c0; N = N0; b = blockIdx.x;
    } else if ((int)blockIdx.x < NB0 + NB1) {
        pairs = p1; bstart = bs1; offs = of1; csr = c1; N = N1; b = (int)blockIdx.x - NB0;
    } else {
        pairs = p2; bstart = bs2; offs = of2; csr = c2; N = N2;
        b = (int)blockIdx.x - NB0 - NB1;
    }
    __shared__ int cnt[512];
    __shared__ int sc[512];
    int tid = threadIdx.x;
    int d0 = b << shift;
    int pS = bstart[b], pE = bstart[b + 1];
    cnt[tid] = 0;
    __syncthreads();
    for (int i = pS + tid; i < pE; i += 512)
        atomicAdd(&cnt[pairs[i].y - d0], 1);
    __syncthreads();
    int v = cnt[tid];
    sc[tid] = v;
    __syncthreads();
    for (int off = 1; off < 512; off <<= 1) {
        int t = (tid >= off) ? sc[tid - off] : 0;
        __syncthreads();
        sc[tid] += t;
        __syncthreads();
    }
    int excl = sc[tid] - v;
    if (d0 + tid < N) offs[d0 + tid] = pS + excl;
    cnt[tid] = excl;
    __syncthreads();
    for (int i = pS + tid; i < pE; i += 512) {
        uint2 u = pairs[i];
        int p = atomicAdd(&cnt[u.y - d0], 1);
        csr[pS + p] = (int)u.x;
    }
}

// ---------------- fused GAT layer (software-pipelined pass A) ----------------
__device__ __forceinline__ void gat_graph(int d, const int* __restrict__ offs,
        const int* __restrict__ csr, const float* __restrict__ el,
        const float* __restrict__ er, const unsigned short* __restrict__ P,
        int hshift, int lane, float* o)
{
    int H = 1 << hshift;
    int off = offs[d];
    int n = offs[d + 1] - off;
    if (n == 0) return;
    int g8 = lane >> 3;
    int fo = (lane & 7) * 8;
    int hf = (hshift == 2) ? ((lane & 7) >> 1) : 0;
    int h = lane & (H - 1);
    float erd = er[d * H + h];
    int estep = 64 >> hshift;
    int i0 = lane >> hshift;
    float acc[8];
#pragma unroll
    for (int q = 0; q < 8; ++q) acc[q] = 0.f;
    float ssum = 0.f;

    // prefetch round 0
    int sn_c = 0; float elv_c = 0.f;
    if (i0 < n) { sn_c = csr[off + i0]; elv_c = el[sn_c * H + h]; }

    for (int base = 0; base < n; base += estep) {
        // prefetch next macro-round's csr + el (overlaps with this round's gathers)
        int inext = base + estep + i0;
        int sn_n = 0; float elv_n = 0.f;
        if (inext < n) { sn_n = csr[off + inext]; elv_n = el[sn_n * H + h]; }

        float a = 0.f;
        if (base + i0 < n) {
            float v = elv_c + erd;
            v = v > 0.f ? v : 0.2f * v;
            a = __expf(v);
            ssum += a;
        }
        int rounds = min(estep, n - base);
#pragma unroll 2
        for (int r = 0; r * 8 < rounds; ++r) {
            int sl = r * 8 + g8;
            int lsn = sl << hshift;
            int s2 = __shfl(sn_c, lsn, 64);
            float a2 = __shfl(a, lsn | hf, 64);
            uint4 u = *reinterpret_cast<const uint4*>(&P[(long)s2 * 64 + fo]);
            acc[0] = fmaf(__uint_as_float(u.x << 16), a2, acc[0]);
            acc[1] = fmaf(__uint_as_float(u.x & 0xffff0000u), a2, acc[1]);
            acc[2] = fmaf(__uint_as_float(u.y << 16), a2, acc[2]);
            acc[3] = fmaf(__uint_as_float(u.y & 0xffff0000u), a2, acc[3]);
            acc[4] = fmaf(__uint_as_float(u.z << 16), a2, acc[4]);
            acc[5] = fmaf(__uint_as_float(u.z & 0xffff0000u), a2, acc[5]);
            acc[6] = fmaf(__uint_as_float(u.w << 16), a2, acc[6]);
            acc[7] = fmaf(__uint_as_float(u.w & 0xffff0000u), a2, acc[7]);
        }
        sn_c = sn_n; elv_c = elv_n;
    }

    for (int oo = H; oo < 64; oo <<= 1) ssum += __shfl_xor(ssum, oo, 64);
    float rinv = 1.f / __shfl(ssum, hf, 64);
#pragma unroll
    for (int q = 0; q < 8; ++q) {
        acc[q] += __shfl_xor(acc[q], 8, 64);
        acc[q] += __shfl_xor(acc[q], 16, 64);
        acc[q] += __shfl_xor(acc[q], 32, 64);
        o[q] = fmaf(acc[q], rinv, o[q]);
    }
}

__global__ void gat_fused(
        int NPn, const int* __restrict__ w_offs, const int* __restrict__ w_csr,
        const float* __restrict__ el_w, const float* __restrict__ er_w,
        const unsigned short* __restrict__ Pw,
        const int* __restrict__ c_offs, const int* __restrict__ c_csr,
        const float* __restrict__ el_c, const float* __restrict__ er_c,
        const unsigned short* __restrict__ Pc,
        const float* __restrict__ bP0, const float* __restrict__ bP1,
        float* __restrict__ outP,
        int NAn, const int* __restrict__ wb_offs, const int* __restrict__ wb_csr,
        const float* __restrict__ el_wb, const float* __restrict__ er_wb,
        const unsigned short* __restrict__ Pwb,
        const float* __restrict__ bA0, float* __restrict__ outA,
        int hshift, int doNorm)
{
    int blocksP = (NPn + 3) >> 2;
    int lane = threadIdx.x & 63;
    int sub = threadIdx.x >> 6;
    int fo = (lane & 7) * 8;
    float o[8];
    float* dst;

    if ((int)blockIdx.x < blocksP) {
        int d = ((int)blockIdx.x << 2) | sub;
        if (d >= NPn) return;
#pragma unroll
        for (int q = 0; q < 8; ++q) o[q] = bP0[fo + q] + bP1[fo + q];
        gat_graph(d, w_offs, w_csr, el_w, er_w, Pw, hshift, lane, o);
        gat_graph(d, c_offs, c_csr, el_c, er_c, Pc, hshift, lane, o);
        dst = outP + (long)d * 64;
    } else {
        int d = (((int)blockIdx.x - blocksP) << 2) | sub;
        if (d >= NAn) return;
#pragma unroll
        for (int q = 0; q < 8; ++q) o[q] = bA0[fo + q];
        gat_graph(d, wb_offs, wb_csr, el_wb, er_wb, Pwb, hshift, lane, o);
        dst = outA + (long)d * 64;
    }

    if (doNorm) {
        float ss = 0.f;
#pragma unroll
        for (int q = 0; q < 8; ++q) ss = fmaf(o[q], o[q], ss);
        ss += __shfl_xor(ss, 1, 64);
        ss += __shfl_xor(ss, 2, 64);
        ss += __shfl_xor(ss, 4, 64);
        float sc = 1.f / fmaxf(sqrtf(ss), 1e-12f);
#pragma unroll
        for (int q = 0; q < 8; ++q) o[q] *= sc;
    }
    if (lane < 8) {
        float4 o0, o1;
        o0.x = o[0]; o0.y = o[1]; o0.z = o[2]; o0.w = o[3];
        o1.x = o[4]; o1.y = o[5]; o1.z = o[6]; o1.w = o[7];
        *reinterpret_cast<float4*>(dst + fo) = o0;
        *reinterpret_cast<float4*>(dst + fo + 4) = o1;
    }
}

extern "C" void kernel_launch(void* const* d_in, const int* in_sizes, int n_in,
                              void* d_out, int out_size, void* d_ws, size_t ws_size,
                              hipStream_t stream)
{
    const float* feat_a = (const float*)d_in[0];
    const float* feat_p = (const float*)d_in[1];
    const float* fmWa = (const float*)d_in[2];
    const float* fmba = (const float*)d_in[3];
    const float* fmWp = (const float*)d_in[4];
    const float* fmbp = (const float*)d_in[5];
    const float* g1w_W = (const float*)d_in[6];  const float* g1w_al = (const float*)d_in[7];
    const float* g1w_ar = (const float*)d_in[8]; const float* g1w_b = (const float*)d_in[9];
    const float* g2w_W = (const float*)d_in[10]; const float* g2w_al = (const float*)d_in[11];
    const float* g2w_ar = (const float*)d_in[12]; const float* g2w_b = (const float*)d_in[13];
    const float* g1wb_W = (const float*)d_in[14]; const float* g1wb_al = (const float*)d_in[15];
    const float* g1wb_ar = (const float*)d_in[16]; const float* g1wb_b = (const float*)d_in[17];
    const float* g2wb_W = (const float*)d_in[18]; const float* g2wb_al = (const float*)d_in[19];
    const float* g2wb_ar = (const float*)d_in[20]; const float* g2wb_b = (const float*)d_in[21];
    const float* g1c_W = (const float*)d_in[22]; const float* g1c_al = (const float*)d_in[23];
    const float* g1c_ar = (const float*)d_in[24]; const float* g1c_b = (const float*)d_in[25];
    const float* g2c_W = (const float*)d_in[26]; const float* g2c_al = (const float*)d_in[27];
    const float* g2c_ar = (const float*)d_in[28]; const float* g2c_b = (const float*)d_in[29];
    const int* w_src = (const int*)d_in[30];
    const int* w_dst = (const int*)d_in[31];
    const int* wb_src = (const int*)d_in[32];
    const int* wb_dst = (const int*)d_in[33];
    const int* c_src = (const int*)d_in[34];
    const int* c_dst = (const int*)d_in[35];

    float* ws = (float*)d_ws;
    size_t off = 0;
    auto alloc = [&](size_t n) { float* p = ws + off; off += n; return p; };
    // region0: h buffers; pairs ALIASES this region (pairs dead before gemm_fm2 writes h)
    float* h_a  = alloc(HA);
    float* h_p  = alloc(HP);
    float* h1_p = alloc(HP);
    float* h1_a = alloc(HA);
    uint2* pairs_w  = (uint2*)h_a;               // E_W uint2 = 12.8MB
    uint2* pairs_c  = (uint2*)h_a + E_W;         // E_C uint2 = 25.6MB
    uint2* pairs_wb = (uint2*)h_a + E_W + E_C;   // E_W uint2 ; total 51.2MB <= 76.8MB
    unsigned short* Pw  = (unsigned short*)alloc(HA / 2 + 16);
    unsigned short* Pc  = (unsigned short*)alloc(HP / 2 + 16);
    unsigned short* Pwb = (unsigned short*)alloc(HP / 2 + 16);
    float* el_w  = alloc((size_t)N_A * 4);
    float* er_w  = alloc((size_t)N_P * 4);
    float* el_c  = alloc((size_t)N_P * 4);
    float* er_c  = alloc((size_t)N_P * 4);
    float* el_wb = alloc((size_t)N_P * 4);
    float* er_wb = alloc((size_t)N_A * 4);
    float* fold  = alloc(12 * 256);
    int* w_offs  = (int*)alloc(N_P + 1);
    int* c_offs  = (int*)alloc(N_P + 1);
    int* wb_offs = (int*)alloc(N_A + 1);
    int* bcnt3   = (int*)alloc(3 * 256);
    int* bstart3 = (int*)alloc(3 * 257);
    int* gcur3   = (int*)alloc(3 * 256);
    int* w_csr   = (int*)alloc(E_W);
    int* c_csr   = (int*)alloc(E_C);
    int* wb_csr  = (int*)alloc(E_W);

    float* wal_w1 = fold + 0*256,  *war_w1 = fold + 1*256;
    float* wal_c1 = fold + 2*256,  *war_c1 = fold + 3*256;
    float* wal_b1 = fold + 4*256,  *war_b1 = fold + 5*256;
    float* wal_w2 = fold + 6*256,  *war_w2 = fold + 7*256;
    float* wal_c2 = fold + 8*256,  *war_c2 = fold + 9*256;
    float* wal_b2 = fold + 10*256, *war_b2 = fold + 11*256;

    const int SHIFT = 9;
    int NB_P = (N_P + 511) >> 9;
    int NB_A = (N_A + 511) >> 9;

    // ---- CSR build (uses pairs region, completes before h buffers are written) ----
    hipMemsetAsync(bcnt3, 0, 3 * 256 * sizeof(int), stream);
    bucket_hist3<<<3 * 256, 256, 0, stream>>>(w_dst, E_W, bcnt3,
                                              c_dst, E_C, bcnt3 + 256,
                                              wb_dst, E_W, bcnt3 + 512, SHIFT, 256);
    bucket_scan3<<<3, 256, 0, stream>>>(bcnt3, bstart3, gcur3,
                                        w_offs, N_P, E_W,
                                        c_offs, N_P, E_C,
                                        wb_offs, N_A, E_W);
    {
        int nbW = (E_W + 2047) / 2048, nbC = (E_C + 2047) / 2048;
        part3<<<nbW + nbC + nbW, 256, 0, stream>>>(
            w_src, w_dst, E_W, nbW, pairs_w,
            c_src, c_dst, E_C, nbC, pairs_c,
            wb_src, wb_dst, E_W, pairs_wb, gcur3, SHIFT);
        csr_fin3<<<NB_P + NB_P + NB_A, 512, 0, stream>>>(
            pairs_w, bstart3, w_offs, w_csr, N_P, NB_P,
            pairs_c, bstart3 + 257, c_offs, c_csr, N_P, NB_P,
            pairs_wb, bstart3 + 514, wb_offs, wb_csr, N_A, SHIFT);
    }

    prep_attn12<<<12, 64, 0, stream>>>(
        PA{g1w_W,  g1w_al,  wal_w1, 4}, PA{g1w_W,  g1w_ar,  war_w1, 4},
        PA{g1c_W,  g1c_al,  wal_c1, 4}, PA{g1c_W,  g1c_ar,  war_c1, 4},
        PA{g1wb_W, g1wb_al, wal_b1, 4}, PA{g1wb_W, g1wb_ar, war_b1, 4},
        PA{g2w_W,  g2w_al,  wal_w2, 1}, PA{g2w_W,  g2w_ar,  war_w2, 1},
        PA{g2c_W,  g2c_al,  wal_c2, 1}, PA{g2c_W,  g2c_ar,  war_c2, 1},
        PA{g2wb_W, g2wb_al, wal_b2, 1}, PA{g2wb_W, g2wb_ar, war_b2, 1});

    // ---- feature mapping (one dispatch) — pairs region now dead ----
    {
        int nb0 = (N_A + 127) / 128;
        int nb1 = (N_P + 127) / 128;
        gemm_fm2<<<nb0 + nb1, 256, 0, stream>>>(feat_a, fmWa, fmba, h_a, N_A, 128, nb0,
                                                feat_p, fmWp, fmbp, h_p, N_P, 256);
    }

    int nbA = (N_A + 127) / 128, nbP = (N_P + 127) / 128;
    int gatGrid = (N_P + 3) / 4 + (N_A + 3) / 4;

    // ---- Layer 1 (H=4) ----
    {
        int npbP = 16, npbA = 32;
        int grid = (N_P + npbP - 1) / npbP + (N_A + npbA - 1) / npbA;
        attnvec_mat<<<grid, 256, 0, stream>>>(
            h_p, N_P, wal_c1, el_c, war_c1, er_c, war_w1, er_w, wal_b1, el_wb,
            h_a, N_A, wal_w1, el_w, war_b1, er_wb, 4, 2);
    }
    proj3<<<nbA + 2 * nbP, 256, 0, stream>>>(h_a, g1w_W, Pw, N_A, nbA,
                                             h_p, g1c_W, Pc, N_P, nbP,
                                             h_p, g1wb_W, Pwb, N_P);
    gat_fused<<<gatGrid, 256, 0, stream>>>(
        N_P, w_offs, w_csr, el_w, er_w, Pw,
        c_offs, c_csr, el_c, er_c, Pc, g1w_b, g1c_b, h1_p,
        N_A, wb_offs, wb_csr, el_wb, er_wb, Pwb, g1wb_b, h1_a, 2, 0);

    // ---- Layer 2 (H=1), normalized output straight to d_out ----
    {
        int npbP = 64, npbA = 64;
        int grid = (N_P + npbP - 1) / npbP + (N_A + npbA - 1) / npbA;
        attnvec_mat<<<grid, 256, 0, stream>>>(
            h1_p, N_P, wal_c2, el_c, war_c2, er_c, war_w2, er_w, wal_b2, el_wb,
            h1_a, N_A, wal_w2, el_w, war_b2, er_wb, 1, 0);
    }
    proj3<<<nbA + 2 * nbP, 256, 0, stream>>>(h1_a, g2w_W, Pw, N_A, nbA,
                                             h1_p, g2c_W, Pc, N_P, nbP,
                                             h1_p, g2wb_W, Pwb, N_P);
    float* out = (float*)d_out;
    gat_fused<<<gatGrid, 256, 0, stream>>>(
        N_P, w_offs, w_csr, el_w, er_w, Pw,
        c_offs, c_csr, el_c, er_c, Pc, g2w_b, g2c_b, out + HA,
        N_A, wb_offs, wb_csr, el_wb, er_wb, Pwb, g2wb_b, out, 0, 1);
}

// Round 13
// 734.662 us; speedup vs baseline: 7.3276x; 1.0010x over previous
//
#include <hip/hip_runtime.h>
#include <hip/hip_bf16.h>

#define N_A 50000
#define N_P 100000
#define E_W 1600000
#define E_C 3200000
#define HA (N_A*64)
#define HP (N_P*64)

typedef __attribute__((ext_vector_type(8))) short short8_t;
typedef __attribute__((ext_vector_type(4))) float f32x4;

__device__ __forceinline__ unsigned short f2b(float f)
{
    __hip_bfloat16 b = __float2bfloat16(f);
    return *reinterpret_cast<unsigned short*>(&b);
}
__device__ __forceinline__ float b2f(unsigned short u)
{
    return __uint_as_float((unsigned)u << 16);
}

// ---------------- fused feature-mapping GEMM (2 segments, fp32 out, relu) ----------------
__global__ __launch_bounds__(256) void gemm_fm2(
        const float* __restrict__ X0, const float* __restrict__ W0,
        const float* __restrict__ b0, float* __restrict__ out0, int M0, int K0, int nb0,
        const float* __restrict__ X1, const float* __restrict__ W1,
        const float* __restrict__ b1, float* __restrict__ out1, int M1, int K1)
{
    __shared__ unsigned short Xs[128][72];
    __shared__ unsigned short Wsh[64][72];
    const float *X, *W, *bias; float* out; int M, K, row0;
    if ((int)blockIdx.x < nb0) {
        X = X0; W = W0; bias = b0; out = out0; M = M0; K = K0; row0 = blockIdx.x * 128;
    } else {
        X = X1; W = W1; bias = b1; out = out1; M = M1; K = K1;
        row0 = ((int)blockIdx.x - nb0) * 128;
    }
    int tid = threadIdx.x, lane = tid & 63, wv = tid >> 6;
    int m = lane & 15, kb = lane >> 4;

    f32x4 acc[2][4];
#pragma unroll
    for (int rb = 0; rb < 2; ++rb)
#pragma unroll
        for (int cb = 0; cb < 4; ++cb) acc[rb][cb] = (f32x4){0.f, 0.f, 0.f, 0.f};

    for (int k0 = 0; k0 < K; k0 += 64) {
        int rbase = (tid >> 4) * 8;
        int c4 = (tid & 15) * 4;
#pragma unroll
        for (int i = 0; i < 8; ++i) {
            int rg = row0 + rbase + i; if (rg >= M) rg = M - 1;
            float4 v = *reinterpret_cast<const float4*>(&X[(long)rg * K + k0 + c4]);
            Xs[rbase + i][c4 + 0] = f2b(v.x);
            Xs[rbase + i][c4 + 1] = f2b(v.y);
            Xs[rbase + i][c4 + 2] = f2b(v.z);
            Xs[rbase + i][c4 + 3] = f2b(v.w);
        }
        int wr = tid >> 2;
        int wc = (tid & 3) * 16;
#pragma unroll
        for (int q = 0; q < 4; ++q) {
            float4 v = *reinterpret_cast<const float4*>(&W[(long)wr * K + k0 + wc + q * 4]);
            Wsh[wr][wc + q * 4 + 0] = f2b(v.x);
            Wsh[wr][wc + q * 4 + 1] = f2b(v.y);
            Wsh[wr][wc + q * 4 + 2] = f2b(v.z);
            Wsh[wr][wc + q * 4 + 3] = f2b(v.w);
        }
        __syncthreads();
#pragma unroll
        for (int kc = 0; kc < 2; ++kc) {
            short8_t a0 = *reinterpret_cast<const short8_t*>(&Xs[wv * 32 + m][kc * 32 + kb * 8]);
            short8_t a1 = *reinterpret_cast<const short8_t*>(&Xs[wv * 32 + 16 + m][kc * 32 + kb * 8]);
#pragma unroll
            for (int cb = 0; cb < 4; ++cb) {
                short8_t b = *reinterpret_cast<const short8_t*>(&Wsh[cb * 16 + m][kc * 32 + kb * 8]);
                acc[0][cb] = __builtin_amdgcn_mfma_f32_16x16x32_bf16(a0, b, acc[0][cb], 0, 0, 0);
                acc[1][cb] = __builtin_amdgcn_mfma_f32_16x16x32_bf16(a1, b, acc[1][cb], 0, 0, 0);
            }
        }
        __syncthreads();
    }

#pragma unroll
    for (int rb = 0; rb < 2; ++rb)
#pragma unroll
    for (int j = 0; j < 4; ++j) {
        int r = row0 + wv * 32 + rb * 16 + (lane >> 4) * 4 + j;
        if (r < M) {
#pragma unroll
            for (int cb = 0; cb < 4; ++cb) {
                int c = cb * 16 + m;
                float v = acc[rb][cb][j] + bias[c];
                out[(long)r * 64 + c] = fmaxf(v, 0.f);
            }
        }
    }
}

// ---------------- fused 3-projection GEMM (K=64, bf16 out) + el/er folds from LDS -------
// seg0 (authors): Pw + 2 folds; seg1 (papers/cites): Pc + 4 folds; seg2: Pwb only.
__global__ __launch_bounds__(256) void proj3a(
        const float* __restrict__ X0, const float* __restrict__ W0,
        unsigned short* __restrict__ o0, int M0, int nb0,
        const float* __restrict__ fA0, float* __restrict__ eA0,   // el_w
        const float* __restrict__ fA1, float* __restrict__ eA1,   // er_wb
        const float* __restrict__ X1, const float* __restrict__ W1,
        unsigned short* __restrict__ o1, int M1, int nb1,
        const float* __restrict__ fP0, float* __restrict__ eP0,   // el_c
        const float* __restrict__ fP1, float* __restrict__ eP1,   // er_c
        const float* __restrict__ fP2, float* __restrict__ eP2,   // er_w
        const float* __restrict__ fP3, float* __restrict__ eP3,   // el_wb
        const float* __restrict__ X2, const float* __restrict__ W2,
        unsigned short* __restrict__ o2, int M2, int H)
{
    __shared__ unsigned short Xs[128][72];
    __shared__ unsigned short Wsh[64][72];
    const float *X, *W; unsigned short* out; int M, row0, nf;
    const float* fv[4]; float* ev[4];
    if ((int)blockIdx.x < nb0) {
        X = X0; W = W0; out = o0; M = M0; row0 = blockIdx.x * 128;
        nf = 2; fv[0] = fA0; ev[0] = eA0; fv[1] = fA1; ev[1] = eA1;
        fv[2] = fA0; ev[2] = eA0; fv[3] = fA1; ev[3] = eA1;
    } else if ((int)blockIdx.x < nb0 + nb1) {
        X = X1; W = W1; out = o1; M = M1; row0 = ((int)blockIdx.x - nb0) * 128;
        nf = 4; fv[0] = fP0; ev[0] = eP0; fv[1] = fP1; ev[1] = eP1;
        fv[2] = fP2; ev[2] = eP2; fv[3] = fP3; ev[3] = eP3;
    } else {
        X = X2; W = W2; out = o2; M = M2; row0 = ((int)blockIdx.x - nb0 - nb1) * 128;
        nf = 0;
    }
    int tid = threadIdx.x, lane = tid & 63, wv = tid >> 6;
    int m = lane & 15, kb = lane >> 4;

    int rbase = (tid >> 4) * 8;
    int c4 = (tid & 15) * 4;
#pragma unroll
    for (int i = 0; i < 8; ++i) {
        int rg = row0 + rbase + i; if (rg >= M) rg = M - 1;
        float4 v = *reinterpret_cast<const float4*>(&X[(long)rg * 64 + c4]);
        Xs[rbase + i][c4 + 0] = f2b(v.x);
        Xs[rbase + i][c4 + 1] = f2b(v.y);
        Xs[rbase + i][c4 + 2] = f2b(v.z);
        Xs[rbase + i][c4 + 3] = f2b(v.w);
    }
    int wr = tid >> 2;
    int wc = (tid & 3) * 16;
#pragma unroll
    for (int q = 0; q < 4; ++q) {
        float4 v = *reinterpret_cast<const float4*>(&W[(long)wr * 64 + wc + q * 4]);
        Wsh[wr][wc + q * 4 + 0] = f2b(v.x);
        Wsh[wr][wc + q * 4 + 1] = f2b(v.y);
        Wsh[wr][wc + q * 4 + 2] = f2b(v.z);
        Wsh[wr][wc + q * 4 + 3] = f2b(v.w);
    }
    __syncthreads();

    f32x4 acc[2][4];
#pragma unroll
    for (int rb = 0; rb < 2; ++rb)
#pragma unroll
        for (int cb = 0; cb < 4; ++cb) acc[rb][cb] = (f32x4){0.f, 0.f, 0.f, 0.f};
#pragma unroll
    for (int kc = 0; kc < 2; ++kc) {
        short8_t a0 = *reinterpret_cast<const short8_t*>(&Xs[wv * 32 + m][kc * 32 + kb * 8]);
        short8_t a1 = *reinterpret_cast<const short8_t*>(&Xs[wv * 32 + 16 + m][kc * 32 + kb * 8]);
#pragma unroll
        for (int cb = 0; cb < 4; ++cb) {
            short8_t b = *reinterpret_cast<const short8_t*>(&Wsh[cb * 16 + m][kc * 32 + kb * 8]);
            acc[0][cb] = __builtin_amdgcn_mfma_f32_16x16x32_bf16(a0, b, acc[0][cb], 0, 0, 0);
            acc[1][cb] = __builtin_amdgcn_mfma_f32_16x16x32_bf16(a1, b, acc[1][cb], 0, 0, 0);
        }
    }
#pragma unroll
    for (int rb = 0; rb < 2; ++rb)
#pragma unroll
    for (int j = 0; j < 4; ++j) {
        int r = row0 + wv * 32 + rb * 16 + (lane >> 4) * 4 + j;
        if (r < M) {
#pragma unroll
            for (int cb = 0; cb < 4; ++cb)
                out[(long)r * 64 + cb * 16 + m] = f2b(acc[rb][cb][j]);
        }
    }

    // ---- attention folds from the staged Xs tile (LDS broadcast reads) ----
    if (nf) {
        int tot = 128 * nf * H;
        for (int t = tid; t < tot; t += 256) {
            int row = t / (nf * H);
            int rest = t - row * (nf * H);
            int f = rest / H;
            int hh = rest - f * H;
            int r = row0 + row;
            if (r >= M) continue;
            const unsigned short* xr = Xs[row];
            const float* fvv = fv[f];
            float s = 0.f;
#pragma unroll 8
            for (int k = 0; k < 64; ++k)
                s = fmaf(b2f(xr[k]), fvv[k * H + hh], s);
            ev[f][(long)r * H + hh] = s;
        }
    }
}

// ---------------- fold W*a for 12 attention vectors ----------------
struct PA { const float* W; const float* a; float* o; int H; };
__global__ void prep_attn12(PA p0, PA p1, PA p2, PA p3, PA p4, PA p5,
                            PA p6, PA p7, PA p8, PA p9, PA p10, PA p11)
{
    PA p;
    switch (blockIdx.x) {
        case 0: p = p0; break;  case 1: p = p1; break;  case 2: p = p2; break;
        case 3: p = p3; break;  case 4: p = p4; break;  case 5: p = p5; break;
        case 6: p = p6; break;  case 7: p = p7; break;  case 8: p = p8; break;
        case 9: p = p9; break;  case 10: p = p10; break; default: p = p11; break;
    }
    int k = threadIdx.x;
    int F = 64 / p.H;
    for (int hh = 0; hh < p.H; ++hh) {
        float s = 0.f;
        for (int f = 0; f < F; ++f)
            s = fmaf(p.W[(hh * F + f) * 64 + k], p.a[hh * F + f], s);
        p.o[k * p.H + hh] = s;
    }
}

// ---------------- CSR build ----------------
__global__ void bucket_hist3(const int* __restrict__ d0, int E0, int* __restrict__ b0,
                             const int* __restrict__ d1, int E1, int* __restrict__ b1,
                             const int* __restrict__ d2, int E2, int* __restrict__ b2,
                             int shift, int blocksPer)
{
    int g = blockIdx.x / blocksPer, bb = blockIdx.x - g * blocksPer;
    const int* dst = g == 0 ? d0 : g == 1 ? d1 : d2;
    int E = g == 0 ? E0 : g == 1 ? E1 : E2;
    int* bcnt = g == 0 ? b0 : g == 1 ? b1 : b2;
    __shared__ int h[256];
    int tid = threadIdx.x;
    h[tid] = 0;
    __syncthreads();
    for (long i = (long)bb * 256 + tid; i < E; i += (long)blocksPer * 256)
        atomicAdd(&h[dst[i] >> shift], 1);
    __syncthreads();
    if (h[tid]) atomicAdd(&bcnt[tid], h[tid]);
}

__global__ void bucket_scan3(int* __restrict__ bcnt, int* __restrict__ bstart,
                             int* __restrict__ gcur,
                             int* __restrict__ o0, int Nn0, int Ee0,
                             int* __restrict__ o1, int Nn1, int Ee1,
                             int* __restrict__ o2, int Nn2, int Ee2)
{
    int g = blockIdx.x;
    int* bc = bcnt + g * 256;
    int* bs = bstart + g * 257;
    int* gc = gcur + g * 256;
    int* offs = g == 0 ? o0 : g == 1 ? o1 : o2;
    int N = g == 0 ? Nn0 : g == 1 ? Nn1 : Nn2;
    int E = g == 0 ? Ee0 : g == 1 ? Ee1 : Ee2;
    __shared__ int sc[256];
    int tid = threadIdx.x;
    int v = bc[tid];
    sc[tid] = v;
    __syncthreads();
    for (int off = 1; off < 256; off <<= 1) {
        int t = (tid >= off) ? sc[tid - off] : 0;
        __syncthreads();
        sc[tid] += t;
        __syncthreads();
    }
    int excl = sc[tid] - v;
    bs[tid] = excl;
    gc[tid] = excl;
    if (tid == 255) bs[256] = E;
    if (tid == 0) offs[N] = E;
}

#define EPT 8
__global__ __launch_bounds__(256) void part3(
        const int* __restrict__ s0, const int* __restrict__ d0, int E0, int nb0,
        uint2* __restrict__ p0,
        const int* __restrict__ s1, const int* __restrict__ d1, int E1, int nb1,
        uint2* __restrict__ p1,
        const int* __restrict__ s2g, const int* __restrict__ d2g, int E2,
        uint2* __restrict__ p2,
        int* __restrict__ gcur3, int shift)
{
    const int* src; const int* dst; int E; uint2* pairs; int* gcur; long base;
    if ((int)blockIdx.x < nb0) {
        src = s0; dst = d0; E = E0; pairs = p0; gcur = gcur3;
        base = (long)blockIdx.x * (256 * EPT);
    } else if ((int)blockIdx.x < nb0 + nb1) {
        src = s1; dst = d1; E = E1; pairs = p1; gcur = gcur3 + 256;
        base = (long)((int)blockIdx.x - nb0) * (256 * EPT);
    } else {
        src = s2g; dst = d2g; E = E2; pairs = p2; gcur = gcur3 + 512;
        base = (long)((int)blockIdx.x - nb0 - nb1) * (256 * EPT);
    }
    __shared__ int hcnt[256];
    __shared__ int hbase[256];
    int tid = threadIdx.x;
    hcnt[tid] = 0;
    __syncthreads();
    int b[EPT], r[EPT], s[EPT], d[EPT];
#pragma unroll
    for (int k = 0; k < EPT; ++k) {
        long idx = base + k * 256 + tid;
        if (idx < E) {
            s[k] = src[idx]; d[k] = dst[idx];
            b[k] = d[k] >> shift;
            r[k] = atomicAdd(&hcnt[b[k]], 1);
        } else b[k] = -1;
    }
    __syncthreads();
    if (hcnt[tid]) hbase[tid] = atomicAdd(&gcur[tid], hcnt[tid]);
    __syncthreads();
#pragma unroll
    for (int k = 0; k < EPT; ++k) {
        if (b[k] >= 0)
            pairs[hbase[b[k]] + r[k]] = make_uint2((unsigned)s[k], (unsigned)d[k]);
    }
}

__global__ __launch_bounds__(512) void csr_fin3(
        const uint2* __restrict__ p0, const int* __restrict__ bs0,
        int* __restrict__ of0, int* __restrict__ c0, int N0, int NB0,
        const uint2* __restrict__ p1, const int* __restrict__ bs1,
        int* __restrict__ of1, int* __restrict__ c1, int N1, int NB1,
        const uint2* __restrict__ p2, const int* __restrict__ bs2,
        int* __restrict__ of2, int* __restrict__ c2, int N2,
        int shift)
{
    const uint2* pairs; const int* bstart; int* offs; int* csr; int N, b;
    if ((int)blockIdx.x < NB0) {
        pairs = p0; bstart = bs0; offs = of0; csr = c0; N = N0; b = blockIdx.x;
    } else if ((int)blockIdx.x < NB0 + NB1) {
        pairs = p1; bstart = bs1; offs = of1; csr = c1; N = N1; b = (int)blockIdx.x - NB0;
    } else {
        pairs = p2; bstart = bs2; offs = of2; csr = c2; N = N2;
        b = (int)blockIdx.x - NB0 - NB1;
    }
    __shared__ int cnt[512];
    __shared__ int sc[512];
    int tid = threadIdx.x;
    int d0 = b << shift;
    int pS = bstart[b], pE = bstart[b + 1];
    cnt[tid] = 0;
    __syncthreads();
    for (int i = pS + tid; i < pE; i += 512)
        atomicAdd(&cnt[pairs[i].y - d0], 1);
    __syncthreads();
    int v = cnt[tid];
    sc[tid] = v;
    __syncthreads();
    for (int off = 1; off < 512; off <<= 1) {
        int t = (tid >= off) ? sc[tid - off] : 0;
        __syncthreads();
        sc[tid] += t;
        __syncthreads();
    }
    int excl = sc[tid] - v;
    if (d0 + tid < N) offs[d0 + tid] = pS + excl;
    cnt[tid] = excl;
    __syncthreads();
    for (int i = pS + tid; i < pE; i += 512) {
        uint2 u = pairs[i];
        int p = atomicAdd(&cnt[u.y - d0], 1);
        csr[pS + p] = (int)u.x;
    }
}

// ---------------- fused GAT layer (software-pipelined pass A) ----------------
__device__ __forceinline__ void gat_graph(int d, const int* __restrict__ offs,
        const int* __restrict__ csr, const float* __restrict__ el,
        const float* __restrict__ er, const unsigned short* __restrict__ P,
        int hshift, int lane, float* o)
{
    int H = 1 << hshift;
    int off = offs[d];
    int n = offs[d + 1] - off;
    if (n == 0) return;
    int g8 = lane >> 3;
    int fo = (lane & 7) * 8;
    int hf = (hshift == 2) ? ((lane & 7) >> 1) : 0;
    int h = lane & (H - 1);
    float erd = er[d * H + h];
    int estep = 64 >> hshift;
    int i0 = lane >> hshift;
    float acc[8];
#pragma unroll
    for (int q = 0; q < 8; ++q) acc[q] = 0.f;
    float ssum = 0.f;

    int sn_c = 0; float elv_c = 0.f;
    if (i0 < n) { sn_c = __builtin_nontemporal_load(&csr[off + i0]); elv_c = el[sn_c * H + h]; }

    for (int base = 0; base < n; base += estep) {
        int inext = base + estep + i0;
        int sn_n = 0; float elv_n = 0.f;
        if (inext < n) { sn_n = __builtin_nontemporal_load(&csr[off + inext]); elv_n = el[sn_n * H + h]; }

        float a = 0.f;
        if (base + i0 < n) {
            float v = elv_c + erd;
            v = v > 0.f ? v : 0.2f * v;
            a = __expf(v);
            ssum += a;
        }
        int rounds = min(estep, n - base);
#pragma unroll 2
        for (int r = 0; r * 8 < rounds; ++r) {
            int sl = r * 8 + g8;
            int lsn = sl << hshift;
            int s2 = __shfl(sn_c, lsn, 64);
            float a2 = __shfl(a, lsn | hf, 64);
            uint4 u = *reinterpret_cast<const uint4*>(&P[(long)s2 * 64 + fo]);
            acc[0] = fmaf(__uint_as_float(u.x << 16), a2, acc[0]);
            acc[1] = fmaf(__uint_as_float(u.x & 0xffff0000u), a2, acc[1]);
            acc[2] = fmaf(__uint_as_float(u.y << 16), a2, acc[2]);
            acc[3] = fmaf(__uint_as_float(u.y & 0xffff0000u), a2, acc[3]);
            acc[4] = fmaf(__uint_as_float(u.z << 16), a2, acc[4]);
            acc[5] = fmaf(__uint_as_float(u.z & 0xffff0000u), a2, acc[5]);
            acc[6] = fmaf(__uint_as_float(u.w << 16), a2, acc[6]);
            acc[7] = fmaf(__uint_as_float(u.w & 0xffff0000u), a2, acc[7]);
        }
        sn_c = sn_n; elv_c = elv_n;
    }

    for (int oo = H; oo < 64; oo <<= 1) ssum += __shfl_xor(ssum, oo, 64);
    float rinv = 1.f / __shfl(ssum, hf, 64);
#pragma unroll
    for (int q = 0; q < 8; ++q) {
        acc[q] += __shfl_xor(acc[q], 8, 64);
        acc[q] += __shfl_xor(acc[q], 16, 64);
        acc[q] += __shfl_xor(acc[q], 32, 64);
        o[q] = fmaf(acc[q], rinv, o[q]);
    }
}

__global__ void gat_fused(
        int NPn, const int* __restrict__ w_offs, const int* __restrict__ w_csr,
        const float* __restrict__ el_w, const float* __restrict__ er_w,
        const unsigned short* __restrict__ Pw,
        const int* __restrict__ c_offs, const int* __restrict__ c_csr,
        const float* __restrict__ el_c, const float* __restrict__ er_c,
        const unsigned short* __restrict__ Pc,
        const float* __restrict__ bP0, const float* __restrict__ bP1,
        float* __restrict__ outP,
        int NAn, const int* __restrict__ wb_offs, const int* __restrict__ wb_csr,
        const float* __restrict__ el_wb, const float* __restrict__ er_wb,
        const unsigned short* __restrict__ Pwb,
        const float* __restrict__ bA0, float* __restrict__ outA,
        int hshift, int doNorm)
{
    int blocksP = (NPn + 3) >> 2;
    int lane = threadIdx.x & 63;
    int sub = threadIdx.x >> 6;
    int fo = (lane & 7) * 8;
    float o[8];
    float* dst;

    if ((int)blockIdx.x < blocksP) {
        int d = ((int)blockIdx.x << 2) | sub;
        if (d >= NPn) return;
#pragma unroll
        for (int q = 0; q < 8; ++q) o[q] = bP0[fo + q] + bP1[fo + q];
        gat_graph(d, w_offs, w_csr, el_w, er_w, Pw, hshift, lane, o);
        gat_graph(d, c_offs, c_csr, el_c, er_c, Pc, hshift, lane, o);
        dst = outP + (long)d * 64;
    } else {
        int d = (((int)blockIdx.x - blocksP) << 2) | sub;
        if (d >= NAn) return;
#pragma unroll
        for (int q = 0; q < 8; ++q) o[q] = bA0[fo + q];
        gat_graph(d, wb_offs, wb_csr, el_wb, er_wb, Pwb, hshift, lane, o);
        dst = outA + (long)d * 64;
    }

    if (doNorm) {
        float ss = 0.f;
#pragma unroll
        for (int q = 0; q < 8; ++q) ss = fmaf(o[q], o[q], ss);
        ss += __shfl_xor(ss, 1, 64);
        ss += __shfl_xor(ss, 2, 64);
        ss += __shfl_xor(ss, 4, 64);
        float sc = 1.f / fmaxf(sqrtf(ss), 1e-12f);
#pragma unroll
        for (int q = 0; q < 8; ++q) o[q] *= sc;
    }
    if (lane < 8) {
        float4 o0, o1;
        o0.x = o[0]; o0.y = o[1]; o0.z = o[2]; o0.w = o[3];
        o1.x = o[4]; o1.y = o[5]; o1.z = o[6]; o1.w = o[7];
        *reinterpret_cast<float4*>(dst + fo) = o0;
        *reinterpret_cast<float4*>(dst + fo + 4) = o1;
    }
}

extern "C" void kernel_launch(void* const* d_in, const int* in_sizes, int n_in,
                              void* d_out, int out_size, void* d_ws, size_t ws_size,
                              hipStream_t stream)
{
    const float* feat_a = (const float*)d_in[0];
    const float* feat_p = (const float*)d_in[1];
    const float* fmWa = (const float*)d_in[2];
    const float* fmba = (const float*)d_in[3];
    const float* fmWp = (const float*)d_in[4];
    const float* fmbp = (const float*)d_in[5];
    const float* g1w_W = (const float*)d_in[6];  const float* g1w_al = (const float*)d_in[7];
    const float* g1w_ar = (const float*)d_in[8]; const float* g1w_b = (const float*)d_in[9];
    const float* g2w_W = (const float*)d_in[10]; const float* g2w_al = (const float*)d_in[11];
    const float* g2w_ar = (const float*)d_in[12]; const float* g2w_b = (const float*)d_in[13];
    const float* g1wb_W = (const float*)d_in[14]; const float* g1wb_al = (const float*)d_in[15];
    const float* g1wb_ar = (const float*)d_in[16]; const float* g1wb_b = (const float*)d_in[17];
    const float* g2wb_W = (const float*)d_in[18]; const float* g2wb_al = (const float*)d_in[19];
    const float* g2wb_ar = (const float*)d_in[20]; const float* g2wb_b = (const float*)d_in[21];
    const float* g1c_W = (const float*)d_in[22]; const float* g1c_al = (const float*)d_in[23];
    const float* g1c_ar = (const float*)d_in[24]; const float* g1c_b = (const float*)d_in[25];
    const float* g2c_W = (const float*)d_in[26]; const float* g2c_al = (const float*)d_in[27];
    const float* g2c_ar = (const float*)d_in[28]; const float* g2c_b = (const float*)d_in[29];
    const int* w_src = (const int*)d_in[30];
    const int* w_dst = (const int*)d_in[31];
    const int* wb_src = (const int*)d_in[32];
    const int* wb_dst = (const int*)d_in[33];
    const int* c_src = (const int*)d_in[34];
    const int* c_dst = (const int*)d_in[35];

    float* ws = (float*)d_ws;
    size_t off = 0;
    auto alloc = [&](size_t n) { float* p = ws + off; off += n; return p; };
    float* h_a  = alloc(HA);
    float* h_p  = alloc(HP);
    float* h1_p = alloc(HP);
    float* h1_a = alloc(HA);
    uint2* pairs_w  = (uint2*)h_a;               // pairs alias h region (dead before fm2)
    uint2* pairs_c  = (uint2*)h_a + E_W;
    uint2* pairs_wb = (uint2*)h_a + E_W + E_C;
    unsigned short* Pw  = (unsigned short*)alloc(HA / 2 + 16);
    unsigned short* Pc  = (unsigned short*)alloc(HP / 2 + 16);
    unsigned short* Pwb = (unsigned short*)alloc(HP / 2 + 16);
    float* el_w  = alloc((size_t)N_A * 4);
    float* er_w  = alloc((size_t)N_P * 4);
    float* el_c  = alloc((size_t)N_P * 4);
    float* er_c  = alloc((size_t)N_P * 4);
    float* el_wb = alloc((size_t)N_P * 4);
    float* er_wb = alloc((size_t)N_A * 4);
    float* fold  = alloc(12 * 256);
    int* w_offs  = (int*)alloc(N_P + 1);
    int* c_offs  = (int*)alloc(N_P + 1);
    int* wb_offs = (int*)alloc(N_A + 1);
    int* bcnt3   = (int*)alloc(3 * 256);
    int* bstart3 = (int*)alloc(3 * 257);
    int* gcur3   = (int*)alloc(3 * 256);
    int* w_csr   = (int*)alloc(E_W);
    int* c_csr   = (int*)alloc(E_C);
    int* wb_csr  = (int*)alloc(E_W);

    float* wal_w1 = fold + 0*256,  *war_w1 = fold + 1*256;
    float* wal_c1 = fold + 2*256,  *war_c1 = fold + 3*256;
    float* wal_b1 = fold + 4*256,  *war_b1 = fold + 5*256;
    float* wal_w2 = fold + 6*256,  *war_w2 = fold + 7*256;
    float* wal_c2 = fold + 8*256,  *war_c2 = fold + 9*256;
    float* wal_b2 = fold + 10*256, *war_b2 = fold + 11*256;

    const int SHIFT = 9;
    int NB_P = (N_P + 511) >> 9;
    int NB_A = (N_A + 511) >> 9;

    // ---- CSR build ----
    hipMemsetAsync(bcnt3, 0, 3 * 256 * sizeof(int), stream);
    bucket_hist3<<<3 * 256, 256, 0, stream>>>(w_dst, E_W, bcnt3,
                                              c_dst, E_C, bcnt3 + 256,
                                              wb_dst, E_W, bcnt3 + 512, SHIFT, 256);
    bucket_scan3<<<3, 256, 0, stream>>>(bcnt3, bstart3, gcur3,
                                        w_offs, N_P, E_W,
                                        c_offs, N_P, E_C,
                                        wb_offs, N_A, E_W);
    {
        int nbW = (E_W + 2047) / 2048, nbC = (E_C + 2047) / 2048;
        part3<<<nbW + nbC + nbW, 256, 0, stream>>>(
            w_src, w_dst, E_W, nbW, pairs_w,
            c_src, c_dst, E_C, nbC, pairs_c,
            wb_src, wb_dst, E_W, pairs_wb, gcur3, SHIFT);
        csr_fin3<<<NB_P + NB_P + NB_A, 512, 0, stream>>>(
            pairs_w, bstart3, w_offs, w_csr, N_P, NB_P,
            pairs_c, bstart3 + 257, c_offs, c_csr, N_P, NB_P,
            pairs_wb, bstart3 + 514, wb_offs, wb_csr, N_A, SHIFT);
    }

    prep_attn12<<<12, 64, 0, stream>>>(
        PA{g1w_W,  g1w_al,  wal_w1, 4}, PA{g1w_W,  g1w_ar,  war_w1, 4},
        PA{g1c_W,  g1c_al,  wal_c1, 4}, PA{g1c_W,  g1c_ar,  war_c1, 4},
        PA{g1wb_W, g1wb_al, wal_b1, 4}, PA{g1wb_W, g1wb_ar, war_b1, 4},
        PA{g2w_W,  g2w_al,  wal_w2, 1}, PA{g2w_W,  g2w_ar,  war_w2, 1},
        PA{g2c_W,  g2c_al,  wal_c2, 1}, PA{g2c_W,  g2c_ar,  war_c2, 1},
        PA{g2wb_W, g2wb_al, wal_b2, 1}, PA{g2wb_W, g2wb_ar, war_b2, 1});

    // ---- feature mapping ----
    {
        int nb0 = (N_A + 127) / 128;
        int nb1 = (N_P + 127) / 128;
        gemm_fm2<<<nb0 + nb1, 256, 0, stream>>>(feat_a, fmWa, fmba, h_a, N_A, 128, nb0,
                                                feat_p, fmWp, fmbp, h_p, N_P, 256);
    }

    int nbA = (N_A + 127) / 128, nbP = (N_P + 127) / 128;
    int gatGrid = (N_P + 3) / 4 + (N_A + 3) / 4;

    // ---- Layer 1 (H=4) ----
    proj3a<<<nbA + 2 * nbP, 256, 0, stream>>>(
        h_a, g1w_W, Pw, N_A, nbA, wal_w1, el_w, war_b1, er_wb,
        h_p, g1c_W, Pc, N_P, nbP, wal_c1, el_c, war_c1, er_c, war_w1, er_w, wal_b1, el_wb,
        h_p, g1wb_W, Pwb, N_P, 4);
    gat_fused<<<gatGrid, 256, 0, stream>>>(
        N_P, w_offs, w_csr, el_w, er_w, Pw,
        c_offs, c_csr, el_c, er_c, Pc, g1w_b, g1c_b, h1_p,
        N_A, wb_offs, wb_csr, el_wb, er_wb, Pwb, g1wb_b, h1_a, 2, 0);

    // ---- Layer 2 (H=1), normalized output straight to d_out ----
    proj3a<<<nbA + 2 * nbP, 256, 0, stream>>>(
        h1_a, g2w_W, Pw, N_A, nbA, wal_w2, el_w, war_b2, er_wb,
        h1_p, g2c_W, Pc, N_P, nbP, wal_c2, el_c, war_c2, er_c, war_w2, er_w, wal_b2, el_wb,
        h1_p, g2wb_W, Pwb, N_P, 1);
    float* out = (float*)d_out;
    gat_fused<<<gatGrid, 256, 0, stream>>>(
        N_P, w_offs, w_csr, el_w, er_w, Pw,
        c_offs, c_csr, el_c, er_c, Pc, g2w_b, g2c_b, out + HA,
        N_A, wb_offs, wb_csr, el_wb, er_wb, Pwb, g2wb_b, out, 0, 1);
}

// Round 14
// 721.067 us; speedup vs baseline: 7.4658x; 1.0189x over previous
//
#include <hip/hip_runtime.h>
#include <hip/hip_bf16.h>

#define N_A 50000
#define N_P 100000
#define E_W 1600000
#define E_C 3200000
#define HA (N_A*64)
#define HP (N_P*64)

typedef __attribute__((ext_vector_type(8))) short short8_t;
typedef __attribute__((ext_vector_type(4))) float f32x4;

__device__ __forceinline__ unsigned short f2b(float f)
{
    __hip_bfloat16 b = __float2bfloat16(f);
    return *reinterpret_cast<unsigned short*>(&b);
}
__device__ __forceinline__ float b2f(unsigned short u)
{
    return __uint_as_float((unsigned)u << 16);
}

// ---------------- fused feature-mapping GEMM (2 segments, fp32 out, relu) ----------------
__global__ __launch_bounds__(256) void gemm_fm2(
        const float* __restrict__ X0, const float* __restrict__ W0,
        const float* __restrict__ b0, float* __restrict__ out0, int M0, int K0, int nb0,
        const float* __restrict__ X1, const float* __restrict__ W1,
        const float* __restrict__ b1, float* __restrict__ out1, int M1, int K1)
{
    __shared__ unsigned short Xs[128][72];
    __shared__ unsigned short Wsh[64][72];
    const float *X, *W, *bias; float* out; int M, K, row0;
    if ((int)blockIdx.x < nb0) {
        X = X0; W = W0; bias = b0; out = out0; M = M0; K = K0; row0 = blockIdx.x * 128;
    } else {
        X = X1; W = W1; bias = b1; out = out1; M = M1; K = K1;
        row0 = ((int)blockIdx.x - nb0) * 128;
    }
    int tid = threadIdx.x, lane = tid & 63, wv = tid >> 6;
    int m = lane & 15, kb = lane >> 4;

    f32x4 acc[2][4];
#pragma unroll
    for (int rb = 0; rb < 2; ++rb)
#pragma unroll
        for (int cb = 0; cb < 4; ++cb) acc[rb][cb] = (f32x4){0.f, 0.f, 0.f, 0.f};

    for (int k0 = 0; k0 < K; k0 += 64) {
        int rbase = (tid >> 4) * 8;
        int c4 = (tid & 15) * 4;
#pragma unroll
        for (int i = 0; i < 8; ++i) {
            int rg = row0 + rbase + i; if (rg >= M) rg = M - 1;
            float4 v = *reinterpret_cast<const float4*>(&X[(long)rg * K + k0 + c4]);
            Xs[rbase + i][c4 + 0] = f2b(v.x);
            Xs[rbase + i][c4 + 1] = f2b(v.y);
            Xs[rbase + i][c4 + 2] = f2b(v.z);
            Xs[rbase + i][c4 + 3] = f2b(v.w);
        }
        int wr = tid >> 2;
        int wc = (tid & 3) * 16;
#pragma unroll
        for (int q = 0; q < 4; ++q) {
            float4 v = *reinterpret_cast<const float4*>(&W[(long)wr * K + k0 + wc + q * 4]);
            Wsh[wr][wc + q * 4 + 0] = f2b(v.x);
            Wsh[wr][wc + q * 4 + 1] = f2b(v.y);
            Wsh[wr][wc + q * 4 + 2] = f2b(v.z);
            Wsh[wr][wc + q * 4 + 3] = f2b(v.w);
        }
        __syncthreads();
#pragma unroll
        for (int kc = 0; kc < 2; ++kc) {
            short8_t a0 = *reinterpret_cast<const short8_t*>(&Xs[wv * 32 + m][kc * 32 + kb * 8]);
            short8_t a1 = *reinterpret_cast<const short8_t*>(&Xs[wv * 32 + 16 + m][kc * 32 + kb * 8]);
#pragma unroll
            for (int cb = 0; cb < 4; ++cb) {
                short8_t b = *reinterpret_cast<const short8_t*>(&Wsh[cb * 16 + m][kc * 32 + kb * 8]);
                acc[0][cb] = __builtin_amdgcn_mfma_f32_16x16x32_bf16(a0, b, acc[0][cb], 0, 0, 0);
                acc[1][cb] = __builtin_amdgcn_mfma_f32_16x16x32_bf16(a1, b, acc[1][cb], 0, 0, 0);
            }
        }
        __syncthreads();
    }

#pragma unroll
    for (int rb = 0; rb < 2; ++rb)
#pragma unroll
    for (int j = 0; j < 4; ++j) {
        int r = row0 + wv * 32 + rb * 16 + (lane >> 4) * 4 + j;
        if (r < M) {
#pragma unroll
            for (int cb = 0; cb < 4; ++cb) {
                int c = cb * 16 + m;
                float v = acc[rb][cb][j] + bias[c];
                out[(long)r * 64 + c] = fmaxf(v, 0.f);
            }
        }
    }
}

// ---------------- fused 3-projection GEMM (K=64, bf16 out) + el/er folds from LDS -------
__global__ __launch_bounds__(256) void proj3a(
        const float* __restrict__ X0, const float* __restrict__ W0,
        unsigned short* __restrict__ o0, int M0, int nb0,
        const float* __restrict__ fA0, float* __restrict__ eA0,
        const float* __restrict__ fA1, float* __restrict__ eA1,
        const float* __restrict__ X1, const float* __restrict__ W1,
        unsigned short* __restrict__ o1, int M1, int nb1,
        const float* __restrict__ fP0, float* __restrict__ eP0,
        const float* __restrict__ fP1, float* __restrict__ eP1,
        const float* __restrict__ fP2, float* __restrict__ eP2,
        const float* __restrict__ fP3, float* __restrict__ eP3,
        const float* __restrict__ X2, const float* __restrict__ W2,
        unsigned short* __restrict__ o2, int M2, int H)
{
    __shared__ unsigned short Xs[128][72];
    __shared__ unsigned short Wsh[64][72];
    const float *X, *W; unsigned short* out; int M, row0, nf;
    const float* fv[4]; float* ev[4];
    if ((int)blockIdx.x < nb0) {
        X = X0; W = W0; out = o0; M = M0; row0 = blockIdx.x * 128;
        nf = 2; fv[0] = fA0; ev[0] = eA0; fv[1] = fA1; ev[1] = eA1;
        fv[2] = fA0; ev[2] = eA0; fv[3] = fA1; ev[3] = eA1;
    } else if ((int)blockIdx.x < nb0 + nb1) {
        X = X1; W = W1; out = o1; M = M1; row0 = ((int)blockIdx.x - nb0) * 128;
        nf = 4; fv[0] = fP0; ev[0] = eP0; fv[1] = fP1; ev[1] = eP1;
        fv[2] = fP2; ev[2] = eP2; fv[3] = fP3; ev[3] = eP3;
    } else {
        X = X2; W = W2; out = o2; M = M2; row0 = ((int)blockIdx.x - nb0 - nb1) * 128;
        nf = 0;
    }
    int tid = threadIdx.x, lane = tid & 63, wv = tid >> 6;
    int m = lane & 15, kb = lane >> 4;

    int rbase = (tid >> 4) * 8;
    int c4 = (tid & 15) * 4;
#pragma unroll
    for (int i = 0; i < 8; ++i) {
        int rg = row0 + rbase + i; if (rg >= M) rg = M - 1;
        float4 v = *reinterpret_cast<const float4*>(&X[(long)rg * 64 + c4]);
        Xs[rbase + i][c4 + 0] = f2b(v.x);
        Xs[rbase + i][c4 + 1] = f2b(v.y);
        Xs[rbase + i][c4 + 2] = f2b(v.z);
        Xs[rbase + i][c4 + 3] = f2b(v.w);
    }
    int wr = tid >> 2;
    int wc = (tid & 3) * 16;
#pragma unroll
    for (int q = 0; q < 4; ++q) {
        float4 v = *reinterpret_cast<const float4*>(&W[(long)wr * 64 + wc + q * 4]);
        Wsh[wr][wc + q * 4 + 0] = f2b(v.x);
        Wsh[wr][wc + q * 4 + 1] = f2b(v.y);
        Wsh[wr][wc + q * 4 + 2] = f2b(v.z);
        Wsh[wr][wc + q * 4 + 3] = f2b(v.w);
    }
    __syncthreads();

    f32x4 acc[2][4];
#pragma unroll
    for (int rb = 0; rb < 2; ++rb)
#pragma unroll
        for (int cb = 0; cb < 4; ++cb) acc[rb][cb] = (f32x4){0.f, 0.f, 0.f, 0.f};
#pragma unroll
    for (int kc = 0; kc < 2; ++kc) {
        short8_t a0 = *reinterpret_cast<const short8_t*>(&Xs[wv * 32 + m][kc * 32 + kb * 8]);
        short8_t a1 = *reinterpret_cast<const short8_t*>(&Xs[wv * 32 + 16 + m][kc * 32 + kb * 8]);
#pragma unroll
        for (int cb = 0; cb < 4; ++cb) {
            short8_t b = *reinterpret_cast<const short8_t*>(&Wsh[cb * 16 + m][kc * 32 + kb * 8]);
            acc[0][cb] = __builtin_amdgcn_mfma_f32_16x16x32_bf16(a0, b, acc[0][cb], 0, 0, 0);
            acc[1][cb] = __builtin_amdgcn_mfma_f32_16x16x32_bf16(a1, b, acc[1][cb], 0, 0, 0);
        }
    }
#pragma unroll
    for (int rb = 0; rb < 2; ++rb)
#pragma unroll
    for (int j = 0; j < 4; ++j) {
        int r = row0 + wv * 32 + rb * 16 + (lane >> 4) * 4 + j;
        if (r < M) {
#pragma unroll
            for (int cb = 0; cb < 4; ++cb)
                out[(long)r * 64 + cb * 16 + m] = f2b(acc[rb][cb][j]);
        }
    }

    if (nf) {
        int tot = 128 * nf * H;
        for (int t = tid; t < tot; t += 256) {
            int row = t / (nf * H);
            int rest = t - row * (nf * H);
            int f = rest / H;
            int hh = rest - f * H;
            int r = row0 + row;
            if (r >= M) continue;
            const unsigned short* xr = Xs[row];
            const float* fvv = fv[f];
            float s = 0.f;
#pragma unroll 8
            for (int k = 0; k < 64; ++k)
                s = fmaf(b2f(xr[k]), fvv[k * H + hh], s);
            ev[f][(long)r * H + hh] = s;
        }
    }
}

// ---------------- fold W*a for 12 attention vectors ----------------
struct PA { const float* W; const float* a; float* o; int H; };
__global__ void prep_attn12(PA p0, PA p1, PA p2, PA p3, PA p4, PA p5,
                            PA p6, PA p7, PA p8, PA p9, PA p10, PA p11)
{
    PA p;
    switch (blockIdx.x) {
        case 0: p = p0; break;  case 1: p = p1; break;  case 2: p = p2; break;
        case 3: p = p3; break;  case 4: p = p4; break;  case 5: p = p5; break;
        case 6: p = p6; break;  case 7: p = p7; break;  case 8: p = p8; break;
        case 9: p = p9; break;  case 10: p = p10; break; default: p = p11; break;
    }
    int k = threadIdx.x;
    int F = 64 / p.H;
    for (int hh = 0; hh < p.H; ++hh) {
        float s = 0.f;
        for (int f = 0; f < F; ++f)
            s = fmaf(p.W[(hh * F + f) * 64 + k], p.a[hh * F + f], s);
        p.o[k * p.H + hh] = s;
    }
}

// ---------------- CSR build ----------------
__global__ void bucket_hist3(const int* __restrict__ d0, int E0, int* __restrict__ b0,
                             const int* __restrict__ d1, int E1, int* __restrict__ b1,
                             const int* __restrict__ d2, int E2, int* __restrict__ b2,
                             int shift, int blocksPer)
{
    int g = blockIdx.x / blocksPer, bb = blockIdx.x - g * blocksPer;
    const int* dst = g == 0 ? d0 : g == 1 ? d1 : d2;
    int E = g == 0 ? E0 : g == 1 ? E1 : E2;
    int* bcnt = g == 0 ? b0 : g == 1 ? b1 : b2;
    __shared__ int h[256];
    int tid = threadIdx.x;
    h[tid] = 0;
    __syncthreads();
    for (long i = (long)bb * 256 + tid; i < E; i += (long)blocksPer * 256)
        atomicAdd(&h[dst[i] >> shift], 1);
    __syncthreads();
    if (h[tid]) atomicAdd(&bcnt[tid], h[tid]);
}

__global__ void bucket_scan3(int* __restrict__ bcnt, int* __restrict__ bstart,
                             int* __restrict__ gcur,
                             int* __restrict__ o0, int Nn0, int Ee0,
                             int* __restrict__ o1, int Nn1, int Ee1,
                             int* __restrict__ o2, int Nn2, int Ee2)
{
    int g = blockIdx.x;
    int* bc = bcnt + g * 256;
    int* bs = bstart + g * 257;
    int* gc = gcur + g * 256;
    int* offs = g == 0 ? o0 : g == 1 ? o1 : o2;
    int N = g == 0 ? Nn0 : g == 1 ? Nn1 : Nn2;
    int E = g == 0 ? Ee0 : g == 1 ? Ee1 : Ee2;
    __shared__ int sc[256];
    int tid = threadIdx.x;
    int v = bc[tid];
    sc[tid] = v;
    __syncthreads();
    for (int off = 1; off < 256; off <<= 1) {
        int t = (tid >= off) ? sc[tid - off] : 0;
        __syncthreads();
        sc[tid] += t;
        __syncthreads();
    }
    int excl = sc[tid] - v;
    bs[tid] = excl;
    gc[tid] = excl;
    if (tid == 255) bs[256] = E;
    if (tid == 0) offs[N] = E;
}

#define EPT 8
__global__ __launch_bounds__(256) void part3(
        const int* __restrict__ s0, const int* __restrict__ d0, int E0, int nb0,
        uint2* __restrict__ p0,
        const int* __restrict__ s1, const int* __restrict__ d1, int E1, int nb1,
        uint2* __restrict__ p1,
        const int* __restrict__ s2g, const int* __restrict__ d2g, int E2,
        uint2* __restrict__ p2,
        int* __restrict__ gcur3, int shift)
{
    const int* src; const int* dst; int E; uint2* pairs; int* gcur; long base;
    if ((int)blockIdx.x < nb0) {
        src = s0; dst = d0; E = E0; pairs = p0; gcur = gcur3;
        base = (long)blockIdx.x * (256 * EPT);
    } else if ((int)blockIdx.x < nb0 + nb1) {
        src = s1; dst = d1; E = E1; pairs = p1; gcur = gcur3 + 256;
        base = (long)((int)blockIdx.x - nb0) * (256 * EPT);
    } else {
        src = s2g; dst = d2g; E = E2; pairs = p2; gcur = gcur3 + 512;
        base = (long)((int)blockIdx.x - nb0 - nb1) * (256 * EPT);
    }
    __shared__ int hcnt[256];
    __shared__ int hbase[256];
    int tid = threadIdx.x;
    hcnt[tid] = 0;
    __syncthreads();
    int b[EPT], r[EPT], s[EPT], d[EPT];
#pragma unroll
    for (int k = 0; k < EPT; ++k) {
        long idx = base + k * 256 + tid;
        if (idx < E) {
            s[k] = src[idx]; d[k] = dst[idx];
            b[k] = d[k] >> shift;
            r[k] = atomicAdd(&hcnt[b[k]], 1);
        } else b[k] = -1;
    }
    __syncthreads();
    if (hcnt[tid]) hbase[tid] = atomicAdd(&gcur[tid], hcnt[tid]);
    __syncthreads();
#pragma unroll
    for (int k = 0; k < EPT; ++k) {
        if (b[k] >= 0)
            pairs[hbase[b[k]] + r[k]] = make_uint2((unsigned)s[k], (unsigned)d[k]);
    }
}

__global__ __launch_bounds__(512) void csr_fin3(
        const uint2* __restrict__ p0, const int* __restrict__ bs0,
        int* __restrict__ of0, int* __restrict__ c0, int N0, int NB0,
        const uint2* __restrict__ p1, const int* __restrict__ bs1,
        int* __restrict__ of1, int* __restrict__ c1, int N1, int NB1,
        const uint2* __restrict__ p2, const int* __restrict__ bs2,
        int* __restrict__ of2, int* __restrict__ c2, int N2,
        int shift)
{
    const uint2* pairs; const int* bstart; int* offs; int* csr; int N, b;
    if ((int)blockIdx.x < NB0) {
        pairs = p0; bstart = bs0; offs = of0; csr = c0; N = N0; b = blockIdx.x;
    } else if ((int)blockIdx.x < NB0 + NB1) {
        pairs = p1; bstart = bs1; offs = of1; csr = c1; N = N1; b = (int)blockIdx.x - NB0;
    } else {
        pairs = p2; bstart = bs2; offs = of2; csr = c2; N = N2;
        b = (int)blockIdx.x - NB0 - NB1;
    }
    __shared__ int cnt[512];
    __shared__ int sc[512];
    int tid = threadIdx.x;
    int d0 = b << shift;
    int pS = bstart[b], pE = bstart[b + 1];
    cnt[tid] = 0;
    __syncthreads();
    for (int i = pS + tid; i < pE; i += 512)
        atomicAdd(&cnt[pairs[i].y - d0], 1);
    __syncthreads();
    int v = cnt[tid];
    sc[tid] = v;
    __syncthreads();
    for (int off = 1; off < 512; off <<= 1) {
        int t = (tid >= off) ? sc[tid - off] : 0;
        __syncthreads();
        sc[tid] += t;
        __syncthreads();
    }
    int excl = sc[tid] - v;
    if (d0 + tid < N) offs[d0 + tid] = pS + excl;
    cnt[tid] = excl;
    __syncthreads();
    for (int i = pS + tid; i < pE; i += 512) {
        uint2 u = pairs[i];
        int p = atomicAdd(&cnt[u.y - d0], 1);
        csr[pS + p] = (int)u.x;
    }
}

// ---------------- fused GAT layer (pipelined pass A + depth-2 payload prefetch) ---------
__device__ __forceinline__ void gat_graph(int d, const int* __restrict__ offs,
        const int* __restrict__ csr, const float* __restrict__ el,
        const float* __restrict__ er, const unsigned short* __restrict__ P,
        int hshift, int lane, float* o)
{
    int H = 1 << hshift;
    int off = offs[d];
    int n = offs[d + 1] - off;
    if (n == 0) return;
    int g8 = lane >> 3;
    int fo = (lane & 7) * 8;
    int hf = (hshift == 2) ? ((lane & 7) >> 1) : 0;
    int h = lane & (H - 1);
    float erd = er[d * H + h];
    int estep = 64 >> hshift;
    int i0 = lane >> hshift;
    float acc[8];
#pragma unroll
    for (int q = 0; q < 8; ++q) acc[q] = 0.f;
    float ssum = 0.f;

    // macro-prefetch round 0's csr + el
    int sn_c = 0; float elv_c = 0.f;
    if (i0 < n) { sn_c = csr[off + i0]; elv_c = el[sn_c * H + h]; }

    for (int base = 0; base < n; base += estep) {
        // prefetch next macro-round's csr + el
        int inext = base + estep + i0;
        int sn_n = 0; float elv_n = 0.f;
        if (inext < n) { sn_n = csr[off + inext]; elv_n = el[sn_n * H + h]; }

        float a = 0.f;
        if (base + i0 < n) {
            float v = elv_c + erd;
            v = v > 0.f ? v : 0.2f * v;
            a = __expf(v);
            ssum += a;
        }
        int rounds = min(estep, n - base);
        int nmr = (rounds + 7) >> 3;

        // depth-2 pipelined payload gathers
        int lsn0 = g8 << hshift;
        int s2_c = __shfl(sn_c, lsn0, 64);
        float a_c = __shfl(a, lsn0 | hf, 64);
        uint4 u_c = *reinterpret_cast<const uint4*>(&P[(long)s2_c * 64 + fo]);
        for (int r = 0; r < nmr; ++r) {
            uint4 u_n; float a_n = 0.f;
            if (r + 1 < nmr) {
                int lsn = (((r + 1) * 8 + g8) << hshift);
                int s2_n = __shfl(sn_c, lsn, 64);
                a_n = __shfl(a, lsn | hf, 64);
                u_n = *reinterpret_cast<const uint4*>(&P[(long)s2_n * 64 + fo]);
            }
            acc[0] = fmaf(__uint_as_float(u_c.x << 16), a_c, acc[0]);
            acc[1] = fmaf(__uint_as_float(u_c.x & 0xffff0000u), a_c, acc[1]);
            acc[2] = fmaf(__uint_as_float(u_c.y << 16), a_c, acc[2]);
            acc[3] = fmaf(__uint_as_float(u_c.y & 0xffff0000u), a_c, acc[3]);
            acc[4] = fmaf(__uint_as_float(u_c.z << 16), a_c, acc[4]);
            acc[5] = fmaf(__uint_as_float(u_c.z & 0xffff0000u), a_c, acc[5]);
            acc[6] = fmaf(__uint_as_float(u_c.w << 16), a_c, acc[6]);
            acc[7] = fmaf(__uint_as_float(u_c.w & 0xffff0000u), a_c, acc[7]);
            u_c = u_n; a_c = a_n;
        }
        sn_c = sn_n; elv_c = elv_n;
    }

    for (int oo = H; oo < 64; oo <<= 1) ssum += __shfl_xor(ssum, oo, 64);
    float rinv = 1.f / __shfl(ssum, hf, 64);
#pragma unroll
    for (int q = 0; q < 8; ++q) {
        acc[q] += __shfl_xor(acc[q], 8, 64);
        acc[q] += __shfl_xor(acc[q], 16, 64);
        acc[q] += __shfl_xor(acc[q], 32, 64);
        o[q] = fmaf(acc[q], rinv, o[q]);
    }
}

__global__ void gat_fused(
        int NPn, const int* __restrict__ w_offs, const int* __restrict__ w_csr,
        const float* __restrict__ el_w, const float* __restrict__ er_w,
        const unsigned short* __restrict__ Pw,
        const int* __restrict__ c_offs, const int* __restrict__ c_csr,
        const float* __restrict__ el_c, const float* __restrict__ er_c,
        const unsigned short* __restrict__ Pc,
        const float* __restrict__ bP0, const float* __restrict__ bP1,
        float* __restrict__ outP,
        int NAn, const int* __restrict__ wb_offs, const int* __restrict__ wb_csr,
        const float* __restrict__ el_wb, const float* __restrict__ er_wb,
        const unsigned short* __restrict__ Pwb,
        const float* __restrict__ bA0, float* __restrict__ outA,
        int hshift, int doNorm)
{
    int blocksP = (NPn + 3) >> 2;
    int lane = threadIdx.x & 63;
    int sub = threadIdx.x >> 6;
    int fo = (lane & 7) * 8;
    float o[8];
    float* dst;

    if ((int)blockIdx.x < blocksP) {
        int d = ((int)blockIdx.x << 2) | sub;
        if (d >= NPn) return;
#pragma unroll
        for (int q = 0; q < 8; ++q) o[q] = bP0[fo + q] + bP1[fo + q];
        gat_graph(d, w_offs, w_csr, el_w, er_w, Pw, hshift, lane, o);
        gat_graph(d, c_offs, c_csr, el_c, er_c, Pc, hshift, lane, o);
        dst = outP + (long)d * 64;
    } else {
        int d = (((int)blockIdx.x - blocksP) << 2) | sub;
        if (d >= NAn) return;
#pragma unroll
        for (int q = 0; q < 8; ++q) o[q] = bA0[fo + q];
        gat_graph(d, wb_offs, wb_csr, el_wb, er_wb, Pwb, hshift, lane, o);
        dst = outA + (long)d * 64;
    }

    if (doNorm) {
        float ss = 0.f;
#pragma unroll
        for (int q = 0; q < 8; ++q) ss = fmaf(o[q], o[q], ss);
        ss += __shfl_xor(ss, 1, 64);
        ss += __shfl_xor(ss, 2, 64);
        ss += __shfl_xor(ss, 4, 64);
        float sc = 1.f / fmaxf(sqrtf(ss), 1e-12f);
#pragma unroll
        for (int q = 0; q < 8; ++q) o[q] *= sc;
    }
    if (lane < 8) {
        float4 o0, o1;
        o0.x = o[0]; o0.y = o[1]; o0.z = o[2]; o0.w = o[3];
        o1.x = o[4]; o1.y = o[5]; o1.z = o[6]; o1.w = o[7];
        *reinterpret_cast<float4*>(dst + fo) = o0;
        *reinterpret_cast<float4*>(dst + fo + 4) = o1;
    }
}

extern "C" void kernel_launch(void* const* d_in, const int* in_sizes, int n_in,
                              void* d_out, int out_size, void* d_ws, size_t ws_size,
                              hipStream_t stream)
{
    const float* feat_a = (const float*)d_in[0];
    const float* feat_p = (const float*)d_in[1];
    const float* fmWa = (const float*)d_in[2];
    const float* fmba = (const float*)d_in[3];
    const float* fmWp = (const float*)d_in[4];
    const float* fmbp = (const float*)d_in[5];
    const float* g1w_W = (const float*)d_in[6];  const float* g1w_al = (const float*)d_in[7];
    const float* g1w_ar = (const float*)d_in[8]; const float* g1w_b = (const float*)d_in[9];
    const float* g2w_W = (const float*)d_in[10]; const float* g2w_al = (const float*)d_in[11];
    const float* g2w_ar = (const float*)d_in[12]; const float* g2w_b = (const float*)d_in[13];
    const float* g1wb_W = (const float*)d_in[14]; const float* g1wb_al = (const float*)d_in[15];
    const float* g1wb_ar = (const float*)d_in[16]; const float* g1wb_b = (const float*)d_in[17];
    const float* g2wb_W = (const float*)d_in[18]; const float* g2wb_al = (const float*)d_in[19];
    const float* g2wb_ar = (const float*)d_in[20]; const float* g2wb_b = (const float*)d_in[21];
    const float* g1c_W = (const float*)d_in[22]; const float* g1c_al = (const float*)d_in[23];
    const float* g1c_ar = (const float*)d_in[24]; const float* g1c_b = (const float*)d_in[25];
    const float* g2c_W = (const float*)d_in[26]; const float* g2c_al = (const float*)d_in[27];
    const float* g2c_ar = (const float*)d_in[28]; const float* g2c_b = (const float*)d_in[29];
    const int* w_src = (const int*)d_in[30];
    const int* w_dst = (const int*)d_in[31];
    const int* wb_src = (const int*)d_in[32];
    const int* wb_dst = (const int*)d_in[33];
    const int* c_src = (const int*)d_in[34];
    const int* c_dst = (const int*)d_in[35];

    float* ws = (float*)d_ws;
    size_t off = 0;
    auto alloc = [&](size_t n) { float* p = ws + off; off += n; return p; };
    float* h_a  = alloc(HA);
    float* h_p  = alloc(HP);
    float* h1_p = alloc(HP);
    float* h1_a = alloc(HA);
    uint2* pairs_w  = (uint2*)h_a;               // pairs alias h region (dead before fm2)
    uint2* pairs_c  = (uint2*)h_a + E_W;
    uint2* pairs_wb = (uint2*)h_a + E_W + E_C;
    unsigned short* Pw  = (unsigned short*)alloc(HA / 2 + 16);
    unsigned short* Pc  = (unsigned short*)alloc(HP / 2 + 16);
    unsigned short* Pwb = (unsigned short*)alloc(HP / 2 + 16);
    float* el_w  = alloc((size_t)N_A * 4);
    float* er_w  = alloc((size_t)N_P * 4);
    float* el_c  = alloc((size_t)N_P * 4);
    float* er_c  = alloc((size_t)N_P * 4);
    float* el_wb = alloc((size_t)N_P * 4);
    float* er_wb = alloc((size_t)N_A * 4);
    float* fold  = alloc(12 * 256);
    int* w_offs  = (int*)alloc(N_P + 1);
    int* c_offs  = (int*)alloc(N_P + 1);
    int* wb_offs = (int*)alloc(N_A + 1);
    int* bcnt3   = (int*)alloc(3 * 256);
    int* bstart3 = (int*)alloc(3 * 257);
    int* gcur3   = (int*)alloc(3 * 256);
    int* w_csr   = (int*)alloc(E_W);
    int* c_csr   = (int*)alloc(E_C);
    int* wb_csr  = (int*)alloc(E_W);

    float* wal_w1 = fold + 0*256,  *war_w1 = fold + 1*256;
    float* wal_c1 = fold + 2*256,  *war_c1 = fold + 3*256;
    float* wal_b1 = fold + 4*256,  *war_b1 = fold + 5*256;
    float* wal_w2 = fold + 6*256,  *war_w2 = fold + 7*256;
    float* wal_c2 = fold + 8*256,  *war_c2 = fold + 9*256;
    float* wal_b2 = fold + 10*256, *war_b2 = fold + 11*256;

    const int SHIFT = 9;
    int NB_P = (N_P + 511) >> 9;
    int NB_A = (N_A + 511) >> 9;

    // ---- CSR build ----
    hipMemsetAsync(bcnt3, 0, 3 * 256 * sizeof(int), stream);
    bucket_hist3<<<3 * 256, 256, 0, stream>>>(w_dst, E_W, bcnt3,
                                              c_dst, E_C, bcnt3 + 256,
                                              wb_dst, E_W, bcnt3 + 512, SHIFT, 256);
    bucket_scan3<<<3, 256, 0, stream>>>(bcnt3, bstart3, gcur3,
                                        w_offs, N_P, E_W,
                                        c_offs, N_P, E_C,
                                        wb_offs, N_A, E_W);
    {
        int nbW = (E_W + 2047) / 2048, nbC = (E_C + 2047) / 2048;
        part3<<<nbW + nbC + nbW, 256, 0, stream>>>(
            w_src, w_dst, E_W, nbW, pairs_w,
            c_src, c_dst, E_C, nbC, pairs_c,
            wb_src, wb_dst, E_W, pairs_wb, gcur3, SHIFT);
        csr_fin3<<<NB_P + NB_P + NB_A, 512, 0, stream>>>(
            pairs_w, bstart3, w_offs, w_csr, N_P, NB_P,
            pairs_c, bstart3 + 257, c_offs, c_csr, N_P, NB_P,
            pairs_wb, bstart3 + 514, wb_offs, wb_csr, N_A, SHIFT);
    }

    prep_attn12<<<12, 64, 0, stream>>>(
        PA{g1w_W,  g1w_al,  wal_w1, 4}, PA{g1w_W,  g1w_ar,  war_w1, 4},
        PA{g1c_W,  g1c_al,  wal_c1, 4}, PA{g1c_W,  g1c_ar,  war_c1, 4},
        PA{g1wb_W, g1wb_al, wal_b1, 4}, PA{g1wb_W, g1wb_ar, war_b1, 4},
        PA{g2w_W,  g2w_al,  wal_w2, 1}, PA{g2w_W,  g2w_ar,  war_w2, 1},
        PA{g2c_W,  g2c_al,  wal_c2, 1}, PA{g2c_W,  g2c_ar,  war_c2, 1},
        PA{g2wb_W, g2wb_al, wal_b2, 1}, PA{g2wb_W, g2wb_ar, war_b2, 1});

    // ---- feature mapping ----
    {
        int nb0 = (N_A + 127) / 128;
        int nb1 = (N_P + 127) / 128;
        gemm_fm2<<<nb0 + nb1, 256, 0, stream>>>(feat_a, fmWa, fmba, h_a, N_A, 128, nb0,
                                                feat_p, fmWp, fmbp, h_p, N_P, 256);
    }

    int nbA = (N_A + 127) / 128, nbP = (N_P + 127) / 128;
    int gatGrid = (N_P + 3) / 4 + (N_A + 3) / 4;

    // ---- Layer 1 (H=4) ----
    proj3a<<<nbA + 2 * nbP, 256, 0, stream>>>(
        h_a, g1w_W, Pw, N_A, nbA, wal_w1, el_w, war_b1, er_wb,
        h_p, g1c_W, Pc, N_P, nbP, wal_c1, el_c, war_c1, er_c, war_w1, er_w, wal_b1, el_wb,
        h_p, g1wb_W, Pwb, N_P, 4);
    gat_fused<<<gatGrid, 256, 0, stream>>>(
        N_P, w_offs, w_csr, el_w, er_w, Pw,
        c_offs, c_csr, el_c, er_c, Pc, g1w_b, g1c_b, h1_p,
        N_A, wb_offs, wb_csr, el_wb, er_wb, Pwb, g1wb_b, h1_a, 2, 0);

    // ---- Layer 2 (H=1), normalized output straight to d_out ----
    proj3a<<<nbA + 2 * nbP, 256, 0, stream>>>(
        h1_a, g2w_W, Pw, N_A, nbA, wal_w2, el_w, war_b2, er_wb,
        h1_p, g2c_W, Pc, N_P, nbP, wal_c2, el_c, war_c2, er_c, war_w2, er_w, wal_b2, el_wb,
        h1_p, g2wb_W, Pwb, N_P, 1);
    float* out = (float*)d_out;
    gat_fused<<<gatGrid, 256, 0, stream>>>(
        N_P, w_offs, w_csr, el_w, er_w, Pw,
        c_offs, c_csr, el_c, er_c, Pc, g2w_b, g2c_b, out + HA,
        N_A, wb_offs, wb_csr, el_wb, er_wb, Pwb, g2wb_b, out, 0, 1);
}

// Round 15
// 710.070 us; speedup vs baseline: 7.5814x; 1.0155x over previous
//
#include <hip/hip_runtime.h>
#include <hip/hip_bf16.h>

#define N_A 50000
#define N_P 100000
#define E_W 1600000
#define E_C 3200000
#define HA (N_A*64)
#define HP (N_P*64)

typedef __attribute__((ext_vector_type(8))) short short8_t;
typedef __attribute__((ext_vector_type(4))) float f32x4;

__device__ __forceinline__ unsigned short f2b(float f)
{
    __hip_bfloat16 b = __float2bfloat16(f);
    return *reinterpret_cast<unsigned short*>(&b);
}
__device__ __forceinline__ float b2f(unsigned short u)
{
    return __uint_as_float((unsigned)u << 16);
}

// ---------------- fused feature-mapping GEMM (2 segments, fp32 out, relu) ----------------
__global__ __launch_bounds__(256) void gemm_fm2(
        const float* __restrict__ X0, const float* __restrict__ W0,
        const float* __restrict__ b0, float* __restrict__ out0, int M0, int K0, int nb0,
        const float* __restrict__ X1, const float* __restrict__ W1,
        const float* __restrict__ b1, float* __restrict__ out1, int M1, int K1)
{
    __shared__ unsigned short Xs[128][72];
    __shared__ unsigned short Wsh[64][72];
    const float *X, *W, *bias; float* out; int M, K, row0;
    if ((int)blockIdx.x < nb0) {
        X = X0; W = W0; bias = b0; out = out0; M = M0; K = K0; row0 = blockIdx.x * 128;
    } else {
        X = X1; W = W1; bias = b1; out = out1; M = M1; K = K1;
        row0 = ((int)blockIdx.x - nb0) * 128;
    }
    int tid = threadIdx.x, lane = tid & 63, wv = tid >> 6;
    int m = lane & 15, kb = lane >> 4;

    f32x4 acc[2][4];
#pragma unroll
    for (int rb = 0; rb < 2; ++rb)
#pragma unroll
        for (int cb = 0; cb < 4; ++cb) acc[rb][cb] = (f32x4){0.f, 0.f, 0.f, 0.f};

    for (int k0 = 0; k0 < K; k0 += 64) {
        int rbase = (tid >> 4) * 8;
        int c4 = (tid & 15) * 4;
#pragma unroll
        for (int i = 0; i < 8; ++i) {
            int rg = row0 + rbase + i; if (rg >= M) rg = M - 1;
            float4 v = *reinterpret_cast<const float4*>(&X[(long)rg * K + k0 + c4]);
            Xs[rbase + i][c4 + 0] = f2b(v.x);
            Xs[rbase + i][c4 + 1] = f2b(v.y);
            Xs[rbase + i][c4 + 2] = f2b(v.z);
            Xs[rbase + i][c4 + 3] = f2b(v.w);
        }
        int wr = tid >> 2;
        int wc = (tid & 3) * 16;
#pragma unroll
        for (int q = 0; q < 4; ++q) {
            float4 v = *reinterpret_cast<const float4*>(&W[(long)wr * K + k0 + wc + q * 4]);
            Wsh[wr][wc + q * 4 + 0] = f2b(v.x);
            Wsh[wr][wc + q * 4 + 1] = f2b(v.y);
            Wsh[wr][wc + q * 4 + 2] = f2b(v.z);
            Wsh[wr][wc + q * 4 + 3] = f2b(v.w);
        }
        __syncthreads();
#pragma unroll
        for (int kc = 0; kc < 2; ++kc) {
            short8_t a0 = *reinterpret_cast<const short8_t*>(&Xs[wv * 32 + m][kc * 32 + kb * 8]);
            short8_t a1 = *reinterpret_cast<const short8_t*>(&Xs[wv * 32 + 16 + m][kc * 32 + kb * 8]);
#pragma unroll
            for (int cb = 0; cb < 4; ++cb) {
                short8_t b = *reinterpret_cast<const short8_t*>(&Wsh[cb * 16 + m][kc * 32 + kb * 8]);
                acc[0][cb] = __builtin_amdgcn_mfma_f32_16x16x32_bf16(a0, b, acc[0][cb], 0, 0, 0);
                acc[1][cb] = __builtin_amdgcn_mfma_f32_16x16x32_bf16(a1, b, acc[1][cb], 0, 0, 0);
            }
        }
        __syncthreads();
    }

#pragma unroll
    for (int rb = 0; rb < 2; ++rb)
#pragma unroll
    for (int j = 0; j < 4; ++j) {
        int r = row0 + wv * 32 + rb * 16 + (lane >> 4) * 4 + j;
        if (r < M) {
#pragma unroll
            for (int cb = 0; cb < 4; ++cb) {
                int c = cb * 16 + m;
                float v = acc[rb][cb][j] + bias[c];
                out[(long)r * 64 + c] = fmaxf(v, 0.f);
            }
        }
    }
}

// ---------------- fused 3-projection GEMM (K=64, bf16 out) + el/er folds from LDS -------
__global__ __launch_bounds__(256) void proj3a(
        const float* __restrict__ X0, const float* __restrict__ W0,
        unsigned short* __restrict__ o0, int M0, int nb0,
        const float* __restrict__ fA0, float* __restrict__ eA0,
        const float* __restrict__ fA1, float* __restrict__ eA1,
        const float* __restrict__ X1, const float* __restrict__ W1,
        unsigned short* __restrict__ o1, int M1, int nb1,
        const float* __restrict__ fP0, float* __restrict__ eP0,
        const float* __restrict__ fP1, float* __restrict__ eP1,
        const float* __restrict__ fP2, float* __restrict__ eP2,
        const float* __restrict__ fP3, float* __restrict__ eP3,
        const float* __restrict__ X2, const float* __restrict__ W2,
        unsigned short* __restrict__ o2, int M2, int H)
{
    __shared__ unsigned short Xs[128][72];
    __shared__ unsigned short Wsh[64][72];
    const float *X, *W; unsigned short* out; int M, row0, nf;
    const float* fv[4]; float* ev[4];
    if ((int)blockIdx.x < nb0) {
        X = X0; W = W0; out = o0; M = M0; row0 = blockIdx.x * 128;
        nf = 2; fv[0] = fA0; ev[0] = eA0; fv[1] = fA1; ev[1] = eA1;
        fv[2] = fA0; ev[2] = eA0; fv[3] = fA1; ev[3] = eA1;
    } else if ((int)blockIdx.x < nb0 + nb1) {
        X = X1; W = W1; out = o1; M = M1; row0 = ((int)blockIdx.x - nb0) * 128;
        nf = 4; fv[0] = fP0; ev[0] = eP0; fv[1] = fP1; ev[1] = eP1;
        fv[2] = fP2; ev[2] = eP2; fv[3] = fP3; ev[3] = eP3;
    } else {
        X = X2; W = W2; out = o2; M = M2; row0 = ((int)blockIdx.x - nb0 - nb1) * 128;
        nf = 0;
    }
    int tid = threadIdx.x, lane = tid & 63, wv = tid >> 6;
    int m = lane & 15, kb = lane >> 4;

    int rbase = (tid >> 4) * 8;
    int c4 = (tid & 15) * 4;
#pragma unroll
    for (int i = 0; i < 8; ++i) {
        int rg = row0 + rbase + i; if (rg >= M) rg = M - 1;
        float4 v = *reinterpret_cast<const float4*>(&X[(long)rg * 64 + c4]);
        Xs[rbase + i][c4 + 0] = f2b(v.x);
        Xs[rbase + i][c4 + 1] = f2b(v.y);
        Xs[rbase + i][c4 + 2] = f2b(v.z);
        Xs[rbase + i][c4 + 3] = f2b(v.w);
    }
    int wr = tid >> 2;
    int wc = (tid & 3) * 16;
#pragma unroll
    for (int q = 0; q < 4; ++q) {
        float4 v = *reinterpret_cast<const float4*>(&W[(long)wr * 64 + wc + q * 4]);
        Wsh[wr][wc + q * 4 + 0] = f2b(v.x);
        Wsh[wr][wc + q * 4 + 1] = f2b(v.y);
        Wsh[wr][wc + q * 4 + 2] = f2b(v.z);
        Wsh[wr][wc + q * 4 + 3] = f2b(v.w);
    }
    __syncthreads();

    f32x4 acc[2][4];
#pragma unroll
    for (int rb = 0; rb < 2; ++rb)
#pragma unroll
        for (int cb = 0; cb < 4; ++cb) acc[rb][cb] = (f32x4){0.f, 0.f, 0.f, 0.f};
#pragma unroll
    for (int kc = 0; kc < 2; ++kc) {
        short8_t a0 = *reinterpret_cast<const short8_t*>(&Xs[wv * 32 + m][kc * 32 + kb * 8]);
        short8_t a1 = *reinterpret_cast<const short8_t*>(&Xs[wv * 32 + 16 + m][kc * 32 + kb * 8]);
#pragma unroll
        for (int cb = 0; cb < 4; ++cb) {
            short8_t b = *reinterpret_cast<const short8_t*>(&Wsh[cb * 16 + m][kc * 32 + kb * 8]);
            acc[0][cb] = __builtin_amdgcn_mfma_f32_16x16x32_bf16(a0, b, acc[0][cb], 0, 0, 0);
            acc[1][cb] = __builtin_amdgcn_mfma_f32_16x16x32_bf16(a1, b, acc[1][cb], 0, 0, 0);
        }
    }
#pragma unroll
    for (int rb = 0; rb < 2; ++rb)
#pragma unroll
    for (int j = 0; j < 4; ++j) {
        int r = row0 + wv * 32 + rb * 16 + (lane >> 4) * 4 + j;
        if (r < M) {
#pragma unroll
            for (int cb = 0; cb < 4; ++cb)
                out[(long)r * 64 + cb * 16 + m] = f2b(acc[rb][cb][j]);
        }
    }

    if (nf) {
        int tot = 128 * nf * H;
        for (int t = tid; t < tot; t += 256) {
            int row = t / (nf * H);
            int rest = t - row * (nf * H);
            int f = rest / H;
            int hh = rest - f * H;
            int r = row0 + row;
            if (r >= M) continue;
            const unsigned short* xr = Xs[row];
            const float* fvv = fv[f];
            float s = 0.f;
#pragma unroll 8
            for (int k = 0; k < 64; ++k)
                s = fmaf(b2f(xr[k]), fvv[k * H + hh], s);
            ev[f][(long)r * H + hh] = s;
        }
    }
}

// ---------------- fold W*a for 12 attention vectors ----------------
struct PA { const float* W; const float* a; float* o; int H; };
__global__ void prep_attn12(PA p0, PA p1, PA p2, PA p3, PA p4, PA p5,
                            PA p6, PA p7, PA p8, PA p9, PA p10, PA p11)
{
    PA p;
    switch (blockIdx.x) {
        case 0: p = p0; break;  case 1: p = p1; break;  case 2: p = p2; break;
        case 3: p = p3; break;  case 4: p = p4; break;  case 5: p = p5; break;
        case 6: p = p6; break;  case 7: p = p7; break;  case 8: p = p8; break;
        case 9: p = p9; break;  case 10: p = p10; break; default: p = p11; break;
    }
    int k = threadIdx.x;
    int F = 64 / p.H;
    for (int hh = 0; hh < p.H; ++hh) {
        float s = 0.f;
        for (int f = 0; f < F; ++f)
            s = fmaf(p.W[(hh * F + f) * 64 + k], p.a[hh * F + f], s);
        p.o[k * p.H + hh] = s;
    }
}

// ---------------- CSR build ----------------
__global__ void bucket_hist3(const int* __restrict__ d0, int E0, int* __restrict__ b0,
                             const int* __restrict__ d1, int E1, int* __restrict__ b1,
                             const int* __restrict__ d2, int E2, int* __restrict__ b2,
                             int shift, int blocksPer)
{
    int g = blockIdx.x / blocksPer, bb = blockIdx.x - g * blocksPer;
    const int* dst = g == 0 ? d0 : g == 1 ? d1 : d2;
    int E = g == 0 ? E0 : g == 1 ? E1 : E2;
    int* bcnt = g == 0 ? b0 : g == 1 ? b1 : b2;
    __shared__ int h[256];
    int tid = threadIdx.x;
    h[tid] = 0;
    __syncthreads();
    for (long i = (long)bb * 256 + tid; i < E; i += (long)blocksPer * 256)
        atomicAdd(&h[dst[i] >> shift], 1);
    __syncthreads();
    if (h[tid]) atomicAdd(&bcnt[tid], h[tid]);
}

__global__ void bucket_scan3(int* __restrict__ bcnt, int* __restrict__ bstart,
                             int* __restrict__ gcur,
                             int* __restrict__ o0, int Nn0, int Ee0,
                             int* __restrict__ o1, int Nn1, int Ee1,
                             int* __restrict__ o2, int Nn2, int Ee2)
{
    int g = blockIdx.x;
    int* bc = bcnt + g * 256;
    int* bs = bstart + g * 257;
    int* gc = gcur + g * 256;
    int* offs = g == 0 ? o0 : g == 1 ? o1 : o2;
    int N = g == 0 ? Nn0 : g == 1 ? Nn1 : Nn2;
    int E = g == 0 ? Ee0 : g == 1 ? Ee1 : Ee2;
    __shared__ int sc[256];
    int tid = threadIdx.x;
    int v = bc[tid];
    sc[tid] = v;
    __syncthreads();
    for (int off = 1; off < 256; off <<= 1) {
        int t = (tid >= off) ? sc[tid - off] : 0;
        __syncthreads();
        sc[tid] += t;
        __syncthreads();
    }
    int excl = sc[tid] - v;
    bs[tid] = excl;
    gc[tid] = excl;
    if (tid == 255) bs[256] = E;
    if (tid == 0) offs[N] = E;
}

#define EPT 8
// 3 graphs, packed pairs: (src << 9) | (dst & 511)
__global__ __launch_bounds__(256) void part3(
        const int* __restrict__ s0, const int* __restrict__ d0, int E0, int nb0,
        unsigned* __restrict__ p0,
        const int* __restrict__ s1, const int* __restrict__ d1, int E1, int nb1,
        unsigned* __restrict__ p1,
        const int* __restrict__ s2g, const int* __restrict__ d2g, int E2,
        unsigned* __restrict__ p2,
        int* __restrict__ gcur3, int shift)
{
    const int* src; const int* dst; int E; unsigned* pairs; int* gcur; long base;
    if ((int)blockIdx.x < nb0) {
        src = s0; dst = d0; E = E0; pairs = p0; gcur = gcur3;
        base = (long)blockIdx.x * (256 * EPT);
    } else if ((int)blockIdx.x < nb0 + nb1) {
        src = s1; dst = d1; E = E1; pairs = p1; gcur = gcur3 + 256;
        base = (long)((int)blockIdx.x - nb0) * (256 * EPT);
    } else {
        src = s2g; dst = d2g; E = E2; pairs = p2; gcur = gcur3 + 512;
        base = (long)((int)blockIdx.x - nb0 - nb1) * (256 * EPT);
    }
    __shared__ int hcnt[256];
    __shared__ int hbase[256];
    int tid = threadIdx.x;
    hcnt[tid] = 0;
    __syncthreads();
    int b[EPT], r[EPT], s[EPT], d[EPT];
#pragma unroll
    for (int k = 0; k < EPT; ++k) {
        long idx = base + k * 256 + tid;
        if (idx < E) {
            s[k] = src[idx]; d[k] = dst[idx];
            b[k] = d[k] >> shift;
            r[k] = atomicAdd(&hcnt[b[k]], 1);
        } else b[k] = -1;
    }
    __syncthreads();
    if (hcnt[tid]) hbase[tid] = atomicAdd(&gcur[tid], hcnt[tid]);
    __syncthreads();
#pragma unroll
    for (int k = 0; k < EPT; ++k) {
        if (b[k] >= 0)
            pairs[hbase[b[k]] + r[k]] = ((unsigned)s[k] << 9) | ((unsigned)d[k] & 511u);
    }
}

__global__ __launch_bounds__(512) void csr_fin3(
        const unsigned* __restrict__ p0, const int* __restrict__ bs0,
        int* __restrict__ of0, int* __restrict__ c0, int N0, int NB0,
        const unsigned* __restrict__ p1, const int* __restrict__ bs1,
        int* __restrict__ of1, int* __restrict__ c1, int N1, int NB1,
        const unsigned* __restrict__ p2, const int* __restrict__ bs2,
        int* __restrict__ of2, int* __restrict__ c2, int N2,
        int shift)
{
    const unsigned* pairs; const int* bstart; int* offs; int* csr; int N, b;
    if ((int)blockIdx.x < NB0) {
        pairs = p0; bstart = bs0; offs = of0; csr = c0; N = N0; b = blockIdx.x;
    } else if ((int)blockIdx.x < NB0 + NB1) {
        pairs = p1; bstart = bs1; offs = of1; csr = c1; N = N1; b = (int)blockIdx.x - NB0;
    } else {
        pairs = p2; bstart = bs2; offs = of2; csr = c2; N = N2;
        b = (int)blockIdx.x - NB0 - NB1;
    }
    __shared__ int cnt[512];
    __shared__ int sc[512];
    int tid = threadIdx.x;
    int d0 = b << shift;
    int pS = bstart[b], pE = bstart[b + 1];
    cnt[tid] = 0;
    __syncthreads();
    for (int i = pS + tid; i < pE; i += 512)
        atomicAdd(&cnt[pairs[i] & 511u], 1);
    __syncthreads();
    int v = cnt[tid];
    sc[tid] = v;
    __syncthreads();
    for (int off = 1; off < 512; off <<= 1) {
        int t = (tid >= off) ? sc[tid - off] : 0;
        __syncthreads();
        sc[tid] += t;
        __syncthreads();
    }
    int excl = sc[tid] - v;
    if (d0 + tid < N) offs[d0 + tid] = pS + excl;
    cnt[tid] = excl;
    __syncthreads();
    for (int i = pS + tid; i < pE; i += 512) {
        unsigned u = pairs[i];
        int p = atomicAdd(&cnt[u & 511u], 1);
        csr[pS + p] = (int)(u >> 9);
    }
}

// ---------------- fused GAT layer (pipelined pass A + depth-2 payload prefetch) ---------
__device__ __forceinline__ void gat_graph(int d, const int* __restrict__ offs,
        const int* __restrict__ csr, const float* __restrict__ el,
        const float* __restrict__ er, const unsigned short* __restrict__ P,
        int hshift, int lane, float* o)
{
    int H = 1 << hshift;
    int off = offs[d];
    int n = offs[d + 1] - off;
    if (n == 0) return;
    int g8 = lane >> 3;
    int fo = (lane & 7) * 8;
    int hf = (hshift == 2) ? ((lane & 7) >> 1) : 0;
    int h = lane & (H - 1);
    float erd = er[d * H + h];
    int estep = 64 >> hshift;
    int i0 = lane >> hshift;
    float acc[8];
#pragma unroll
    for (int q = 0; q < 8; ++q) acc[q] = 0.f;
    float ssum = 0.f;

    int sn_c = 0; float elv_c = 0.f;
    if (i0 < n) { sn_c = csr[off + i0]; elv_c = el[sn_c * H + h]; }

    for (int base = 0; base < n; base += estep) {
        int inext = base + estep + i0;
        int sn_n = 0; float elv_n = 0.f;
        if (inext < n) { sn_n = csr[off + inext]; elv_n = el[sn_n * H + h]; }

        float a = 0.f;
        if (base + i0 < n) {
            float v = elv_c + erd;
            v = v > 0.f ? v : 0.2f * v;
            a = __expf(v);
            ssum += a;
        }
        int rounds = min(estep, n - base);
        int nmr = (rounds + 7) >> 3;

        int lsn0 = g8 << hshift;
        int s2_c = __shfl(sn_c, lsn0, 64);
        float a_c = __shfl(a, lsn0 | hf, 64);
        uint4 u_c = *reinterpret_cast<const uint4*>(&P[(long)s2_c * 64 + fo]);
        for (int r = 0; r < nmr; ++r) {
            uint4 u_n; float a_n = 0.f;
            if (r + 1 < nmr) {
                int lsn = (((r + 1) * 8 + g8) << hshift);
                int s2_n = __shfl(sn_c, lsn, 64);
                a_n = __shfl(a, lsn | hf, 64);
                u_n = *reinterpret_cast<const uint4*>(&P[(long)s2_n * 64 + fo]);
            }
            acc[0] = fmaf(__uint_as_float(u_c.x << 16), a_c, acc[0]);
            acc[1] = fmaf(__uint_as_float(u_c.x & 0xffff0000u), a_c, acc[1]);
            acc[2] = fmaf(__uint_as_float(u_c.y << 16), a_c, acc[2]);
            acc[3] = fmaf(__uint_as_float(u_c.y & 0xffff0000u), a_c, acc[3]);
            acc[4] = fmaf(__uint_as_float(u_c.z << 16), a_c, acc[4]);
            acc[5] = fmaf(__uint_as_float(u_c.z & 0xffff0000u), a_c, acc[5]);
            acc[6] = fmaf(__uint_as_float(u_c.w << 16), a_c, acc[6]);
            acc[7] = fmaf(__uint_as_float(u_c.w & 0xffff0000u), a_c, acc[7]);
            u_c = u_n; a_c = a_n;
        }
        sn_c = sn_n; elv_c = elv_n;
    }

    for (int oo = H; oo < 64; oo <<= 1) ssum += __shfl_xor(ssum, oo, 64);
    float rinv = 1.f / __shfl(ssum, hf, 64);
#pragma unroll
    for (int q = 0; q < 8; ++q) {
        acc[q] += __shfl_xor(acc[q], 8, 64);
        acc[q] += __shfl_xor(acc[q], 16, 64);
        acc[q] += __shfl_xor(acc[q], 32, 64);
        o[q] = fmaf(acc[q], rinv, o[q]);
    }
}

__global__ void gat_fused(
        int NPn, const int* __restrict__ w_offs, const int* __restrict__ w_csr,
        const float* __restrict__ el_w, const float* __restrict__ er_w,
        const unsigned short* __restrict__ Pw,
        const int* __restrict__ c_offs, const int* __restrict__ c_csr,
        const float* __restrict__ el_c, const float* __restrict__ er_c,
        const unsigned short* __restrict__ Pc,
        const float* __restrict__ bP0, const float* __restrict__ bP1,
        float* __restrict__ outP,
        int NAn, const int* __restrict__ wb_offs, const int* __restrict__ wb_csr,
        const float* __restrict__ el_wb, const float* __restrict__ er_wb,
        const unsigned short* __restrict__ Pwb,
        const float* __restrict__ bA0, float* __restrict__ outA,
        int hshift, int doNorm)
{
    int blocksP = (NPn + 3) >> 2;
    int lane = threadIdx.x & 63;
    int sub = threadIdx.x >> 6;
    int fo = (lane & 7) * 8;
    float o[8];
    float* dst;

    if ((int)blockIdx.x < blocksP) {
        int d = ((int)blockIdx.x << 2) | sub;
        if (d >= NPn) return;
#pragma unroll
        for (int q = 0; q < 8; ++q) o[q] = bP0[fo + q] + bP1[fo + q];
        gat_graph(d, w_offs, w_csr, el_w, er_w, Pw, hshift, lane, o);
        gat_graph(d, c_offs, c_csr, el_c, er_c, Pc, hshift, lane, o);
        dst = outP + (long)d * 64;
    } else {
        int d = (((int)blockIdx.x - blocksP) << 2) | sub;
        if (d >= NAn) return;
#pragma unroll
        for (int q = 0; q < 8; ++q) o[q] = bA0[fo + q];
        gat_graph(d, wb_offs, wb_csr, el_wb, er_wb, Pwb, hshift, lane, o);
        dst = outA + (long)d * 64;
    }

    if (doNorm) {
        float ss = 0.f;
#pragma unroll
        for (int q = 0; q < 8; ++q) ss = fmaf(o[q], o[q], ss);
        ss += __shfl_xor(ss, 1, 64);
        ss += __shfl_xor(ss, 2, 64);
        ss += __shfl_xor(ss, 4, 64);
        float sc = 1.f / fmaxf(sqrtf(ss), 1e-12f);
#pragma unroll
        for (int q = 0; q < 8; ++q) o[q] *= sc;
    }
    if (lane < 8) {
        float4 o0, o1;
        o0.x = o[0]; o0.y = o[1]; o0.z = o[2]; o0.w = o[3];
        o1.x = o[4]; o1.y = o[5]; o1.z = o[6]; o1.w = o[7];
        *reinterpret_cast<float4*>(dst + fo) = o0;
        *reinterpret_cast<float4*>(dst + fo + 4) = o1;
    }
}

extern "C" void kernel_launch(void* const* d_in, const int* in_sizes, int n_in,
                              void* d_out, int out_size, void* d_ws, size_t ws_size,
                              hipStream_t stream)
{
    const float* feat_a = (const float*)d_in[0];
    const float* feat_p = (const float*)d_in[1];
    const float* fmWa = (const float*)d_in[2];
    const float* fmba = (const float*)d_in[3];
    const float* fmWp = (const float*)d_in[4];
    const float* fmbp = (const float*)d_in[5];
    const float* g1w_W = (const float*)d_in[6];  const float* g1w_al = (const float*)d_in[7];
    const float* g1w_ar = (const float*)d_in[8]; const float* g1w_b = (const float*)d_in[9];
    const float* g2w_W = (const float*)d_in[10]; const float* g2w_al = (const float*)d_in[11];
    const float* g2w_ar = (const float*)d_in[12]; const float* g2w_b = (const float*)d_in[13];
    const float* g1wb_W = (const float*)d_in[14]; const float* g1wb_al = (const float*)d_in[15];
    const float* g1wb_ar = (const float*)d_in[16]; const float* g1wb_b = (const float*)d_in[17];
    const float* g2wb_W = (const float*)d_in[18]; const float* g2wb_al = (const float*)d_in[19];
    const float* g2wb_ar = (const float*)d_in[20]; const float* g2wb_b = (const float*)d_in[21];
    const float* g1c_W = (const float*)d_in[22]; const float* g1c_al = (const float*)d_in[23];
    const float* g1c_ar = (const float*)d_in[24]; const float* g1c_b = (const float*)d_in[25];
    const float* g2c_W = (const float*)d_in[26]; const float* g2c_al = (const float*)d_in[27];
    const float* g2c_ar = (const float*)d_in[28]; const float* g2c_b = (const float*)d_in[29];
    const int* w_src = (const int*)d_in[30];
    const int* w_dst = (const int*)d_in[31];
    const int* wb_src = (const int*)d_in[32];
    const int* wb_dst = (const int*)d_in[33];
    const int* c_src = (const int*)d_in[34];
    const int* c_dst = (const int*)d_in[35];

    float* ws = (float*)d_ws;
    size_t off = 0;
    auto alloc = [&](size_t n) { float* p = ws + off; off += n; return p; };
    float* h_a  = alloc(HA);
    float* h_p  = alloc(HP);
    float* h1_p = alloc(HP);
    float* h1_a = alloc(HA);
    unsigned* pairs_w  = (unsigned*)h_a;           // packed pairs alias h region
    unsigned* pairs_c  = (unsigned*)h_a + E_W;
    unsigned* pairs_wb = (unsigned*)h_a + E_W + E_C;
    unsigned short* Pw  = (unsigned short*)alloc(HA / 2 + 16);
    unsigned short* Pc  = (unsigned short*)alloc(HP / 2 + 16);
    unsigned short* Pwb = (unsigned short*)alloc(HP / 2 + 16);
    float* el_w  = alloc((size_t)N_A * 4);
    float* er_w  = alloc((size_t)N_P * 4);
    float* el_c  = alloc((size_t)N_P * 4);
    float* er_c  = alloc((size_t)N_P * 4);
    float* el_wb = alloc((size_t)N_P * 4);
    float* er_wb = alloc((size_t)N_A * 4);
    float* fold  = alloc(12 * 256);
    int* w_offs  = (int*)alloc(N_P + 1);
    int* c_offs  = (int*)alloc(N_P + 1);
    int* wb_offs = (int*)alloc(N_A + 1);
    int* bcnt3   = (int*)alloc(3 * 256);
    int* bstart3 = (int*)alloc(3 * 257);
    int* gcur3   = (int*)alloc(3 * 256);
    int* w_csr   = (int*)alloc(E_W);
    int* c_csr   = (int*)alloc(E_C);
    int* wb_csr  = (int*)alloc(E_W);

    float* wal_w1 = fold + 0*256,  *war_w1 = fold + 1*256;
    float* wal_c1 = fold + 2*256,  *war_c1 = fold + 3*256;
    float* wal_b1 = fold + 4*256,  *war_b1 = fold + 5*256;
    float* wal_w2 = fold + 6*256,  *war_w2 = fold + 7*256;
    float* wal_c2 = fold + 8*256,  *war_c2 = fold + 9*256;
    float* wal_b2 = fold + 10*256, *war_b2 = fold + 11*256;

    const int SHIFT = 9;
    int NB_P = (N_P + 511) >> 9;
    int NB_A = (N_A + 511) >> 9;

    // ---- CSR build ----
    hipMemsetAsync(bcnt3, 0, 3 * 256 * sizeof(int), stream);
    bucket_hist3<<<3 * 256, 256, 0, stream>>>(w_dst, E_W, bcnt3,
                                              c_dst, E_C, bcnt3 + 256,
                                              wb_dst, E_W, bcnt3 + 512, SHIFT, 256);
    bucket_scan3<<<3, 256, 0, stream>>>(bcnt3, bstart3, gcur3,
                                        w_offs, N_P, E_W,
                                        c_offs, N_P, E_C,
                                        wb_offs, N_A, E_W);
    {
        int nbW = (E_W + 2047) / 2048, nbC = (E_C + 2047) / 2048;
        part3<<<nbW + nbC + nbW, 256, 0, stream>>>(
            w_src, w_dst, E_W, nbW, pairs_w,
            c_src, c_dst, E_C, nbC, pairs_c,
            wb_src, wb_dst, E_W, pairs_wb, gcur3, SHIFT);
        csr_fin3<<<NB_P + NB_P + NB_A, 512, 0, stream>>>(
            pairs_w, bstart3, w_offs, w_csr, N_P, NB_P,
            pairs_c, bstart3 + 257, c_offs, c_csr, N_P, NB_P,
            pairs_wb, bstart3 + 514, wb_offs, wb_csr, N_A, SHIFT);
    }

    prep_attn12<<<12, 64, 0, stream>>>(
        PA{g1w_W,  g1w_al,  wal_w1, 4}, PA{g1w_W,  g1w_ar,  war_w1, 4},
        PA{g1c_W,  g1c_al,  wal_c1, 4}, PA{g1c_W,  g1c_ar,  war_c1, 4},
        PA{g1wb_W, g1wb_al, wal_b1, 4}, PA{g1wb_W, g1wb_ar, war_b1, 4},
        PA{g2w_W,  g2w_al,  wal_w2, 1}, PA{g2w_W,  g2w_ar,  war_w2, 1},
        PA{g2c_W,  g2c_al,  wal_c2, 1}, PA{g2c_W,  g2c_ar,  war_c2, 1},
        PA{g2wb_W, g2wb_al, wal_b2, 1}, PA{g2wb_W, g2wb_ar, war_b2, 1});

    // ---- feature mapping ----
    {
        int nb0 = (N_A + 127) / 128;
        int nb1 = (N_P + 127) / 128;
        gemm_fm2<<<nb0 + nb1, 256, 0, stream>>>(feat_a, fmWa, fmba, h_a, N_A, 128, nb0,
                                                feat_p, fmWp, fmbp, h_p, N_P, 256);
    }

    int nbA = (N_A + 127) / 128, nbP = (N_P + 127) / 128;
    int gatGrid = (N_P + 3) / 4 + (N_A + 3) / 4;

    // ---- Layer 1 (H=4) ----
    proj3a<<<nbA + 2 * nbP, 256, 0, stream>>>(
        h_a, g1w_W, Pw, N_A, nbA, wal_w1, el_w, war_b1, er_wb,
        h_p, g1c_W, Pc, N_P, nbP, wal_c1, el_c, war_c1, er_c, war_w1, er_w, wal_b1, el_wb,
        h_p, g1wb_W, Pwb, N_P, 4);
    gat_fused<<<gatGrid, 256, 0, stream>>>(
        N_P, w_offs, w_csr, el_w, er_w, Pw,
        c_offs, c_csr, el_c, er_c, Pc, g1w_b, g1c_b, h1_p,
        N_A, wb_offs, wb_csr, el_wb, er_wb, Pwb, g1wb_b, h1_a, 2, 0);

    // ---- Layer 2 (H=1), normalized output straight to d_out ----
    proj3a<<<nbA + 2 * nbP, 256, 0, stream>>>(
        h1_a, g2w_W, Pw, N_A, nbA, wal_w2, el_w, war_b2, er_wb,
        h1_p, g2c_W, Pc, N_P, nbP, wal_c2, el_c, war_c2, er_c, war_w2, er_w, wal_b2, el_wb,
        h1_p, g2wb_W, Pwb, N_P, 1);
    float* out = (float*)d_out;
    gat_fused<<<gatGrid, 256, 0, stream>>>(
        N_P, w_offs, w_csr, el_w, er_w, Pw,
        c_offs, c_csr, el_c, er_c, Pc, g2w_b, g2c_b, out + HA,
        N_A, wb_offs, wb_csr, el_wb, er_wb, Pwb, g2wb_b, out, 0, 1);
}